// Round 1
// baseline (3619.175 us; speedup 1.0000x reference)
//
#include <hip/hip_runtime.h>
#include <hip/hip_bf16.h>

// HeteroMessagePassingLayer: GCN(glom->glom) + GATv2(imm->glom) + GIN(glom->imm)
// + HeteroConv(sum) + shared LayerNorm + ReLU.  f32 baseline, atomics for
// segment sums, tiled f32 GEMMs.

constexpr int D = 256;

// ---------------------------------------------------------------- utilities
__device__ __forceinline__ float4 ld4(const float* p) {
    return *reinterpret_cast<const float4*>(p);
}
__device__ __forceinline__ void st4(float* p, float4 v) {
    *reinterpret_cast<float4*>(p) = v;
}
__device__ __forceinline__ unsigned fenc(float f) {
    unsigned u = __float_as_uint(f);
    return (u & 0x80000000u) ? ~u : (u | 0x80000000u);
}
__device__ __forceinline__ float fdec(unsigned u) {
    return (u & 0x80000000u) ? __uint_as_float(u ^ 0x80000000u)
                             : __uint_as_float(~u);
}

// ------------------------------------------------------------------- GEMM
// C[M,256] = A[M,256] @ W[256,256] (+ bias).  64x64 tile, 4x4 microtile.
__global__ __launch_bounds__(256)
void k_gemm(const float* __restrict__ A, const float* __restrict__ W,
            const float* __restrict__ bias, float* __restrict__ C, int M)
{
    __shared__ float As[32][65];   // As[k][m]  (65: conflict-free scalar reads)
    __shared__ float Bs[32][68];   // Bs[k][n]  (68 floats = 272B, 16B-aligned rows)

    const int row0 = blockIdx.x * 64;
    const int col0 = blockIdx.y * 64;
    const int tid  = threadIdx.x;
    const int tx   = tid & 15;
    const int ty   = tid >> 4;

    float acc[4][4] = {};

    for (int kk = 0; kk < D; kk += 32) {
#pragma unroll
        for (int i = 0; i < 8; ++i) {           // A tile: 64 rows x 32 k
            int e = tid + i * 256;
            int r = e >> 5, k = e & 31;
            int gr = row0 + r;
            As[k][r] = (gr < M) ? A[gr * D + kk + k] : 0.f;
        }
#pragma unroll
        for (int i = 0; i < 8; ++i) {           // B tile: 32 k x 64 cols
            int e = tid + i * 256;
            int k = e >> 6, c = e & 63;
            Bs[k][c] = W[(kk + k) * D + col0 + c];
        }
        __syncthreads();
#pragma unroll
        for (int k = 0; k < 32; ++k) {
            float a0 = As[k][ty * 4 + 0];
            float a1 = As[k][ty * 4 + 1];
            float a2 = As[k][ty * 4 + 2];
            float a3 = As[k][ty * 4 + 3];
            float4 b = *reinterpret_cast<const float4*>(&Bs[k][tx * 4]);
            acc[0][0] += a0 * b.x; acc[0][1] += a0 * b.y; acc[0][2] += a0 * b.z; acc[0][3] += a0 * b.w;
            acc[1][0] += a1 * b.x; acc[1][1] += a1 * b.y; acc[1][2] += a1 * b.z; acc[1][3] += a1 * b.w;
            acc[2][0] += a2 * b.x; acc[2][1] += a2 * b.y; acc[2][2] += a2 * b.z; acc[2][3] += a2 * b.w;
            acc[3][0] += a3 * b.x; acc[3][1] += a3 * b.y; acc[3][2] += a3 * b.z; acc[3][3] += a3 * b.w;
        }
        __syncthreads();
    }

#pragma unroll
    for (int i = 0; i < 4; ++i) {
        int gr = row0 + ty * 4 + i;
        if (gr < M) {
            int gc = col0 + tx * 4;
            float4 v = make_float4(acc[i][0], acc[i][1], acc[i][2], acc[i][3]);
            if (bias) {
                v.x += bias[gc + 0]; v.y += bias[gc + 1];
                v.z += bias[gc + 2]; v.w += bias[gc + 3];
            }
            st4(&C[gr * D + gc], v);
        }
    }
}

// ------------------------------------------------------------ small inits
__global__ void k_init_nodes(float* deg, float* denom, unsigned* mseg, int N)
{
    int i = blockIdx.x * 256 + threadIdx.x;
    if (i < N) {
        deg[i]   = 1.0f;            // self-loop weight
        denom[i] = 0.0f;
        mseg[i]  = 0x007FFFFFu;     // fenc(-inf)
    }
}

__global__ void k_zero4(float* p, int n4)
{
    int i = blockIdx.x * 256 + threadIdx.x;
    if (i < n4) st4(p + i * 4, make_float4(0.f, 0.f, 0.f, 0.f));
}

__global__ void k_deg_accum(const int* __restrict__ ei, const float* __restrict__ ew,
                            float* __restrict__ deg, int E)
{
    int e = blockIdx.x * 256 + threadIdx.x;
    if (e < E) atomicAdd(&deg[ei[E + e]], ew[e]);
}

__global__ void k_rsqrt_inplace(float* deg, int N)
{
    int i = blockIdx.x * 256 + threadIdx.x;
    if (i < N) deg[i] = rsqrtf(deg[i]);
}

// glom_acc = dinv^2 * xw + b_gcn + b_gat       (GCN self loop + both biases)
__global__ void k_init_glom(const float* __restrict__ xw, const float* __restrict__ dinv,
                            const float* __restrict__ b_gcn, const float* __restrict__ b_gat,
                            float* __restrict__ out, int N)
{
    int idx = blockIdx.x * 256 + threadIdx.x;      // one float4 per thread
    if (idx >= N * (D / 4)) return;
    int node = idx >> 6;                            // D/4 = 64 float4 per row
    int c4   = (idx & 63) * 4;
    float di = dinv[node];
    float sc = di * di;
    float4 v = ld4(&xw[node * D + c4]);
    float4 g = ld4(&b_gcn[c4]);
    float4 a = ld4(&b_gat[c4]);
    v.x = sc * v.x + g.x + a.x;
    v.y = sc * v.y + g.y + a.y;
    v.z = sc * v.z + g.z + a.z;
    v.w = sc * v.w + g.w + a.w;
    st4(&out[node * D + c4], v);
}

// ------------------------------------------------------------- GCN edges
__global__ __launch_bounds__(256)
void k_gcn_edge(const int* __restrict__ ei, const float* __restrict__ ew,
                const float* __restrict__ dinv, const float* __restrict__ xw,
                float* __restrict__ out, int E)
{
    int e    = (blockIdx.x * 256 + threadIdx.x) >> 6;   // one wave per edge
    int lane = threadIdx.x & 63;
    if (e >= E) return;
    int s = ei[e], d = ei[E + e];
    float coef = dinv[s] * ew[e] * dinv[d];
    float4 v = ld4(&xw[s * D + lane * 4]);
    float* o = &out[d * D + lane * 4];
    atomicAdd(o + 0, coef * v.x);
    atomicAdd(o + 1, coef * v.y);
    atomicAdd(o + 2, coef * v.z);
    atomicAdd(o + 3, coef * v.w);
}

// ------------------------------------------------------------- GAT edges
__global__ __launch_bounds__(256)
void k_gat_logits(const int* __restrict__ ei, const float* __restrict__ ea,
                  const float* __restrict__ hl, const float* __restrict__ hr,
                  const float* __restrict__ We, const float* __restrict__ att,
                  float* __restrict__ logits, unsigned* __restrict__ mseg, int E)
{
    int e    = (blockIdx.x * 256 + threadIdx.x) >> 6;
    int lane = threadIdx.x & 63;
    if (e >= E) return;
    int s = ei[e], d = ei[E + e];
    float eav = ea[e];
    float4 a = ld4(&hl[s * D + lane * 4]);
    float4 b = ld4(&hr[d * D + lane * 4]);
    float4 w = ld4(&We[lane * 4]);
    float4 t = ld4(&att[lane * 4]);

    float z, p = 0.f;
    z = a.x + b.x + eav * w.x; z = (z > 0.f) ? z : 0.2f * z; p += z * t.x;
    z = a.y + b.y + eav * w.y; z = (z > 0.f) ? z : 0.2f * z; p += z * t.y;
    z = a.z + b.z + eav * w.z; z = (z > 0.f) ? z : 0.2f * z; p += z * t.z;
    z = a.w + b.w + eav * w.w; z = (z > 0.f) ? z : 0.2f * z; p += z * t.w;

#pragma unroll
    for (int off = 32; off > 0; off >>= 1) p += __shfl_xor(p, off, 64);

    if (lane == 0) {
        logits[e] = p;
        atomicMax(&mseg[d], fenc(p));
    }
}

__global__ void k_gat_exp(const int* __restrict__ ei, const float* __restrict__ logits,
                          const unsigned* __restrict__ mseg, float* __restrict__ exb,
                          float* __restrict__ denom, int E)
{
    int e = blockIdx.x * 256 + threadIdx.x;
    if (e >= E) return;
    int d = ei[E + e];
    float m  = fdec(mseg[d]);
    float ex = expf(logits[e] - m);
    exb[e] = ex;
    atomicAdd(&denom[d], ex);
}

__global__ __launch_bounds__(256)
void k_gat_aggr(const int* __restrict__ ei, const float* __restrict__ exb,
                const float* __restrict__ denom, const float* __restrict__ hl,
                float* __restrict__ out, int E)
{
    int e    = (blockIdx.x * 256 + threadIdx.x) >> 6;
    int lane = threadIdx.x & 63;
    if (e >= E) return;
    int s = ei[e], d = ei[E + e];
    float alpha = exb[e] / denom[d];
    float4 v = ld4(&hl[s * D + lane * 4]);
    float* o = &out[d * D + lane * 4];
    atomicAdd(o + 0, alpha * v.x);
    atomicAdd(o + 1, alpha * v.y);
    atomicAdd(o + 2, alpha * v.z);
    atomicAdd(o + 3, alpha * v.w);
}

// ------------------------------------------------------------- GIN edges
__global__ __launch_bounds__(256)
void k_gin_edge(const int* __restrict__ ei, const float* __restrict__ x,
                float* __restrict__ agg, int E)
{
    int e    = (blockIdx.x * 256 + threadIdx.x) >> 6;
    int lane = threadIdx.x & 63;
    if (e >= E) return;
    int s = ei[e], d = ei[E + e];
    float4 v = ld4(&x[s * D + lane * 4]);
    float* o = &agg[d * D + lane * 4];
    atomicAdd(o + 0, v.x);
    atomicAdd(o + 1, v.y);
    atomicAdd(o + 2, v.z);
    atomicAdd(o + 3, v.w);
}

// agg = (1+eps)*x_imm + agg      (in place; feeds GIN GEMM)
__global__ void k_gin_in(const float* __restrict__ x_imm, const float* __restrict__ eps,
                         float* __restrict__ agg, int N)
{
    int idx = blockIdx.x * 256 + threadIdx.x;
    if (idx >= N * (D / 4)) return;
    float c = 1.0f + eps[0];
    float4 a = ld4(&agg[idx * 4]);
    float4 x = ld4(&x_imm[idx * 4]);
    a.x = c * x.x + a.x;
    a.y = c * x.y + a.y;
    a.z = c * x.z + a.z;
    a.w = c * x.w + a.w;
    st4(&agg[idx * 4], a);
}

// -------------------------------------------------------- LayerNorm+ReLU
__global__ __launch_bounds__(256)
void k_ln_relu(float* __restrict__ io, const float* __restrict__ gamma,
               const float* __restrict__ beta, int rows)
{
    int r    = (blockIdx.x * 256 + threadIdx.x) >> 6;   // one wave per row
    int lane = threadIdx.x & 63;
    if (r >= rows) return;
    float4 v = ld4(&io[r * D + lane * 4]);
    float s  = v.x + v.y + v.z + v.w;
    float sq = v.x * v.x + v.y * v.y + v.z * v.z + v.w * v.w;
#pragma unroll
    for (int off = 32; off > 0; off >>= 1) {
        s  += __shfl_xor(s, off, 64);
        sq += __shfl_xor(sq, off, 64);
    }
    float mu  = s * (1.0f / 256.0f);
    float var = sq * (1.0f / 256.0f) - mu * mu;
    float rs  = rsqrtf(var + 1e-5f);
    float4 g = ld4(&gamma[lane * 4]);
    float4 b = ld4(&beta[lane * 4]);
    float4 o;
    o.x = fmaxf(0.f, (v.x - mu) * rs * g.x + b.x);
    o.y = fmaxf(0.f, (v.y - mu) * rs * g.y + b.y);
    o.z = fmaxf(0.f, (v.z - mu) * rs * g.z + b.z);
    o.w = fmaxf(0.f, (v.w - mu) * rs * g.w + b.w);
    st4(&io[r * D + lane * 4], o);
}

// ------------------------------------------------------------------ launch
extern "C" void kernel_launch(void* const* d_in, const int* in_sizes, int n_in,
                              void* d_out, int out_size, void* d_ws, size_t ws_size,
                              hipStream_t stream)
{
    const float* x_glom = (const float*)d_in[0];
    const float* x_imm  = (const float*)d_in[1];
    const float* ew_gg  = (const float*)d_in[2];
    const float* ea_ig  = (const float*)d_in[3];
    const float* W_gcn  = (const float*)d_in[4];
    const float* b_gcn  = (const float*)d_in[5];
    const float* Wl     = (const float*)d_in[6];
    const float* bl     = (const float*)d_in[7];
    const float* Wr     = (const float*)d_in[8];
    const float* br     = (const float*)d_in[9];
    const float* att    = (const float*)d_in[10];
    const float* We     = (const float*)d_in[11];
    const float* b_gat  = (const float*)d_in[12];
    const float* eps    = (const float*)d_in[13];
    const float* W_gin  = (const float*)d_in[14];
    const float* b_gin  = (const float*)d_in[15];
    const float* gamma  = (const float*)d_in[16];
    const float* beta   = (const float*)d_in[17];
    const int*   ei_gg  = (const int*)d_in[18];
    const int*   ei_ig  = (const int*)d_in[19];
    const int*   ei_gi  = (const int*)d_in[20];

    const int N = in_sizes[0] / D;     // 20000
    const int E = in_sizes[2];         // 320000

    // workspace layout
    float* xw     = (float*)d_ws;          // N*D
    float* hl     = xw + (size_t)N * D;    // N*D
    float* hr     = hl + (size_t)N * D;    // N*D
    float* agg    = hr + (size_t)N * D;    // N*D
    float* deg    = agg + (size_t)N * D;   // N  (becomes dinv in place)
    float* denom  = deg + N;               // N
    unsigned* mseg = (unsigned*)(denom + N); // N
    float* logits = (float*)(mseg + N);    // E
    float* exb    = logits + E;            // E

    float* glom_acc = (float*)d_out;              // N*D (pre-LN glom)
    float* imm_pre  = (float*)d_out + (size_t)N * D; // N*D (pre-LN imm)

    dim3 gemm_grid((N + 63) / 64, D / 64);
    int nb_nodes  = (N + 255) / 256;
    int nb_nd4    = (N * (D / 4) + 255) / 256;
    int nb_edge_w = (E * 64 + 255) / 256;   // wave per edge
    int nb_edge_t = (E + 255) / 256;        // thread per edge
    int nb_ln     = (2 * N * 64 + 255) / 256;

    // --- GEMMs (independent of edge work) ---
    k_gemm<<<gemm_grid, 256, 0, stream>>>(x_glom, W_gcn, nullptr, xw, N);
    k_gemm<<<gemm_grid, 256, 0, stream>>>(x_imm,  Wl,    bl,      hl, N);
    k_gemm<<<gemm_grid, 256, 0, stream>>>(x_glom, Wr,    br,      hr, N);

    // --- inits ---
    k_init_nodes<<<nb_nodes, 256, 0, stream>>>(deg, denom, mseg, N);
    k_zero4<<<nb_nd4, 256, 0, stream>>>(agg, N * (D / 4));

    // --- GCN ---
    k_deg_accum<<<nb_edge_t, 256, 0, stream>>>(ei_gg, ew_gg, deg, E);
    k_rsqrt_inplace<<<nb_nodes, 256, 0, stream>>>(deg, N);
    k_init_glom<<<nb_nd4, 256, 0, stream>>>(xw, deg, b_gcn, b_gat, glom_acc, N);
    k_gcn_edge<<<nb_edge_w, 256, 0, stream>>>(ei_gg, ew_gg, deg, xw, glom_acc, E);

    // --- GATv2 ---
    k_gat_logits<<<nb_edge_w, 256, 0, stream>>>(ei_ig, ea_ig, hl, hr, We, att,
                                                logits, mseg, E);
    k_gat_exp<<<nb_edge_t, 256, 0, stream>>>(ei_ig, logits, mseg, exb, denom, E);
    k_gat_aggr<<<nb_edge_w, 256, 0, stream>>>(ei_ig, exb, denom, hl, glom_acc, E);

    // --- GIN ---
    k_gin_edge<<<nb_edge_w, 256, 0, stream>>>(ei_gi, x_glom, agg, E);
    k_gin_in<<<nb_nd4, 256, 0, stream>>>(x_imm, eps, agg, N);
    k_gemm<<<gemm_grid, 256, 0, stream>>>(agg, W_gin, b_gin, imm_pre, N);

    // --- LayerNorm + ReLU (in place on d_out) ---
    k_ln_relu<<<nb_ln, 256, 0, stream>>>((float*)d_out, gamma, beta, 2 * N);
}

// Round 2
// 715.114 us; speedup vs baseline: 5.0610x; 5.0610x over previous
//
#include <hip/hip_runtime.h>
#include <hip/hip_bf16.h>

// HeteroMessagePassingLayer: GCN(glom->glom) + GATv2(imm->glom) + GIN(glom->imm)
// + HeteroConv(sum) + shared LayerNorm + ReLU.
// Round 2: CSR gather aggregation (no feature atomics), fused glom epilogue.

constexpr int D = 256;

// ---------------------------------------------------------------- utilities
__device__ __forceinline__ float4 ld4(const float* p) {
    return *reinterpret_cast<const float4*>(p);
}
__device__ __forceinline__ void st4(float* p, float4 v) {
    *reinterpret_cast<float4*>(p) = v;
}

// ------------------------------------------------------------------- GEMM
// C[M,256] = A[M,256] @ W[256,256] (+ bias).  64x64 tile, 4x4 microtile.
__global__ __launch_bounds__(256)
void k_gemm(const float* __restrict__ A, const float* __restrict__ W,
            const float* __restrict__ bias, float* __restrict__ C, int M)
{
    __shared__ float As[32][65];
    __shared__ float Bs[32][68];

    const int row0 = blockIdx.x * 64;
    const int col0 = blockIdx.y * 64;
    const int tid  = threadIdx.x;
    const int tx   = tid & 15;
    const int ty   = tid >> 4;

    float acc[4][4] = {};

    for (int kk = 0; kk < D; kk += 32) {
#pragma unroll
        for (int i = 0; i < 8; ++i) {           // A tile: 64 rows x 32 k
            int e = tid + i * 256;
            int r = e >> 5, k = e & 31;
            int gr = row0 + r;
            As[k][r] = (gr < M) ? A[gr * D + kk + k] : 0.f;
        }
#pragma unroll
        for (int i = 0; i < 8; ++i) {           // B tile: 32 k x 64 cols
            int e = tid + i * 256;
            int k = e >> 6, c = e & 63;
            Bs[k][c] = W[(kk + k) * D + col0 + c];
        }
        __syncthreads();
#pragma unroll
        for (int k = 0; k < 32; ++k) {
            float a0 = As[k][ty * 4 + 0];
            float a1 = As[k][ty * 4 + 1];
            float a2 = As[k][ty * 4 + 2];
            float a3 = As[k][ty * 4 + 3];
            float4 b = *reinterpret_cast<const float4*>(&Bs[k][tx * 4]);
            acc[0][0] += a0 * b.x; acc[0][1] += a0 * b.y; acc[0][2] += a0 * b.z; acc[0][3] += a0 * b.w;
            acc[1][0] += a1 * b.x; acc[1][1] += a1 * b.y; acc[1][2] += a1 * b.z; acc[1][3] += a1 * b.w;
            acc[2][0] += a2 * b.x; acc[2][1] += a2 * b.y; acc[2][2] += a2 * b.z; acc[2][3] += a2 * b.w;
            acc[3][0] += a3 * b.x; acc[3][1] += a3 * b.y; acc[3][2] += a3 * b.z; acc[3][3] += a3 * b.w;
        }
        __syncthreads();
    }

#pragma unroll
    for (int i = 0; i < 4; ++i) {
        int gr = row0 + ty * 4 + i;
        if (gr < M) {
            int gc = col0 + tx * 4;
            float4 v = make_float4(acc[i][0], acc[i][1], acc[i][2], acc[i][3]);
            if (bias) {
                v.x += bias[gc + 0]; v.y += bias[gc + 1];
                v.z += bias[gc + 2]; v.w += bias[gc + 3];
            }
            st4(&C[gr * D + gc], v);
        }
    }
}

// --------------------------------------------------------------- CSR build
__global__ void k_zero_int(int* p, int n)
{
    int i = blockIdx.x * 256 + threadIdx.x;
    if (i < n) p[i] = 0;
}

// histogram of dst for the 3 edge types
__global__ void k_hist3(const int* __restrict__ ei_gg, const int* __restrict__ ei_ig,
                        const int* __restrict__ ei_gi, int* __restrict__ counts,
                        int E, int N)
{
    int i = blockIdx.x * 256 + threadIdx.x;
    if (i >= 3 * E) return;
    int t = i / E, e = i - t * E;
    const int* ei = (t == 0) ? ei_gg : (t == 1) ? ei_ig : ei_gi;
    atomicAdd(&counts[t * N + ei[E + e]], 1);
}

// single-block exclusive scan per edge type; also fills cursor copy
__global__ __launch_bounds__(256)
void k_scan3(const int* __restrict__ counts, int* __restrict__ rows,
             int* __restrict__ cur, int N)
{
    const int t = blockIdx.x;                 // edge type 0..2
    const int* c = counts + (size_t)t * N;
    int* r = rows + (size_t)t * (N + 1);
    int* q = cur + (size_t)t * N;
    __shared__ int sh[256];
    __shared__ int carry;
    if (threadIdx.x == 0) carry = 0;
    __syncthreads();
    for (int base = 0; base < N; base += 256) {
        int i = base + threadIdx.x;
        int v = (i < N) ? c[i] : 0;
        sh[threadIdx.x] = v;
        __syncthreads();
#pragma unroll
        for (int off = 1; off < 256; off <<= 1) {
            int add = (threadIdx.x >= off) ? sh[threadIdx.x - off] : 0;
            __syncthreads();
            sh[threadIdx.x] += add;
            __syncthreads();
        }
        int excl = carry + sh[threadIdx.x] - v;
        if (i < N) { r[i] = excl; q[i] = excl; }
        __syncthreads();
        if (threadIdx.x == 255) carry += sh[255];
        __syncthreads();
    }
    if (threadIdx.x == 0) r[N] = carry;
}

// scatter edges into CSR order
__global__ void k_scatter3(const int* __restrict__ ei_gg, const int* __restrict__ ei_ig,
                           const int* __restrict__ ei_gi, const float* __restrict__ ew_gg,
                           int* __restrict__ cur,
                           int* __restrict__ src_gcn, float* __restrict__ val_gcn,
                           int* __restrict__ src_gat, int* __restrict__ eid_gat,
                           int* __restrict__ src_gin, int E, int N)
{
    int i = blockIdx.x * 256 + threadIdx.x;
    if (i >= 3 * E) return;
    int t = i / E, e = i - t * E;
    if (t == 0) {
        int s = ei_gg[e], d = ei_gg[E + e];
        int pos = atomicAdd(&cur[d], 1);
        src_gcn[pos] = s;
        val_gcn[pos] = ew_gg[e];
    } else if (t == 1) {
        int s = ei_ig[e], d = ei_ig[E + e];
        int pos = atomicAdd(&cur[N + d], 1);
        src_gat[pos] = s;
        eid_gat[pos] = e;
    } else {
        int s = ei_gi[e], d = ei_gi[E + e];
        int pos = atomicAdd(&cur[2 * N + d], 1);
        src_gin[pos] = s;
    }
}

// dinv[i] = rsqrt(1 + sum of incoming edge weights)    (GCN gcn_norm)
__global__ void k_dinv(const int* __restrict__ rows, const float* __restrict__ val,
                       float* __restrict__ dinv, int N)
{
    int i = blockIdx.x * 256 + threadIdx.x;
    if (i >= N) return;
    float s = 1.0f;
    int p1 = rows[i + 1];
    for (int p = rows[i]; p < p1; ++p) s += val[p];
    dinv[i] = rsqrtf(s);
}

// ------------------------------------------------------------- GAT logits
__global__ __launch_bounds__(256)
void k_gat_logits(const int* __restrict__ ei, const float* __restrict__ ea,
                  const float* __restrict__ hl, const float* __restrict__ hr,
                  const float* __restrict__ We, const float* __restrict__ att,
                  float* __restrict__ logits, int E)
{
    int e    = (blockIdx.x * 256 + threadIdx.x) >> 6;   // one wave per edge
    int lane = threadIdx.x & 63;
    if (e >= E) return;
    int s = ei[e], d = ei[E + e];
    float eav = ea[e];
    float4 a = ld4(&hl[s * D + lane * 4]);
    float4 b = ld4(&hr[d * D + lane * 4]);
    float4 w = ld4(&We[lane * 4]);
    float4 t = ld4(&att[lane * 4]);

    float z, p = 0.f;
    z = a.x + b.x + eav * w.x; z = (z > 0.f) ? z : 0.2f * z; p += z * t.x;
    z = a.y + b.y + eav * w.y; z = (z > 0.f) ? z : 0.2f * z; p += z * t.y;
    z = a.z + b.z + eav * w.z; z = (z > 0.f) ? z : 0.2f * z; p += z * t.z;
    z = a.w + b.w + eav * w.w; z = (z > 0.f) ? z : 0.2f * z; p += z * t.w;

#pragma unroll
    for (int off = 32; off > 0; off >>= 1) p += __shfl_xor(p, off, 64);

    if (lane == 0) logits[e] = p;
}

// ------------------------- fused glom: GCN aggr + GAT softmax/aggr + LN+ReLU
__global__ __launch_bounds__(256)
void k_glom_fused(const float* __restrict__ xw, const float* __restrict__ hl,
                  const float* __restrict__ dinv,
                  const int* __restrict__ rows_gcn, const int* __restrict__ src_gcn,
                  const float* __restrict__ val_gcn,
                  const int* __restrict__ rows_gat, const int* __restrict__ src_gat,
                  const int* __restrict__ eid_gat, const float* __restrict__ logits,
                  const float* __restrict__ b_gcn, const float* __restrict__ b_gat,
                  const float* __restrict__ gamma, const float* __restrict__ beta,
                  float* __restrict__ out, int N)
{
    int node = (blockIdx.x * 256 + threadIdx.x) >> 6;    // one wave per node
    int lane = threadIdx.x & 63;
    if (node >= N) return;

    float di = dinv[node];
    float sc = di * di;
    float4 acc = ld4(&xw[node * D + lane * 4]);
    float4 g0  = ld4(&b_gcn[lane * 4]);
    float4 a0  = ld4(&b_gat[lane * 4]);
    acc.x = sc * acc.x + g0.x + a0.x;
    acc.y = sc * acc.y + g0.y + a0.y;
    acc.z = sc * acc.z + g0.z + a0.z;
    acc.w = sc * acc.w + g0.w + a0.w;

    // ---- GCN neighbor sum ----
    int p1 = rows_gcn[node + 1];
    for (int p = rows_gcn[node]; p < p1; ++p) {
        int s = src_gcn[p];
        float coef = dinv[s] * val_gcn[p] * di;
        float4 v = ld4(&xw[s * D + lane * 4]);
        acc.x += coef * v.x; acc.y += coef * v.y;
        acc.z += coef * v.z; acc.w += coef * v.w;
    }

    // ---- GAT softmax + weighted sum ----
    int q0 = rows_gat[node], q1 = rows_gat[node + 1];
    if (q1 > q0) {
        float m = -3.4e38f;
        for (int q = q0; q < q1; ++q) m = fmaxf(m, logits[eid_gat[q]]);
        float4 a2 = make_float4(0.f, 0.f, 0.f, 0.f);
        float den = 0.f;
        for (int q = q0; q < q1; ++q) {
            float ex = __expf(logits[eid_gat[q]] - m);
            den += ex;
            int s = src_gat[q];
            float4 v = ld4(&hl[s * D + lane * 4]);
            a2.x += ex * v.x; a2.y += ex * v.y;
            a2.z += ex * v.z; a2.w += ex * v.w;
        }
        float inv = 1.0f / den;
        acc.x += a2.x * inv; acc.y += a2.y * inv;
        acc.z += a2.z * inv; acc.w += a2.w * inv;
    }

    // ---- LayerNorm + ReLU ----
    float s_  = acc.x + acc.y + acc.z + acc.w;
    float sq  = acc.x * acc.x + acc.y * acc.y + acc.z * acc.z + acc.w * acc.w;
#pragma unroll
    for (int off = 32; off > 0; off >>= 1) {
        s_ += __shfl_xor(s_, off, 64);
        sq += __shfl_xor(sq, off, 64);
    }
    float mu  = s_ * (1.0f / 256.0f);
    float var = sq * (1.0f / 256.0f) - mu * mu;
    float rs  = rsqrtf(var + 1e-5f);
    float4 g = ld4(&gamma[lane * 4]);
    float4 b = ld4(&beta[lane * 4]);
    float4 o;
    o.x = fmaxf(0.f, (acc.x - mu) * rs * g.x + b.x);
    o.y = fmaxf(0.f, (acc.y - mu) * rs * g.y + b.y);
    o.z = fmaxf(0.f, (acc.z - mu) * rs * g.z + b.z);
    o.w = fmaxf(0.f, (acc.w - mu) * rs * g.w + b.w);
    st4(&out[node * D + lane * 4], o);
}

// --------------------------- GIN gather: agg = (1+eps)*x_imm + sum x_glom[s]
__global__ __launch_bounds__(256)
void k_gin_gather(const float* __restrict__ x_glom, const float* __restrict__ x_imm,
                  const float* __restrict__ eps,
                  const int* __restrict__ rows, const int* __restrict__ src,
                  float* __restrict__ agg, int N)
{
    int node = (blockIdx.x * 256 + threadIdx.x) >> 6;
    int lane = threadIdx.x & 63;
    if (node >= N) return;
    float c = 1.0f + eps[0];
    float4 acc = ld4(&x_imm[node * D + lane * 4]);
    acc.x *= c; acc.y *= c; acc.z *= c; acc.w *= c;
    int p1 = rows[node + 1];
    for (int p = rows[node]; p < p1; ++p) {
        int s = src[p];
        float4 v = ld4(&x_glom[s * D + lane * 4]);
        acc.x += v.x; acc.y += v.y; acc.z += v.z; acc.w += v.w;
    }
    st4(&agg[node * D + lane * 4], acc);
}

// -------------------------------------------------------- LayerNorm+ReLU
__global__ __launch_bounds__(256)
void k_ln_relu(float* __restrict__ io, const float* __restrict__ gamma,
               const float* __restrict__ beta, int rows)
{
    int r    = (blockIdx.x * 256 + threadIdx.x) >> 6;
    int lane = threadIdx.x & 63;
    if (r >= rows) return;
    float4 v = ld4(&io[r * D + lane * 4]);
    float s  = v.x + v.y + v.z + v.w;
    float sq = v.x * v.x + v.y * v.y + v.z * v.z + v.w * v.w;
#pragma unroll
    for (int off = 32; off > 0; off >>= 1) {
        s  += __shfl_xor(s, off, 64);
        sq += __shfl_xor(sq, off, 64);
    }
    float mu  = s * (1.0f / 256.0f);
    float var = sq * (1.0f / 256.0f) - mu * mu;
    float rs  = rsqrtf(var + 1e-5f);
    float4 g = ld4(&gamma[lane * 4]);
    float4 b = ld4(&beta[lane * 4]);
    float4 o;
    o.x = fmaxf(0.f, (v.x - mu) * rs * g.x + b.x);
    o.y = fmaxf(0.f, (v.y - mu) * rs * g.y + b.y);
    o.z = fmaxf(0.f, (v.z - mu) * rs * g.z + b.z);
    o.w = fmaxf(0.f, (v.w - mu) * rs * g.w + b.w);
    st4(&io[r * D + lane * 4], o);
}

// ------------------------------------------------------------------ launch
extern "C" void kernel_launch(void* const* d_in, const int* in_sizes, int n_in,
                              void* d_out, int out_size, void* d_ws, size_t ws_size,
                              hipStream_t stream)
{
    const float* x_glom = (const float*)d_in[0];
    const float* x_imm  = (const float*)d_in[1];
    const float* ew_gg  = (const float*)d_in[2];
    const float* ea_ig  = (const float*)d_in[3];
    const float* W_gcn  = (const float*)d_in[4];
    const float* b_gcn  = (const float*)d_in[5];
    const float* Wl     = (const float*)d_in[6];
    const float* bl     = (const float*)d_in[7];
    const float* Wr     = (const float*)d_in[8];
    const float* br     = (const float*)d_in[9];
    const float* att    = (const float*)d_in[10];
    const float* We     = (const float*)d_in[11];
    const float* b_gat  = (const float*)d_in[12];
    const float* eps    = (const float*)d_in[13];
    const float* W_gin  = (const float*)d_in[14];
    const float* b_gin  = (const float*)d_in[15];
    const float* gamma  = (const float*)d_in[16];
    const float* beta   = (const float*)d_in[17];
    const int*   ei_gg  = (const int*)d_in[18];
    const int*   ei_ig  = (const int*)d_in[19];
    const int*   ei_gi  = (const int*)d_in[20];

    const int N = in_sizes[0] / D;     // 20000
    const int E = in_sizes[2];         // 320000

    // ---- workspace layout ----
    float* xw      = (float*)d_ws;               // N*D
    float* hl      = xw + (size_t)N * D;         // N*D
    float* hr      = hl + (size_t)N * D;         // N*D (reused as agg after logits)
    float* dinv    = hr + (size_t)N * D;         // N
    float* logits  = dinv + N;                   // E
    int*   counts  = (int*)(logits + E);         // 3N
    int*   rows    = counts + 3 * N;             // 3(N+1)
    int*   cur     = rows + 3 * (N + 1);         // 3N
    int*   src_gcn = cur + 3 * N;                // E
    float* val_gcn = (float*)(src_gcn + E);      // E
    int*   src_gat = (int*)(val_gcn + E);        // E
    int*   eid_gat = src_gat + E;                // E
    int*   src_gin = eid_gat + E;                // E
    float* agg     = hr;                         // alias (hr dead after logits)

    float* glom_out = (float*)d_out;                    // N*D
    float* imm_pre  = (float*)d_out + (size_t)N * D;    // N*D

    dim3 gemm_grid((N + 63) / 64, D / 64);
    int nb_3n    = (3 * N + 255) / 256;
    int nb_nodes = (N + 255) / 256;
    int nb_3e    = (3 * E + 255) / 256;
    int nb_ew    = (E * 64 + 255) / 256;      // wave per edge
    int nb_nw    = (N * 64 + 255) / 256;      // wave per node
    int nb_lni   = (N * 64 + 255) / 256;

    // --- GEMMs (projections) ---
    k_gemm<<<gemm_grid, 256, 0, stream>>>(x_glom, W_gcn, nullptr, xw, N);
    k_gemm<<<gemm_grid, 256, 0, stream>>>(x_imm,  Wl,    bl,      hl, N);
    k_gemm<<<gemm_grid, 256, 0, stream>>>(x_glom, Wr,    br,      hr, N);

    // --- CSR build for all 3 edge types ---
    k_zero_int<<<nb_3n, 256, 0, stream>>>(counts, 3 * N);
    k_hist3<<<nb_3e, 256, 0, stream>>>(ei_gg, ei_ig, ei_gi, counts, E, N);
    k_scan3<<<3, 256, 0, stream>>>(counts, rows, cur, N);
    k_scatter3<<<nb_3e, 256, 0, stream>>>(ei_gg, ei_ig, ei_gi, ew_gg, cur,
                                          src_gcn, val_gcn, src_gat, eid_gat,
                                          src_gin, E, N);

    // --- GCN degree norm ---
    k_dinv<<<nb_nodes, 256, 0, stream>>>(rows, val_gcn, dinv, N);

    // --- GAT logits (needs hl, hr) ---
    k_gat_logits<<<nb_ew, 256, 0, stream>>>(ei_ig, ea_ig, hl, hr, We, att,
                                            logits, E);

    // --- fused glom: GCN aggr + GAT softmax/aggr + LN + ReLU ---
    k_glom_fused<<<nb_nw, 256, 0, stream>>>(xw, hl, dinv,
                                            rows, src_gcn, val_gcn,
                                            rows + (N + 1), src_gat, eid_gat, logits,
                                            b_gcn, b_gat, gamma, beta,
                                            glom_out, N);

    // --- GIN: gather (into agg = old hr) + GEMM + LN ---
    k_gin_gather<<<nb_nw, 256, 0, stream>>>(x_glom, x_imm, eps,
                                            rows + 2 * (N + 1), src_gin, agg, N);
    k_gemm<<<gemm_grid, 256, 0, stream>>>(agg, W_gin, b_gin, imm_pre, N);
    k_ln_relu<<<nb_lni, 256, 0, stream>>>(imm_pre, gamma, beta, N);
}

// Round 3
// 473.258 us; speedup vs baseline: 7.6474x; 1.5110x over previous
//
#include <hip/hip_runtime.h>

// HeteroMessagePassingLayer Round 3:
//  - bf16 gathered feature tables (halve random-gather bytes)
//  - GATv2 logits fused into glom kernel via online softmax (kills k_gat_logits)
//  - MFMA bf16 GEMMs (16x16x32), W pre-transposed to [N][K]

constexpr int D = 256;

typedef __attribute__((ext_vector_type(4))) float f32x4v;
typedef __attribute__((ext_vector_type(8))) short short8;

// ---------------------------------------------------------------- utilities
__device__ __forceinline__ float4 ld4(const float* p) {
    return *reinterpret_cast<const float4*>(p);
}
__device__ __forceinline__ void st4(float* p, float4 v) {
    *reinterpret_cast<float4*>(p) = v;
}
__device__ __forceinline__ unsigned short f2bf(float f) {
    unsigned u = __float_as_uint(f);
    u = u + 0x7FFFu + ((u >> 16) & 1u);     // round-to-nearest-even
    return (unsigned short)(u >> 16);
}
__device__ __forceinline__ float bf2f(unsigned short u) {
    return __uint_as_float(((unsigned)u) << 16);
}
// load 4 consecutive bf16 -> float4
__device__ __forceinline__ float4 ldb4(const unsigned short* p) {
    ushort4 u = *reinterpret_cast<const ushort4*>(p);
    return make_float4(bf2f(u.x), bf2f(u.y), bf2f(u.z), bf2f(u.w));
}

// ------------------------------------------------------------- cast f32->bf16
__global__ void k_cast(const float* __restrict__ x, unsigned short* __restrict__ y,
                       int n4)
{
    int i = blockIdx.x * 256 + threadIdx.x;
    if (i >= n4) return;
    float4 v = ld4(x + (size_t)i * 4);
    ushort4 o;
    o.x = f2bf(v.x); o.y = f2bf(v.y); o.z = f2bf(v.z); o.w = f2bf(v.w);
    *reinterpret_cast<ushort4*>(y + (size_t)i * 4) = o;
}

// ----------------------------------------------- W[K][N] -> Wt[N][K] in bf16
__global__ void k_prep_wt(const float* __restrict__ W, unsigned short* __restrict__ Wt)
{
    int i = blockIdx.x * 256 + threadIdx.x;     // 65536 elements
    int c = i >> 8, k = i & 255;
    Wt[i] = f2bf(W[k * D + c]);
}

// ------------------------------------------------------------- MFMA GEMM
// C[M,256] = A[M,256](bf16) @ W(bf16, pre-transposed Bt[N][K]) + bias
// block = 4 waves; wave computes 16 rows x 64 cols of C.
template<int OUTBF>
__global__ __launch_bounds__(256)
void k_gemm_mfma(const unsigned short* __restrict__ A,
                 const unsigned short* __restrict__ Bt,
                 const float* __restrict__ bias, void* __restrict__ Cout, int M)
{
    const int lane = threadIdx.x & 63;
    const int wave = threadIdx.x >> 6;
    const int lr = lane & 15;        // fragment row (A) / col (B) / col (C)
    const int lk = lane >> 4;        // k-group
    const int row0 = blockIdx.x * 64 + wave * 16;
    const int col0 = blockIdx.y * 64;

    int arow = row0 + lr;
    int arow_c = (arow < M) ? arow : (M - 1);
    const unsigned short* ap = A + (size_t)arow_c * D + lk * 8;
    const unsigned short* bp = Bt + (size_t)(col0 + lr) * D + lk * 8;

    f32x4v acc[4] = {};

#pragma unroll
    for (int k0 = 0; k0 < 256; k0 += 32) {
        short8 af = *reinterpret_cast<const short8*>(ap + k0);
#pragma unroll
        for (int nf = 0; nf < 4; ++nf) {
            short8 bf = *reinterpret_cast<const short8*>(bp + (size_t)nf * 16 * D + k0);
            acc[nf] = __builtin_amdgcn_mfma_f32_16x16x32_bf16(af, bf, acc[nf], 0, 0, 0);
        }
    }

#pragma unroll
    for (int nf = 0; nf < 4; ++nf) {
        int c = col0 + nf * 16 + lr;
        float bv = bias ? bias[c] : 0.f;
#pragma unroll
        for (int i = 0; i < 4; ++i) {
            int r = row0 + 4 * lk + i;
            if (r < M) {
                float v = acc[nf][i] + bv;
                if (OUTBF)
                    ((unsigned short*)Cout)[(size_t)r * D + c] = f2bf(v);
                else
                    ((float*)Cout)[(size_t)r * D + c] = v;
            }
        }
    }
}

// --------------------------------------------------------------- CSR build
__global__ void k_zero_int(int* p, int n)
{
    int i = blockIdx.x * 256 + threadIdx.x;
    if (i < n) p[i] = 0;
}

__global__ void k_hist3(const int* __restrict__ ei_gg, const int* __restrict__ ei_ig,
                        const int* __restrict__ ei_gi, int* __restrict__ counts,
                        int E, int N)
{
    int i = blockIdx.x * 256 + threadIdx.x;
    if (i >= 3 * E) return;
    int t = i / E, e = i - t * E;
    const int* ei = (t == 0) ? ei_gg : (t == 1) ? ei_ig : ei_gi;
    atomicAdd(&counts[t * N + ei[E + e]], 1);
}

__global__ __launch_bounds__(256)
void k_scan3(const int* __restrict__ counts, int* __restrict__ rows,
             int* __restrict__ cur, int N)
{
    const int t = blockIdx.x;
    const int* c = counts + (size_t)t * N;
    int* r = rows + (size_t)t * (N + 1);
    int* q = cur + (size_t)t * N;
    __shared__ int sh[256];
    __shared__ int carry;
    if (threadIdx.x == 0) carry = 0;
    __syncthreads();
    for (int base = 0; base < N; base += 256) {
        int i = base + threadIdx.x;
        int v = (i < N) ? c[i] : 0;
        sh[threadIdx.x] = v;
        __syncthreads();
#pragma unroll
        for (int off = 1; off < 256; off <<= 1) {
            int add = (threadIdx.x >= off) ? sh[threadIdx.x - off] : 0;
            __syncthreads();
            sh[threadIdx.x] += add;
            __syncthreads();
        }
        int excl = carry + sh[threadIdx.x] - v;
        if (i < N) { r[i] = excl; q[i] = excl; }
        __syncthreads();
        if (threadIdx.x == 255) carry += sh[255];
        __syncthreads();
    }
    if (threadIdx.x == 0) r[N] = carry;
}

__global__ void k_scatter3(const int* __restrict__ ei_gg, const int* __restrict__ ei_ig,
                           const int* __restrict__ ei_gi, const float* __restrict__ ew_gg,
                           const float* __restrict__ ea_ig, int* __restrict__ cur,
                           int* __restrict__ src_gcn, float* __restrict__ val_gcn,
                           int* __restrict__ src_gat, float* __restrict__ val_gat,
                           int* __restrict__ src_gin, int E, int N)
{
    int i = blockIdx.x * 256 + threadIdx.x;
    if (i >= 3 * E) return;
    int t = i / E, e = i - t * E;
    if (t == 0) {
        int s = ei_gg[e], d = ei_gg[E + e];
        int pos = atomicAdd(&cur[d], 1);
        src_gcn[pos] = s;
        val_gcn[pos] = ew_gg[e];
    } else if (t == 1) {
        int s = ei_ig[e], d = ei_ig[E + e];
        int pos = atomicAdd(&cur[N + d], 1);
        src_gat[pos] = s;
        val_gat[pos] = ea_ig[e];
    } else {
        int s = ei_gi[e], d = ei_gi[E + e];
        int pos = atomicAdd(&cur[2 * N + d], 1);
        src_gin[pos] = s;
    }
}

// dinv[i] = rsqrt(1 + sum of incoming edge weights)
__global__ void k_dinv(const int* __restrict__ rows, const float* __restrict__ val,
                       float* __restrict__ dinv, int N)
{
    int i = blockIdx.x * 256 + threadIdx.x;
    if (i >= N) return;
    float s = 1.0f;
    int p1 = rows[i + 1];
    for (int p = rows[i]; p < p1; ++p) s += val[p];
    dinv[i] = rsqrtf(s);
}

// ---- fused glom: GCN aggr + GATv2 logits + online softmax aggr + LN + ReLU
__global__ __launch_bounds__(256)
void k_glom_fused(const unsigned short* __restrict__ xw,
                  const unsigned short* __restrict__ hl,
                  const unsigned short* __restrict__ hr,
                  const float* __restrict__ dinv,
                  const int* __restrict__ rows_gcn, const int* __restrict__ src_gcn,
                  const float* __restrict__ val_gcn,
                  const int* __restrict__ rows_gat, const int* __restrict__ src_gat,
                  const float* __restrict__ val_gat,
                  const float* __restrict__ We, const float* __restrict__ att,
                  const float* __restrict__ b_gcn, const float* __restrict__ b_gat,
                  const float* __restrict__ gamma, const float* __restrict__ beta,
                  float* __restrict__ out, int N)
{
    int node = (blockIdx.x * 256 + threadIdx.x) >> 6;    // one wave per node
    int lane = threadIdx.x & 63;
    if (node >= N) return;

    float4 We4  = ld4(&We[lane * 4]);
    float4 att4 = ld4(&att[lane * 4]);
    float4 hrv  = ldb4(&hr[(size_t)node * D + lane * 4]);

    float di = dinv[node];
    float sc = di * di;
    float4 acc = ldb4(&xw[(size_t)node * D + lane * 4]);
    float4 g0  = ld4(&b_gcn[lane * 4]);
    float4 a0  = ld4(&b_gat[lane * 4]);
    acc.x = sc * acc.x + g0.x + a0.x;
    acc.y = sc * acc.y + g0.y + a0.y;
    acc.z = sc * acc.z + g0.z + a0.z;
    acc.w = sc * acc.w + g0.w + a0.w;

    // ---- GCN neighbor sum ----
    int p1 = rows_gcn[node + 1];
    for (int p = rows_gcn[node]; p < p1; ++p) {
        int s = src_gcn[p];
        float coef = dinv[s] * val_gcn[p] * di;
        float4 v = ldb4(&xw[(size_t)s * D + lane * 4]);
        acc.x += coef * v.x; acc.y += coef * v.y;
        acc.z += coef * v.z; acc.w += coef * v.w;
    }

    // ---- GATv2: logits + online softmax + weighted sum (single pass) ----
    int q0 = rows_gat[node], q1 = rows_gat[node + 1];
    if (q1 > q0) {
        float m = -3.4e38f, den = 0.f;
        float4 ag = make_float4(0.f, 0.f, 0.f, 0.f);
        for (int q = q0; q < q1; ++q) {
            int s = src_gat[q];
            float eav = val_gat[q];
            float4 h = ldb4(&hl[(size_t)s * D + lane * 4]);
            float z, p = 0.f;
            z = h.x + hrv.x + eav * We4.x; z = fmaxf(z, 0.f) + 0.2f * fminf(z, 0.f); p += z * att4.x;
            z = h.y + hrv.y + eav * We4.y; z = fmaxf(z, 0.f) + 0.2f * fminf(z, 0.f); p += z * att4.y;
            z = h.z + hrv.z + eav * We4.z; z = fmaxf(z, 0.f) + 0.2f * fminf(z, 0.f); p += z * att4.z;
            z = h.w + hrv.w + eav * We4.w; z = fmaxf(z, 0.f) + 0.2f * fminf(z, 0.f); p += z * att4.w;
#pragma unroll
            for (int off = 32; off > 0; off >>= 1) p += __shfl_xor(p, off, 64);
            // online softmax update (p uniform across wave)
            if (p > m) {
                float cx = __expf(m - p);
                den *= cx;
                ag.x *= cx; ag.y *= cx; ag.z *= cx; ag.w *= cx;
                m = p;
            }
            float ex = __expf(p - m);
            den += ex;
            ag.x += ex * h.x; ag.y += ex * h.y;
            ag.z += ex * h.z; ag.w += ex * h.w;
        }
        float inv = 1.0f / den;
        acc.x += ag.x * inv; acc.y += ag.y * inv;
        acc.z += ag.z * inv; acc.w += ag.w * inv;
    }

    // ---- LayerNorm + ReLU ----
    float s_ = acc.x + acc.y + acc.z + acc.w;
    float sq = acc.x * acc.x + acc.y * acc.y + acc.z * acc.z + acc.w * acc.w;
#pragma unroll
    for (int off = 32; off > 0; off >>= 1) {
        s_ += __shfl_xor(s_, off, 64);
        sq += __shfl_xor(sq, off, 64);
    }
    float mu  = s_ * (1.0f / 256.0f);
    float var = sq * (1.0f / 256.0f) - mu * mu;
    float rs  = rsqrtf(var + 1e-5f);
    float4 g = ld4(&gamma[lane * 4]);
    float4 b = ld4(&beta[lane * 4]);
    float4 o;
    o.x = fmaxf(0.f, (acc.x - mu) * rs * g.x + b.x);
    o.y = fmaxf(0.f, (acc.y - mu) * rs * g.y + b.y);
    o.z = fmaxf(0.f, (acc.z - mu) * rs * g.z + b.z);
    o.w = fmaxf(0.f, (acc.w - mu) * rs * g.w + b.w);
    st4(&out[(size_t)node * D + lane * 4], o);
}

// ---- GIN gather: agg_b = bf16( (1+eps)*x_imm + sum x_glom[s] )
__global__ __launch_bounds__(256)
void k_gin_gather(const unsigned short* __restrict__ xb_glom,
                  const float* __restrict__ x_imm, const float* __restrict__ eps,
                  const int* __restrict__ rows, const int* __restrict__ src,
                  unsigned short* __restrict__ agg, int N)
{
    int node = (blockIdx.x * 256 + threadIdx.x) >> 6;
    int lane = threadIdx.x & 63;
    if (node >= N) return;
    float c = 1.0f + eps[0];
    float4 acc = ld4(&x_imm[(size_t)node * D + lane * 4]);
    acc.x *= c; acc.y *= c; acc.z *= c; acc.w *= c;
    int p1 = rows[node + 1];
    for (int p = rows[node]; p < p1; ++p) {
        int s = src[p];
        float4 v = ldb4(&xb_glom[(size_t)s * D + lane * 4]);
        acc.x += v.x; acc.y += v.y; acc.z += v.z; acc.w += v.w;
    }
    ushort4 o;
    o.x = f2bf(acc.x); o.y = f2bf(acc.y); o.z = f2bf(acc.z); o.w = f2bf(acc.w);
    *reinterpret_cast<ushort4*>(agg + (size_t)node * D + lane * 4) = o;
}

// -------------------------------------------------------- LayerNorm+ReLU
__global__ __launch_bounds__(256)
void k_ln_relu(float* __restrict__ io, const float* __restrict__ gamma,
               const float* __restrict__ beta, int rows)
{
    int r    = (blockIdx.x * 256 + threadIdx.x) >> 6;
    int lane = threadIdx.x & 63;
    if (r >= rows) return;
    float4 v = ld4(&io[(size_t)r * D + lane * 4]);
    float s  = v.x + v.y + v.z + v.w;
    float sq = v.x * v.x + v.y * v.y + v.z * v.z + v.w * v.w;
#pragma unroll
    for (int off = 32; off > 0; off >>= 1) {
        s  += __shfl_xor(s, off, 64);
        sq += __shfl_xor(sq, off, 64);
    }
    float mu  = s * (1.0f / 256.0f);
    float var = sq * (1.0f / 256.0f) - mu * mu;
    float rs  = rsqrtf(var + 1e-5f);
    float4 g = ld4(&gamma[lane * 4]);
    float4 b = ld4(&beta[lane * 4]);
    float4 o;
    o.x = fmaxf(0.f, (v.x - mu) * rs * g.x + b.x);
    o.y = fmaxf(0.f, (v.y - mu) * rs * g.y + b.y);
    o.z = fmaxf(0.f, (v.z - mu) * rs * g.z + b.z);
    o.w = fmaxf(0.f, (v.w - mu) * rs * g.w + b.w);
    st4(&io[(size_t)r * D + lane * 4], o);
}

// ------------------------------------------------------------------ launch
extern "C" void kernel_launch(void* const* d_in, const int* in_sizes, int n_in,
                              void* d_out, int out_size, void* d_ws, size_t ws_size,
                              hipStream_t stream)
{
    const float* x_glom = (const float*)d_in[0];
    const float* x_imm  = (const float*)d_in[1];
    const float* ew_gg  = (const float*)d_in[2];
    const float* ea_ig  = (const float*)d_in[3];
    const float* W_gcn  = (const float*)d_in[4];
    const float* b_gcn  = (const float*)d_in[5];
    const float* Wl     = (const float*)d_in[6];
    const float* bl     = (const float*)d_in[7];
    const float* Wr     = (const float*)d_in[8];
    const float* br     = (const float*)d_in[9];
    const float* att    = (const float*)d_in[10];
    const float* We     = (const float*)d_in[11];
    const float* b_gat  = (const float*)d_in[12];
    const float* eps    = (const float*)d_in[13];
    const float* W_gin  = (const float*)d_in[14];
    const float* b_gin  = (const float*)d_in[15];
    const float* gamma  = (const float*)d_in[16];
    const float* beta   = (const float*)d_in[17];
    const int*   ei_gg  = (const int*)d_in[18];
    const int*   ei_ig  = (const int*)d_in[19];
    const int*   ei_gi  = (const int*)d_in[20];

    const int N = in_sizes[0] / D;     // 20000
    const int E = in_sizes[2];         // 320000
    const size_t ND = (size_t)N * D;

    // ---- workspace layout (bytes, 256-aligned chunks) ----
    char* base = (char*)d_ws;
    size_t off = 0;
    auto alloc = [&](size_t bytes) {
        void* p = base + off;
        off = (off + bytes + 255) & ~(size_t)255;
        return p;
    };
    unsigned short* xb_glom = (unsigned short*)alloc(ND * 2);
    unsigned short* xb_imm  = (unsigned short*)alloc(ND * 2);
    unsigned short* xw_b    = (unsigned short*)alloc(ND * 2);
    unsigned short* hl_b    = (unsigned short*)alloc(ND * 2);
    unsigned short* hr_b    = (unsigned short*)alloc(ND * 2);
    unsigned short* agg_b   = (unsigned short*)alloc(ND * 2);
    unsigned short* Wt0     = (unsigned short*)alloc(D * D * 2);
    unsigned short* Wt1     = (unsigned short*)alloc(D * D * 2);
    unsigned short* Wt2     = (unsigned short*)alloc(D * D * 2);
    unsigned short* Wt3     = (unsigned short*)alloc(D * D * 2);
    float* dinv    = (float*)alloc(N * 4);
    float* val_gcn = (float*)alloc(E * 4);
    float* val_gat = (float*)alloc(E * 4);
    int*   counts  = (int*)alloc(3 * N * 4);
    int*   rows    = (int*)alloc(3 * (N + 1) * 4);
    int*   cur     = (int*)alloc(3 * N * 4);
    int*   src_gcn = (int*)alloc(E * 4);
    int*   src_gat = (int*)alloc(E * 4);
    int*   src_gin = (int*)alloc(E * 4);

    float* glom_out = (float*)d_out;                    // N*D
    float* imm_pre  = (float*)d_out + ND;               // N*D

    dim3 gemm_grid((N + 63) / 64, 4);
    int nb_cast  = (int)((ND / 4 + 255) / 256);
    int nb_wt    = (D * D + 255) / 256;
    int nb_3n    = (3 * N + 255) / 256;
    int nb_nodes = (N + 255) / 256;
    int nb_3e    = (3 * E + 255) / 256;
    int nb_nw    = (N * 64 + 255) / 256;      // wave per node

    // --- prep: casts + W transposes ---
    k_cast<<<nb_cast, 256, 0, stream>>>(x_glom, xb_glom, (int)(ND / 4));
    k_cast<<<nb_cast, 256, 0, stream>>>(x_imm,  xb_imm,  (int)(ND / 4));
    k_prep_wt<<<nb_wt, 256, 0, stream>>>(W_gcn, Wt0);
    k_prep_wt<<<nb_wt, 256, 0, stream>>>(Wl,    Wt1);
    k_prep_wt<<<nb_wt, 256, 0, stream>>>(Wr,    Wt2);
    k_prep_wt<<<nb_wt, 256, 0, stream>>>(W_gin, Wt3);

    // --- CSR build ---
    k_zero_int<<<nb_3n, 256, 0, stream>>>(counts, 3 * N);
    k_hist3<<<nb_3e, 256, 0, stream>>>(ei_gg, ei_ig, ei_gi, counts, E, N);
    k_scan3<<<3, 256, 0, stream>>>(counts, rows, cur, N);
    k_scatter3<<<nb_3e, 256, 0, stream>>>(ei_gg, ei_ig, ei_gi, ew_gg, ea_ig, cur,
                                          src_gcn, val_gcn, src_gat, val_gat,
                                          src_gin, E, N);

    // --- projections (MFMA bf16) ---
    k_gemm_mfma<1><<<gemm_grid, 256, 0, stream>>>(xb_glom, Wt0, nullptr, xw_b, N);
    k_gemm_mfma<1><<<gemm_grid, 256, 0, stream>>>(xb_imm,  Wt1, bl,      hl_b, N);
    k_gemm_mfma<1><<<gemm_grid, 256, 0, stream>>>(xb_glom, Wt2, br,      hr_b, N);

    // --- GCN degree norm ---
    k_dinv<<<nb_nodes, 256, 0, stream>>>(rows, val_gcn, dinv, N);

    // --- fused glom: GCN + GATv2(online softmax) + LN + ReLU ---
    k_glom_fused<<<nb_nw, 256, 0, stream>>>(xw_b, hl_b, hr_b, dinv,
                                            rows, src_gcn, val_gcn,
                                            rows + (N + 1), src_gat, val_gat,
                                            We, att, b_gcn, b_gat, gamma, beta,
                                            glom_out, N);

    // --- GIN: gather + MFMA GEMM + LN ---
    k_gin_gather<<<nb_nw, 256, 0, stream>>>(xb_glom, x_imm, eps,
                                            rows + 2 * (N + 1), src_gin, agg_b, N);
    k_gemm_mfma<0><<<gemm_grid, 256, 0, stream>>>(agg_b, Wt3, b_gin, imm_pre, N);
    k_ln_relu<<<nb_nw, 256, 0, stream>>>(imm_pre, gamma, beta, N);
}

// Round 4
// 342.165 us; speedup vs baseline: 10.5773x; 1.3831x over previous
//
#include <hip/hip_runtime.h>

// HeteroMessagePassingLayer Round 4:
//  - 4x unrolled gather loops (independent loads + pipelined shuffle reduces)
//  - parallel 3-kernel deterministic CSR scan (was 3-block serial scan)
//  - merged prep launches

constexpr int D = 256;

typedef __attribute__((ext_vector_type(4))) float f32x4v;
typedef __attribute__((ext_vector_type(8))) short short8;

// ---------------------------------------------------------------- utilities
__device__ __forceinline__ float4 ld4(const float* p) {
    return *reinterpret_cast<const float4*>(p);
}
__device__ __forceinline__ void st4(float* p, float4 v) {
    *reinterpret_cast<float4*>(p) = v;
}
__device__ __forceinline__ unsigned short f2bf(float f) {
    unsigned u = __float_as_uint(f);
    u = u + 0x7FFFu + ((u >> 16) & 1u);
    return (unsigned short)(u >> 16);
}
__device__ __forceinline__ float bf2f(unsigned short u) {
    return __uint_as_float(((unsigned)u) << 16);
}
__device__ __forceinline__ float4 ldb4(const unsigned short* p) {
    ushort4 u = *reinterpret_cast<const ushort4*>(p);
    return make_float4(bf2f(u.x), bf2f(u.y), bf2f(u.z), bf2f(u.w));
}
__device__ __forceinline__ float wave_sum(float p) {
#pragma unroll
    for (int off = 32; off > 0; off >>= 1) p += __shfl_xor(p, off, 64);
    return p;
}
__device__ __forceinline__ float gat_partial(float4 h, float4 hrv, float ea,
                                             float4 We4, float4 att4) {
    float z, pp = 0.f;
    z = h.x + hrv.x + ea * We4.x; z = fmaxf(z, 0.f) + 0.2f * fminf(z, 0.f); pp += z * att4.x;
    z = h.y + hrv.y + ea * We4.y; z = fmaxf(z, 0.f) + 0.2f * fminf(z, 0.f); pp += z * att4.y;
    z = h.z + hrv.z + ea * We4.z; z = fmaxf(z, 0.f) + 0.2f * fminf(z, 0.f); pp += z * att4.z;
    z = h.w + hrv.w + ea * We4.w; z = fmaxf(z, 0.f) + 0.2f * fminf(z, 0.f); pp += z * att4.w;
    return pp;
}

// ------------------------------------------------------------- cast f32->bf16
// grid.y = 2 selects (x_glom->xb_glom, x_imm->xb_imm)
__global__ void k_cast2(const float* __restrict__ x0, unsigned short* __restrict__ y0,
                        const float* __restrict__ x1, unsigned short* __restrict__ y1,
                        int n4)
{
    int i = blockIdx.x * 256 + threadIdx.x;
    if (i >= n4) return;
    const float* x = blockIdx.y ? x1 : x0;
    unsigned short* y = blockIdx.y ? y1 : y0;
    float4 v = ld4(x + (size_t)i * 4);
    ushort4 o;
    o.x = f2bf(v.x); o.y = f2bf(v.y); o.z = f2bf(v.z); o.w = f2bf(v.w);
    *reinterpret_cast<ushort4*>(y + (size_t)i * 4) = o;
}

// ------------------------------- W[K][N] -> Wt[N][K] bf16, 4 weights (grid.y)
__global__ void k_prep_wt4(const float* __restrict__ W0, const float* __restrict__ W1,
                           const float* __restrict__ W2, const float* __restrict__ W3,
                           unsigned short* __restrict__ Wt)
{
    int i = blockIdx.x * 256 + threadIdx.x;     // 65536 per weight
    int w = blockIdx.y;
    const float* W = (w == 0) ? W0 : (w == 1) ? W1 : (w == 2) ? W2 : W3;
    int c = i >> 8, k = i & 255;
    Wt[(size_t)w * D * D + i] = f2bf(W[k * D + c]);
}

// ------------------------------------------------------------- MFMA GEMM
template<int OUTBF>
__global__ __launch_bounds__(256)
void k_gemm_mfma(const unsigned short* __restrict__ A,
                 const unsigned short* __restrict__ Bt,
                 const float* __restrict__ bias, void* __restrict__ Cout, int M)
{
    const int lane = threadIdx.x & 63;
    const int wave = threadIdx.x >> 6;
    const int lr = lane & 15;
    const int lk = lane >> 4;
    const int row0 = blockIdx.x * 64 + wave * 16;
    const int col0 = blockIdx.y * 64;

    int arow = row0 + lr;
    int arow_c = (arow < M) ? arow : (M - 1);
    const unsigned short* ap = A + (size_t)arow_c * D + lk * 8;
    const unsigned short* bp = Bt + (size_t)(col0 + lr) * D + lk * 8;

    f32x4v acc[4] = {};

#pragma unroll
    for (int k0 = 0; k0 < 256; k0 += 32) {
        short8 af = *reinterpret_cast<const short8*>(ap + k0);
#pragma unroll
        for (int nf = 0; nf < 4; ++nf) {
            short8 bf = *reinterpret_cast<const short8*>(bp + (size_t)nf * 16 * D + k0);
            acc[nf] = __builtin_amdgcn_mfma_f32_16x16x32_bf16(af, bf, acc[nf], 0, 0, 0);
        }
    }

#pragma unroll
    for (int nf = 0; nf < 4; ++nf) {
        int c = col0 + nf * 16 + lr;
        float bv = bias ? bias[c] : 0.f;
#pragma unroll
        for (int i = 0; i < 4; ++i) {
            int r = row0 + 4 * lk + i;
            if (r < M) {
                float v = acc[nf][i] + bv;
                if (OUTBF)
                    ((unsigned short*)Cout)[(size_t)r * D + c] = f2bf(v);
                else
                    ((float*)Cout)[(size_t)r * D + c] = v;
            }
        }
    }
}

// --------------------------------------------------------------- CSR build
__global__ void k_zero_int(int* p, int n)
{
    int i = blockIdx.x * 256 + threadIdx.x;
    if (i < n) p[i] = 0;
}

__global__ void k_hist3(const int* __restrict__ ei_gg, const int* __restrict__ ei_ig,
                        const int* __restrict__ ei_gi, int* __restrict__ counts,
                        int E, int N)
{
    int i = blockIdx.x * 256 + threadIdx.x;
    if (i >= 3 * E) return;
    int t = i / E, e = i - t * E;
    const int* ei = (t == 0) ? ei_gg : (t == 1) ? ei_ig : ei_gi;
    atomicAdd(&counts[t * N + ei[E + e]], 1);
}

// tile-level exclusive scan; grid = (TPT, 3)
__global__ __launch_bounds__(256)
void k_scan_tile(const int* __restrict__ counts, int* __restrict__ rows,
                 int* __restrict__ partials, int N, int TPT)
{
    int t = blockIdx.y, tile = blockIdx.x;
    int i = tile * 256 + threadIdx.x;
    __shared__ int sh[256];
    int v = (i < N) ? counts[(size_t)t * N + i] : 0;
    sh[threadIdx.x] = v;
    __syncthreads();
#pragma unroll
    for (int off = 1; off < 256; off <<= 1) {
        int add = (threadIdx.x >= off) ? sh[threadIdx.x - off] : 0;
        __syncthreads();
        sh[threadIdx.x] += add;
        __syncthreads();
    }
    if (i < N) rows[(size_t)t * (N + 1) + i] = sh[threadIdx.x] - v;
    if (threadIdx.x == 255) partials[t * TPT + tile] = sh[255];
}

// exclusive scan of tile partials; grid = 3, block = 128 (TPT<=128)
__global__ __launch_bounds__(128)
void k_scan_part(int* __restrict__ partials, int TPT)
{
    int t = blockIdx.x;
    __shared__ int sh[128];
    int v = (threadIdx.x < TPT) ? partials[t * TPT + threadIdx.x] : 0;
    sh[threadIdx.x] = v;
    __syncthreads();
#pragma unroll
    for (int off = 1; off < 128; off <<= 1) {
        int add = (threadIdx.x >= off) ? sh[threadIdx.x - off] : 0;
        __syncthreads();
        sh[threadIdx.x] += add;
        __syncthreads();
    }
    if (threadIdx.x < TPT) partials[t * TPT + threadIdx.x] = sh[threadIdx.x] - v;
}

// add tile offsets, fill cur copy and rows[N]
__global__ void k_scan_final(int* __restrict__ rows, int* __restrict__ cur,
                             const int* __restrict__ partials, int N, int TPT, int E)
{
    int i = blockIdx.x * 256 + threadIdx.x;
    if (i >= 3 * N) return;
    int t = i / N, j = i - t * N;
    int r = rows[(size_t)t * (N + 1) + j] + partials[t * TPT + (j >> 8)];
    rows[(size_t)t * (N + 1) + j] = r;
    cur[(size_t)t * N + j] = r;
    if (j == 0) rows[(size_t)t * (N + 1) + N] = E;
}

__global__ void k_scatter3(const int* __restrict__ ei_gg, const int* __restrict__ ei_ig,
                           const int* __restrict__ ei_gi, const float* __restrict__ ew_gg,
                           const float* __restrict__ ea_ig, int* __restrict__ cur,
                           int* __restrict__ src_gcn, float* __restrict__ val_gcn,
                           int* __restrict__ src_gat, float* __restrict__ val_gat,
                           int* __restrict__ src_gin, int E, int N)
{
    int i = blockIdx.x * 256 + threadIdx.x;
    if (i >= 3 * E) return;
    int t = i / E, e = i - t * E;
    if (t == 0) {
        int s = ei_gg[e], d = ei_gg[E + e];
        int pos = atomicAdd(&cur[d], 1);
        src_gcn[pos] = s;
        val_gcn[pos] = ew_gg[e];
    } else if (t == 1) {
        int s = ei_ig[e], d = ei_ig[E + e];
        int pos = atomicAdd(&cur[N + d], 1);
        src_gat[pos] = s;
        val_gat[pos] = ea_ig[e];
    } else {
        int s = ei_gi[e], d = ei_gi[E + e];
        int pos = atomicAdd(&cur[2 * N + d], 1);
        src_gin[pos] = s;
    }
}

__global__ void k_dinv(const int* __restrict__ rows, const float* __restrict__ val,
                       float* __restrict__ dinv, int N)
{
    int i = blockIdx.x * 256 + threadIdx.x;
    if (i >= N) return;
    float s = 1.0f;
    int p1 = rows[i + 1];
    for (int p = rows[i]; p < p1; ++p) s += val[p];
    dinv[i] = rsqrtf(s);
}

// ---- fused glom: GCN aggr + GATv2 online-softmax aggr + LN + ReLU (4x unroll)
__global__ __launch_bounds__(256)
void k_glom_fused(const unsigned short* __restrict__ xw,
                  const unsigned short* __restrict__ hl,
                  const unsigned short* __restrict__ hr,
                  const float* __restrict__ dinv,
                  const int* __restrict__ rows_gcn, const int* __restrict__ src_gcn,
                  const float* __restrict__ val_gcn,
                  const int* __restrict__ rows_gat, const int* __restrict__ src_gat,
                  const float* __restrict__ val_gat,
                  const float* __restrict__ We, const float* __restrict__ att,
                  const float* __restrict__ b_gcn, const float* __restrict__ b_gat,
                  const float* __restrict__ gamma, const float* __restrict__ beta,
                  float* __restrict__ out, int N)
{
    int node = (blockIdx.x * 256 + threadIdx.x) >> 6;    // one wave per node
    int lane = threadIdx.x & 63;
    if (node >= N) return;

    float4 We4  = ld4(&We[lane * 4]);
    float4 att4 = ld4(&att[lane * 4]);
    float4 hrv  = ldb4(&hr[(size_t)node * D + lane * 4]);

    float di = dinv[node];
    float sc = di * di;
    float4 acc = ldb4(&xw[(size_t)node * D + lane * 4]);
    float4 g0  = ld4(&b_gcn[lane * 4]);
    float4 a0  = ld4(&b_gat[lane * 4]);
    acc.x = sc * acc.x + g0.x + a0.x;
    acc.y = sc * acc.y + g0.y + a0.y;
    acc.z = sc * acc.z + g0.z + a0.z;
    acc.w = sc * acc.w + g0.w + a0.w;

    // ---- GCN neighbor sum, 4 edges in flight ----
    int p  = rows_gcn[node];
    int p1 = rows_gcn[node + 1];
    for (; p + 4 <= p1; p += 4) {
        int s0 = src_gcn[p + 0], s1 = src_gcn[p + 1];
        int s2 = src_gcn[p + 2], s3 = src_gcn[p + 3];
        float c0 = dinv[s0] * val_gcn[p + 0] * di;
        float c1 = dinv[s1] * val_gcn[p + 1] * di;
        float c2 = dinv[s2] * val_gcn[p + 2] * di;
        float c3 = dinv[s3] * val_gcn[p + 3] * di;
        float4 v0 = ldb4(&xw[(size_t)s0 * D + lane * 4]);
        float4 v1 = ldb4(&xw[(size_t)s1 * D + lane * 4]);
        float4 v2 = ldb4(&xw[(size_t)s2 * D + lane * 4]);
        float4 v3 = ldb4(&xw[(size_t)s3 * D + lane * 4]);
        acc.x += c0 * v0.x + c1 * v1.x + c2 * v2.x + c3 * v3.x;
        acc.y += c0 * v0.y + c1 * v1.y + c2 * v2.y + c3 * v3.y;
        acc.z += c0 * v0.z + c1 * v1.z + c2 * v2.z + c3 * v3.z;
        acc.w += c0 * v0.w + c1 * v1.w + c2 * v2.w + c3 * v3.w;
    }
    for (; p < p1; ++p) {
        int s = src_gcn[p];
        float c = dinv[s] * val_gcn[p] * di;
        float4 v = ldb4(&xw[(size_t)s * D + lane * 4]);
        acc.x += c * v.x; acc.y += c * v.y;
        acc.z += c * v.z; acc.w += c * v.w;
    }

    // ---- GATv2 online softmax, 4 edges in flight ----
    int q  = rows_gat[node];
    int q1 = rows_gat[node + 1];
    int has = (q1 > q);
    float m = -3.4e38f, den = 0.f;
    float4 ag = make_float4(0.f, 0.f, 0.f, 0.f);
    for (; q + 4 <= q1; q += 4) {
        int s0 = src_gat[q + 0], s1 = src_gat[q + 1];
        int s2 = src_gat[q + 2], s3 = src_gat[q + 3];
        float e0 = val_gat[q + 0], e1 = val_gat[q + 1];
        float e2 = val_gat[q + 2], e3 = val_gat[q + 3];
        float4 h0 = ldb4(&hl[(size_t)s0 * D + lane * 4]);
        float4 h1 = ldb4(&hl[(size_t)s1 * D + lane * 4]);
        float4 h2 = ldb4(&hl[(size_t)s2 * D + lane * 4]);
        float4 h3 = ldb4(&hl[(size_t)s3 * D + lane * 4]);
        float pp0 = wave_sum(gat_partial(h0, hrv, e0, We4, att4));
        float pp1 = wave_sum(gat_partial(h1, hrv, e1, We4, att4));
        float pp2 = wave_sum(gat_partial(h2, hrv, e2, We4, att4));
        float pp3 = wave_sum(gat_partial(h3, hrv, e3, We4, att4));
        float mb = fmaxf(fmaxf(pp0, pp1), fmaxf(pp2, pp3));
        float mn = fmaxf(m, mb);
        float scale = __expf(m - mn);
        float x0 = __expf(pp0 - mn), x1 = __expf(pp1 - mn);
        float x2 = __expf(pp2 - mn), x3 = __expf(pp3 - mn);
        den = den * scale + x0 + x1 + x2 + x3;
        ag.x = ag.x * scale + x0 * h0.x + x1 * h1.x + x2 * h2.x + x3 * h3.x;
        ag.y = ag.y * scale + x0 * h0.y + x1 * h1.y + x2 * h2.y + x3 * h3.y;
        ag.z = ag.z * scale + x0 * h0.z + x1 * h1.z + x2 * h2.z + x3 * h3.z;
        ag.w = ag.w * scale + x0 * h0.w + x1 * h1.w + x2 * h2.w + x3 * h3.w;
        m = mn;
    }
    for (; q < q1; ++q) {
        int s = src_gat[q];
        float ea = val_gat[q];
        float4 h = ldb4(&hl[(size_t)s * D + lane * 4]);
        float pp = wave_sum(gat_partial(h, hrv, ea, We4, att4));
        float mn = fmaxf(m, pp);
        float scale = __expf(m - mn);
        float ex = __expf(pp - mn);
        den = den * scale + ex;
        ag.x = ag.x * scale + ex * h.x;
        ag.y = ag.y * scale + ex * h.y;
        ag.z = ag.z * scale + ex * h.z;
        ag.w = ag.w * scale + ex * h.w;
        m = mn;
    }
    if (has) {
        float inv = 1.0f / den;
        acc.x += ag.x * inv; acc.y += ag.y * inv;
        acc.z += ag.z * inv; acc.w += ag.w * inv;
    }

    // ---- LayerNorm + ReLU ----
    float s_ = acc.x + acc.y + acc.z + acc.w;
    float sq = acc.x * acc.x + acc.y * acc.y + acc.z * acc.z + acc.w * acc.w;
#pragma unroll
    for (int off = 32; off > 0; off >>= 1) {
        s_ += __shfl_xor(s_, off, 64);
        sq += __shfl_xor(sq, off, 64);
    }
    float mu  = s_ * (1.0f / 256.0f);
    float var = sq * (1.0f / 256.0f) - mu * mu;
    float rs  = rsqrtf(var + 1e-5f);
    float4 g = ld4(&gamma[lane * 4]);
    float4 b = ld4(&beta[lane * 4]);
    float4 o;
    o.x = fmaxf(0.f, (acc.x - mu) * rs * g.x + b.x);
    o.y = fmaxf(0.f, (acc.y - mu) * rs * g.y + b.y);
    o.z = fmaxf(0.f, (acc.z - mu) * rs * g.z + b.z);
    o.w = fmaxf(0.f, (acc.w - mu) * rs * g.w + b.w);
    st4(&out[(size_t)node * D + lane * 4], o);
}

// ---- GIN gather (4x unroll): agg_b = bf16( (1+eps)*x_imm + sum x_glom[s] )
__global__ __launch_bounds__(256)
void k_gin_gather(const unsigned short* __restrict__ xb_glom,
                  const float* __restrict__ x_imm, const float* __restrict__ eps,
                  const int* __restrict__ rows, const int* __restrict__ src,
                  unsigned short* __restrict__ agg, int N)
{
    int node = (blockIdx.x * 256 + threadIdx.x) >> 6;
    int lane = threadIdx.x & 63;
    if (node >= N) return;
    float c = 1.0f + eps[0];
    float4 acc = ld4(&x_imm[(size_t)node * D + lane * 4]);
    acc.x *= c; acc.y *= c; acc.z *= c; acc.w *= c;
    int p  = rows[node];
    int p1 = rows[node + 1];
    for (; p + 4 <= p1; p += 4) {
        int s0 = src[p + 0], s1 = src[p + 1], s2 = src[p + 2], s3 = src[p + 3];
        float4 v0 = ldb4(&xb_glom[(size_t)s0 * D + lane * 4]);
        float4 v1 = ldb4(&xb_glom[(size_t)s1 * D + lane * 4]);
        float4 v2 = ldb4(&xb_glom[(size_t)s2 * D + lane * 4]);
        float4 v3 = ldb4(&xb_glom[(size_t)s3 * D + lane * 4]);
        acc.x += (v0.x + v1.x) + (v2.x + v3.x);
        acc.y += (v0.y + v1.y) + (v2.y + v3.y);
        acc.z += (v0.z + v1.z) + (v2.z + v3.z);
        acc.w += (v0.w + v1.w) + (v2.w + v3.w);
    }
    for (; p < p1; ++p) {
        int s = src[p];
        float4 v = ldb4(&xb_glom[(size_t)s * D + lane * 4]);
        acc.x += v.x; acc.y += v.y; acc.z += v.z; acc.w += v.w;
    }
    ushort4 o;
    o.x = f2bf(acc.x); o.y = f2bf(acc.y); o.z = f2bf(acc.z); o.w = f2bf(acc.w);
    *reinterpret_cast<ushort4*>(agg + (size_t)node * D + lane * 4) = o;
}

// -------------------------------------------------------- LayerNorm+ReLU
__global__ __launch_bounds__(256)
void k_ln_relu(float* __restrict__ io, const float* __restrict__ gamma,
               const float* __restrict__ beta, int rows)
{
    int r    = (blockIdx.x * 256 + threadIdx.x) >> 6;
    int lane = threadIdx.x & 63;
    if (r >= rows) return;
    float4 v = ld4(&io[(size_t)r * D + lane * 4]);
    float s  = v.x + v.y + v.z + v.w;
    float sq = v.x * v.x + v.y * v.y + v.z * v.z + v.w * v.w;
#pragma unroll
    for (int off = 32; off > 0; off >>= 1) {
        s  += __shfl_xor(s, off, 64);
        sq += __shfl_xor(sq, off, 64);
    }
    float mu  = s * (1.0f / 256.0f);
    float var = sq * (1.0f / 256.0f) - mu * mu;
    float rs  = rsqrtf(var + 1e-5f);
    float4 g = ld4(&gamma[lane * 4]);
    float4 b = ld4(&beta[lane * 4]);
    float4 o;
    o.x = fmaxf(0.f, (v.x - mu) * rs * g.x + b.x);
    o.y = fmaxf(0.f, (v.y - mu) * rs * g.y + b.y);
    o.z = fmaxf(0.f, (v.z - mu) * rs * g.z + b.z);
    o.w = fmaxf(0.f, (v.w - mu) * rs * g.w + b.w);
    st4(&io[(size_t)r * D + lane * 4], o);
}

// ------------------------------------------------------------------ launch
extern "C" void kernel_launch(void* const* d_in, const int* in_sizes, int n_in,
                              void* d_out, int out_size, void* d_ws, size_t ws_size,
                              hipStream_t stream)
{
    const float* x_glom = (const float*)d_in[0];
    const float* x_imm  = (const float*)d_in[1];
    const float* ew_gg  = (const float*)d_in[2];
    const float* ea_ig  = (const float*)d_in[3];
    const float* W_gcn  = (const float*)d_in[4];
    const float* b_gcn  = (const float*)d_in[5];
    const float* Wl     = (const float*)d_in[6];
    const float* bl     = (const float*)d_in[7];
    const float* Wr     = (const float*)d_in[8];
    const float* br     = (const float*)d_in[9];
    const float* att    = (const float*)d_in[10];
    const float* We     = (const float*)d_in[11];
    const float* b_gat  = (const float*)d_in[12];
    const float* eps    = (const float*)d_in[13];
    const float* W_gin  = (const float*)d_in[14];
    const float* b_gin  = (const float*)d_in[15];
    const float* gamma  = (const float*)d_in[16];
    const float* beta   = (const float*)d_in[17];
    const int*   ei_gg  = (const int*)d_in[18];
    const int*   ei_ig  = (const int*)d_in[19];
    const int*   ei_gi  = (const int*)d_in[20];

    const int N = in_sizes[0] / D;     // 20000
    const int E = in_sizes[2];         // 320000
    const size_t ND = (size_t)N * D;
    const int TPT = (N + 255) / 256;   // scan tiles per edge type (79)

    // ---- workspace layout ----
    char* base = (char*)d_ws;
    size_t off = 0;
    auto alloc = [&](size_t bytes) {
        void* p = base + off;
        off = (off + bytes + 255) & ~(size_t)255;
        return p;
    };
    unsigned short* xb_glom = (unsigned short*)alloc(ND * 2);
    unsigned short* xb_imm  = (unsigned short*)alloc(ND * 2);
    unsigned short* xw_b    = (unsigned short*)alloc(ND * 2);
    unsigned short* hl_b    = (unsigned short*)alloc(ND * 2);
    unsigned short* hr_b    = (unsigned short*)alloc(ND * 2);
    unsigned short* agg_b   = (unsigned short*)alloc(ND * 2);
    unsigned short* Wt      = (unsigned short*)alloc(4 * D * D * 2);
    float* dinv    = (float*)alloc(N * 4);
    float* val_gcn = (float*)alloc(E * 4);
    float* val_gat = (float*)alloc(E * 4);
    int*   counts  = (int*)alloc(3 * (size_t)N * 4);
    int*   rows    = (int*)alloc(3 * (size_t)(N + 1) * 4);
    int*   cur     = (int*)alloc(3 * (size_t)N * 4);
    int*   parts   = (int*)alloc(3 * (size_t)TPT * 4);
    int*   src_gcn = (int*)alloc(E * 4);
    int*   src_gat = (int*)alloc(E * 4);
    int*   src_gin = (int*)alloc(E * 4);

    float* glom_out = (float*)d_out;
    float* imm_pre  = (float*)d_out + ND;

    dim3 gemm_grid((N + 63) / 64, 4);
    int nb_cast  = (int)((ND / 4 + 255) / 256);
    int nb_wt    = (D * D + 255) / 256;
    int nb_3n    = (3 * N + 255) / 256;
    int nb_nodes = (N + 255) / 256;
    int nb_3e    = (3 * E + 255) / 256;
    int nb_nw    = (N * 64 + 255) / 256;

    // --- prep: casts + W transposes ---
    k_cast2<<<dim3(nb_cast, 2), 256, 0, stream>>>(x_glom, xb_glom, x_imm, xb_imm,
                                                  (int)(ND / 4));
    k_prep_wt4<<<dim3(nb_wt, 4), 256, 0, stream>>>(W_gcn, Wl, Wr, W_gin, Wt);

    // --- CSR build (parallel scan) ---
    k_zero_int<<<nb_3n, 256, 0, stream>>>(counts, 3 * N);
    k_hist3<<<nb_3e, 256, 0, stream>>>(ei_gg, ei_ig, ei_gi, counts, E, N);
    k_scan_tile<<<dim3(TPT, 3), 256, 0, stream>>>(counts, rows, parts, N, TPT);
    k_scan_part<<<3, 128, 0, stream>>>(parts, TPT);
    k_scan_final<<<nb_3n, 256, 0, stream>>>(rows, cur, parts, N, TPT, E);
    k_scatter3<<<nb_3e, 256, 0, stream>>>(ei_gg, ei_ig, ei_gi, ew_gg, ea_ig, cur,
                                          src_gcn, val_gcn, src_gat, val_gat,
                                          src_gin, E, N);

    // --- projections (MFMA bf16) ---
    k_gemm_mfma<1><<<gemm_grid, 256, 0, stream>>>(xb_glom, Wt,             nullptr, xw_b, N);
    k_gemm_mfma<1><<<gemm_grid, 256, 0, stream>>>(xb_imm,  Wt + D * D,     bl,      hl_b, N);
    k_gemm_mfma<1><<<gemm_grid, 256, 0, stream>>>(xb_glom, Wt + 2 * D * D, br,      hr_b, N);

    // --- GCN degree norm ---
    k_dinv<<<nb_nodes, 256, 0, stream>>>(rows, val_gcn, dinv, N);

    // --- fused glom: GCN + GATv2(online softmax) + LN + ReLU ---
    k_glom_fused<<<nb_nw, 256, 0, stream>>>(xw_b, hl_b, hr_b, dinv,
                                            rows, src_gcn, val_gcn,
                                            rows + (N + 1), src_gat, val_gat,
                                            We, att, b_gcn, b_gat, gamma, beta,
                                            glom_out, N);

    // --- GIN: gather + MFMA GEMM + LN ---
    k_gin_gather<<<nb_nw, 256, 0, stream>>>(xb_glom, x_imm, eps,
                                            rows + 2 * (N + 1), src_gin, agg_b, N);
    k_gemm_mfma<0><<<gemm_grid, 256, 0, stream>>>(agg_b, Wt + 3 * D * D, b_gin, imm_pre, N);
    k_ln_relu<<<nb_nw, 256, 0, stream>>>(imm_pre, gamma, beta, N);
}

// Round 5
// 337.485 us; speedup vs baseline: 10.7239x; 1.0139x over previous
//
#include <hip/hip_runtime.h>

// HeteroMessagePassingLayer Round 5:
//  - glom_fused + gin_gather merged into one 2N-wave launch
//  - xw rows pre-scaled by dinv in GEMM epilogue (kills per-edge dinv[s] load)
//  - dual-output GEMM (xw|hr), LN+ReLU fused into GIN GEMM
//  - hipMemsetAsync for counts; deg accumulated in scatter

constexpr int D = 256;

typedef __attribute__((ext_vector_type(4))) float f32x4v;
typedef __attribute__((ext_vector_type(8))) short short8;

// ---------------------------------------------------------------- utilities
__device__ __forceinline__ float4 ld4(const float* p) {
    return *reinterpret_cast<const float4*>(p);
}
__device__ __forceinline__ void st4(float* p, float4 v) {
    *reinterpret_cast<float4*>(p) = v;
}
__device__ __forceinline__ unsigned short f2bf(float f) {
    unsigned u = __float_as_uint(f);
    u = u + 0x7FFFu + ((u >> 16) & 1u);
    return (unsigned short)(u >> 16);
}
__device__ __forceinline__ float bf2f(unsigned short u) {
    return __uint_as_float(((unsigned)u) << 16);
}
__device__ __forceinline__ float4 ldb4(const unsigned short* p) {
    ushort4 u = *reinterpret_cast<const ushort4*>(p);
    return make_float4(bf2f(u.x), bf2f(u.y), bf2f(u.z), bf2f(u.w));
}
__device__ __forceinline__ float wave_sum(float p) {
#pragma unroll
    for (int off = 32; off > 0; off >>= 1) p += __shfl_xor(p, off, 64);
    return p;
}
__device__ __forceinline__ float gat_partial(float4 h, float4 hrv, float ea,
                                             float4 We4, float4 att4) {
    float z, pp = 0.f;
    z = h.x + hrv.x + ea * We4.x; z = fmaxf(z, 0.f) + 0.2f * fminf(z, 0.f); pp += z * att4.x;
    z = h.y + hrv.y + ea * We4.y; z = fmaxf(z, 0.f) + 0.2f * fminf(z, 0.f); pp += z * att4.y;
    z = h.z + hrv.z + ea * We4.z; z = fmaxf(z, 0.f) + 0.2f * fminf(z, 0.f); pp += z * att4.z;
    z = h.w + hrv.w + ea * We4.w; z = fmaxf(z, 0.f) + 0.2f * fminf(z, 0.f); pp += z * att4.w;
    return pp;
}

// ------------------------------------------------------------- cast f32->bf16
__global__ void k_cast2(const float* __restrict__ x0, unsigned short* __restrict__ y0,
                        const float* __restrict__ x1, unsigned short* __restrict__ y1,
                        int n4)
{
    int i = blockIdx.x * 256 + threadIdx.x;
    if (i >= n4) return;
    const float* x = blockIdx.y ? x1 : x0;
    unsigned short* y = blockIdx.y ? y1 : y0;
    float4 v = ld4(x + (size_t)i * 4);
    ushort4 o;
    o.x = f2bf(v.x); o.y = f2bf(v.y); o.z = f2bf(v.z); o.w = f2bf(v.w);
    *reinterpret_cast<ushort4*>(y + (size_t)i * 4) = o;
}

// ------------------------------- W[K][N] -> Wt[N][K] bf16; order Wgcn,Wr,Wl,Wgin
__global__ void k_prep_wt4(const float* __restrict__ W0, const float* __restrict__ W1,
                           const float* __restrict__ W2, const float* __restrict__ W3,
                           unsigned short* __restrict__ Wt)
{
    int i = blockIdx.x * 256 + threadIdx.x;
    int w = blockIdx.y;
    const float* W = (w == 0) ? W0 : (w == 1) ? W1 : (w == 2) ? W2 : W3;
    int c = i >> 8, k = i & 255;
    Wt[(size_t)w * D * D + i] = f2bf(W[k * D + c]);
}

// --------------------------------------------- dual-output projection GEMM
// C[M, NC] = A @ Bt^T;  cols < 256 -> out0 (scaled by rowscale0, bias0),
// cols >= 256 -> out1 (bias1).  out1==null -> single output.
__global__ __launch_bounds__(256)
void k_gemm_proj(const unsigned short* __restrict__ A,
                 const unsigned short* __restrict__ Bt,
                 const float* __restrict__ rowscale0,
                 const float* __restrict__ bias0, const float* __restrict__ bias1,
                 unsigned short* __restrict__ out0, unsigned short* __restrict__ out1,
                 int M)
{
    const int lane = threadIdx.x & 63;
    const int wave = threadIdx.x >> 6;
    const int lr = lane & 15;
    const int lk = lane >> 4;
    const int row0 = blockIdx.x * 64 + wave * 16;
    const int col0 = blockIdx.y * 64;

    int arow = row0 + lr;
    int arow_c = (arow < M) ? arow : (M - 1);
    const unsigned short* ap = A + (size_t)arow_c * D + lk * 8;
    const unsigned short* bp = Bt + (size_t)(col0 + lr) * D + lk * 8;

    f32x4v acc[4] = {};
#pragma unroll
    for (int k0 = 0; k0 < 256; k0 += 32) {
        short8 af = *reinterpret_cast<const short8*>(ap + k0);
#pragma unroll
        for (int nf = 0; nf < 4; ++nf) {
            short8 bf = *reinterpret_cast<const short8*>(bp + (size_t)nf * 16 * D + k0);
            acc[nf] = __builtin_amdgcn_mfma_f32_16x16x32_bf16(af, bf, acc[nf], 0, 0, 0);
        }
    }

#pragma unroll
    for (int nf = 0; nf < 4; ++nf) {
        int c = col0 + nf * 16 + lr;
        bool second = (out1 != nullptr) && (c >= 256);
        unsigned short* dst = second ? out1 : out0;
        int cc = second ? (c - 256) : c;
        float bv = second ? bias1[cc] : (bias0 ? bias0[cc] : 0.f);
#pragma unroll
        for (int i = 0; i < 4; ++i) {
            int r = row0 + 4 * lk + i;
            if (r < M) {
                float sc = (!second && rowscale0) ? rowscale0[r] : 1.0f;
                dst[(size_t)r * D + cc] = f2bf(acc[nf][i] * sc + bv);
            }
        }
    }
}

// ------------------------------------- GIN GEMM + fused LayerNorm + ReLU
// block = 4 waves; block computes 16 rows x 256 cols, then LN per row.
__global__ __launch_bounds__(256)
void k_gin_gemm_ln(const unsigned short* __restrict__ A,
                   const unsigned short* __restrict__ Bt,
                   const float* __restrict__ bias,
                   const float* __restrict__ gamma, const float* __restrict__ beta,
                   float* __restrict__ out, int M)
{
    __shared__ float lds_s[4][16];
    __shared__ float lds_q[4][16];
    const int lane = threadIdx.x & 63;
    const int wave = threadIdx.x >> 6;
    const int lr = lane & 15;
    const int lk = lane >> 4;
    const int row0 = blockIdx.x * 16;
    const int col0 = wave * 64;

    int arow = row0 + lr;
    int arow_c = (arow < M) ? arow : (M - 1);
    const unsigned short* ap = A + (size_t)arow_c * D + lk * 8;
    const unsigned short* bp = Bt + (size_t)(col0 + lr) * D + lk * 8;

    f32x4v acc[4] = {};
#pragma unroll
    for (int k0 = 0; k0 < 256; k0 += 32) {
        short8 af = *reinterpret_cast<const short8*>(ap + k0);
#pragma unroll
        for (int nf = 0; nf < 4; ++nf) {
            short8 bf = *reinterpret_cast<const short8*>(bp + (size_t)nf * 16 * D + k0);
            acc[nf] = __builtin_amdgcn_mfma_f32_16x16x32_bf16(af, bf, acc[nf], 0, 0, 0);
        }
    }

    float bv[4], gv[4], be[4];
#pragma unroll
    for (int nf = 0; nf < 4; ++nf) {
        int c = col0 + nf * 16 + lr;
        bv[nf] = bias[c]; gv[nf] = gamma[c]; be[nf] = beta[c];
    }

    float ps[4], pq[4];
#pragma unroll
    for (int i = 0; i < 4; ++i) {
        float s = 0.f, q = 0.f;
#pragma unroll
        for (int nf = 0; nf < 4; ++nf) {
            float v = acc[nf][i] + bv[nf];
            acc[nf][i] = v;
            s += v; q += v * v;
        }
        ps[i] = s; pq[i] = q;
    }
    // reduce across the 16 lanes sharing lk (lane bits 0..3)
#pragma unroll
    for (int off = 1; off < 16; off <<= 1) {
#pragma unroll
        for (int i = 0; i < 4; ++i) {
            ps[i] += __shfl_xor(ps[i], off, 64);
            pq[i] += __shfl_xor(pq[i], off, 64);
        }
    }
    if (lr == 0) {
#pragma unroll
        for (int i = 0; i < 4; ++i) {
            lds_s[wave][lk * 4 + i] = ps[i];
            lds_q[wave][lk * 4 + i] = pq[i];
        }
    }
    __syncthreads();

#pragma unroll
    for (int i = 0; i < 4; ++i) {
        int rl = lk * 4 + i;
        float s = lds_s[0][rl] + lds_s[1][rl] + lds_s[2][rl] + lds_s[3][rl];
        float q = lds_q[0][rl] + lds_q[1][rl] + lds_q[2][rl] + lds_q[3][rl];
        float mu  = s * (1.0f / 256.0f);
        float var = q * (1.0f / 256.0f) - mu * mu;
        float rs  = rsqrtf(var + 1e-5f);
        int r = row0 + rl;
        if (r < M) {
#pragma unroll
            for (int nf = 0; nf < 4; ++nf) {
                int c = col0 + nf * 16 + lr;
                out[(size_t)r * D + c] =
                    fmaxf(0.f, (acc[nf][i] - mu) * rs * gv[nf] + be[nf]);
            }
        }
    }
}

// --------------------------------------------------------------- CSR build
__global__ void k_hist3(const int* __restrict__ ei_gg, const int* __restrict__ ei_ig,
                        const int* __restrict__ ei_gi, int* __restrict__ counts,
                        int E, int N)
{
    int i = blockIdx.x * 256 + threadIdx.x;
    if (i >= 3 * E) return;
    int t = i / E, e = i - t * E;
    const int* ei = (t == 0) ? ei_gg : (t == 1) ? ei_ig : ei_gi;
    atomicAdd(&counts[t * N + ei[E + e]], 1);
}

__global__ __launch_bounds__(256)
void k_scan_tile(const int* __restrict__ counts, int* __restrict__ rows,
                 int* __restrict__ partials, int N, int TPT)
{
    int t = blockIdx.y, tile = blockIdx.x;
    int i = tile * 256 + threadIdx.x;
    __shared__ int sh[256];
    int v = (i < N) ? counts[(size_t)t * N + i] : 0;
    sh[threadIdx.x] = v;
    __syncthreads();
#pragma unroll
    for (int off = 1; off < 256; off <<= 1) {
        int add = (threadIdx.x >= off) ? sh[threadIdx.x - off] : 0;
        __syncthreads();
        sh[threadIdx.x] += add;
        __syncthreads();
    }
    if (i < N) rows[(size_t)t * (N + 1) + i] = sh[threadIdx.x] - v;
    if (threadIdx.x == 255) partials[t * TPT + tile] = sh[255];
}

__global__ __launch_bounds__(128)
void k_scan_part(int* __restrict__ partials, int TPT)
{
    int t = blockIdx.x;
    __shared__ int sh[128];
    int v = (threadIdx.x < TPT) ? partials[t * TPT + threadIdx.x] : 0;
    sh[threadIdx.x] = v;
    __syncthreads();
#pragma unroll
    for (int off = 1; off < 128; off <<= 1) {
        int add = (threadIdx.x >= off) ? sh[threadIdx.x - off] : 0;
        __syncthreads();
        sh[threadIdx.x] += add;
        __syncthreads();
    }
    if (threadIdx.x < TPT) partials[t * TPT + threadIdx.x] = sh[threadIdx.x] - v;
}

// add tile offsets; fill cur copy, rows[N], deg init
__global__ void k_scan_final(int* __restrict__ rows, int* __restrict__ cur,
                             const int* __restrict__ partials, float* __restrict__ deg,
                             int N, int TPT, int E)
{
    int i = blockIdx.x * 256 + threadIdx.x;
    if (i >= 3 * N) return;
    int t = i / N, j = i - t * N;
    int r = rows[(size_t)t * (N + 1) + j] + partials[t * TPT + (j >> 8)];
    rows[(size_t)t * (N + 1) + j] = r;
    cur[(size_t)t * N + j] = r;
    if (j == 0) rows[(size_t)t * (N + 1) + N] = E;
    if (t == 0) deg[j] = 1.0f;       // self-loop weight
}

__global__ void k_scatter3(const int* __restrict__ ei_gg, const int* __restrict__ ei_ig,
                           const int* __restrict__ ei_gi, const float* __restrict__ ew_gg,
                           const float* __restrict__ ea_ig, int* __restrict__ cur,
                           int* __restrict__ src_gcn, float* __restrict__ val_gcn,
                           int* __restrict__ src_gat, float* __restrict__ val_gat,
                           int* __restrict__ src_gin, float* __restrict__ deg,
                           int E, int N)
{
    int i = blockIdx.x * 256 + threadIdx.x;
    if (i >= 3 * E) return;
    int t = i / E, e = i - t * E;
    if (t == 0) {
        int s = ei_gg[e], d = ei_gg[E + e];
        int pos = atomicAdd(&cur[d], 1);
        src_gcn[pos] = s;
        float w = ew_gg[e];
        val_gcn[pos] = w;
        atomicAdd(&deg[d], w);
    } else if (t == 1) {
        int s = ei_ig[e], d = ei_ig[E + e];
        int pos = atomicAdd(&cur[N + d], 1);
        src_gat[pos] = s;
        val_gat[pos] = ea_ig[e];
    } else {
        int s = ei_gi[e], d = ei_gi[E + e];
        int pos = atomicAdd(&cur[2 * N + d], 1);
        src_gin[pos] = s;
    }
}

__global__ void k_dinv(const float* __restrict__ deg, float* __restrict__ dinv, int N)
{
    int i = blockIdx.x * 256 + threadIdx.x;
    if (i < N) dinv[i] = rsqrtf(deg[i]);
}

// ================== fused gather: glom (GCN+GATv2+LN) and GIN, one launch
__global__ __launch_bounds__(256)
void k_gather_fused(// glom inputs
                    const unsigned short* __restrict__ xws,   // dinv-scaled xw (bf16)
                    const unsigned short* __restrict__ hl,
                    const unsigned short* __restrict__ hr,
                    const float* __restrict__ dinv,
                    const int* __restrict__ rows_gcn, const int* __restrict__ src_gcn,
                    const float* __restrict__ val_gcn,
                    const int* __restrict__ rows_gat, const int* __restrict__ src_gat,
                    const float* __restrict__ val_gat,
                    const float* __restrict__ We, const float* __restrict__ att,
                    const float* __restrict__ b_gcn, const float* __restrict__ b_gat,
                    const float* __restrict__ gamma, const float* __restrict__ beta,
                    float* __restrict__ glom_out,
                    // gin inputs
                    const unsigned short* __restrict__ xb_glom,
                    const float* __restrict__ x_imm, const float* __restrict__ eps,
                    const int* __restrict__ rows_gin, const int* __restrict__ src_gin,
                    unsigned short* __restrict__ agg,
                    int N)
{
    int gw   = (blockIdx.x * 256 + threadIdx.x) >> 6;   // global wave id
    int lane = threadIdx.x & 63;

    if (gw < N) {
        // ------------------------------ glom path -------------------------
        int node = gw;
        float4 We4  = ld4(&We[lane * 4]);
        float4 att4 = ld4(&att[lane * 4]);
        float4 hrv  = ldb4(&hr[(size_t)node * D + lane * 4]);

        float di = dinv[node];
        float4 acc = ldb4(&xws[(size_t)node * D + lane * 4]);   // = dinv*xw
        float4 g0  = ld4(&b_gcn[lane * 4]);
        float4 a0  = ld4(&b_gat[lane * 4]);
        acc.x = di * acc.x + g0.x + a0.x;      // dinv^2 * xw + biases
        acc.y = di * acc.y + g0.y + a0.y;
        acc.z = di * acc.z + g0.z + a0.z;
        acc.w = di * acc.w + g0.w + a0.w;

        // ---- GCN neighbor sum (coef = w * dinv[d]; dinv[s] folded into xws)
        int p  = rows_gcn[node];
        int p1 = rows_gcn[node + 1];
        for (; p + 4 <= p1; p += 4) {
            int s0 = src_gcn[p + 0], s1 = src_gcn[p + 1];
            int s2 = src_gcn[p + 2], s3 = src_gcn[p + 3];
            float c0 = val_gcn[p + 0] * di;
            float c1 = val_gcn[p + 1] * di;
            float c2 = val_gcn[p + 2] * di;
            float c3 = val_gcn[p + 3] * di;
            float4 v0 = ldb4(&xws[(size_t)s0 * D + lane * 4]);
            float4 v1 = ldb4(&xws[(size_t)s1 * D + lane * 4]);
            float4 v2 = ldb4(&xws[(size_t)s2 * D + lane * 4]);
            float4 v3 = ldb4(&xws[(size_t)s3 * D + lane * 4]);
            acc.x += c0 * v0.x + c1 * v1.x + c2 * v2.x + c3 * v3.x;
            acc.y += c0 * v0.y + c1 * v1.y + c2 * v2.y + c3 * v3.y;
            acc.z += c0 * v0.z + c1 * v1.z + c2 * v2.z + c3 * v3.z;
            acc.w += c0 * v0.w + c1 * v1.w + c2 * v2.w + c3 * v3.w;
        }
        for (; p < p1; ++p) {
            int s = src_gcn[p];
            float c = val_gcn[p] * di;
            float4 v = ldb4(&xws[(size_t)s * D + lane * 4]);
            acc.x += c * v.x; acc.y += c * v.y;
            acc.z += c * v.z; acc.w += c * v.w;
        }

        // ---- GATv2 online softmax, 4 edges in flight ----
        int q  = rows_gat[node];
        int q1 = rows_gat[node + 1];
        int has = (q1 > q);
        float m = -3.4e38f, den = 0.f;
        float4 ag = make_float4(0.f, 0.f, 0.f, 0.f);
        for (; q + 4 <= q1; q += 4) {
            int s0 = src_gat[q + 0], s1 = src_gat[q + 1];
            int s2 = src_gat[q + 2], s3 = src_gat[q + 3];
            float e0 = val_gat[q + 0], e1 = val_gat[q + 1];
            float e2 = val_gat[q + 2], e3 = val_gat[q + 3];
            float4 h0 = ldb4(&hl[(size_t)s0 * D + lane * 4]);
            float4 h1 = ldb4(&hl[(size_t)s1 * D + lane * 4]);
            float4 h2 = ldb4(&hl[(size_t)s2 * D + lane * 4]);
            float4 h3 = ldb4(&hl[(size_t)s3 * D + lane * 4]);
            float pp0 = wave_sum(gat_partial(h0, hrv, e0, We4, att4));
            float pp1 = wave_sum(gat_partial(h1, hrv, e1, We4, att4));
            float pp2 = wave_sum(gat_partial(h2, hrv, e2, We4, att4));
            float pp3 = wave_sum(gat_partial(h3, hrv, e3, We4, att4));
            float mb = fmaxf(fmaxf(pp0, pp1), fmaxf(pp2, pp3));
            float mn = fmaxf(m, mb);
            float scale = __expf(m - mn);
            float x0 = __expf(pp0 - mn), x1 = __expf(pp1 - mn);
            float x2 = __expf(pp2 - mn), x3 = __expf(pp3 - mn);
            den = den * scale + x0 + x1 + x2 + x3;
            ag.x = ag.x * scale + x0 * h0.x + x1 * h1.x + x2 * h2.x + x3 * h3.x;
            ag.y = ag.y * scale + x0 * h0.y + x1 * h1.y + x2 * h2.y + x3 * h3.y;
            ag.z = ag.z * scale + x0 * h0.z + x1 * h1.z + x2 * h2.z + x3 * h3.z;
            ag.w = ag.w * scale + x0 * h0.w + x1 * h1.w + x2 * h2.w + x3 * h3.w;
            m = mn;
        }
        for (; q < q1; ++q) {
            int s = src_gat[q];
            float ea = val_gat[q];
            float4 h = ldb4(&hl[(size_t)s * D + lane * 4]);
            float pp = wave_sum(gat_partial(h, hrv, ea, We4, att4));
            float mn = fmaxf(m, pp);
            float scale = __expf(m - mn);
            float ex = __expf(pp - mn);
            den = den * scale + ex;
            ag.x = ag.x * scale + ex * h.x;
            ag.y = ag.y * scale + ex * h.y;
            ag.z = ag.z * scale + ex * h.z;
            ag.w = ag.w * scale + ex * h.w;
            m = mn;
        }
        if (has) {
            float inv = 1.0f / den;
            acc.x += ag.x * inv; acc.y += ag.y * inv;
            acc.z += ag.z * inv; acc.w += ag.w * inv;
        }

        // ---- LayerNorm + ReLU ----
        float s_ = acc.x + acc.y + acc.z + acc.w;
        float sq = acc.x * acc.x + acc.y * acc.y + acc.z * acc.z + acc.w * acc.w;
#pragma unroll
        for (int off = 32; off > 0; off >>= 1) {
            s_ += __shfl_xor(s_, off, 64);
            sq += __shfl_xor(sq, off, 64);
        }
        float mu  = s_ * (1.0f / 256.0f);
        float var = sq * (1.0f / 256.0f) - mu * mu;
        float rs  = rsqrtf(var + 1e-5f);
        float4 g = ld4(&gamma[lane * 4]);
        float4 b = ld4(&beta[lane * 4]);
        float4 o;
        o.x = fmaxf(0.f, (acc.x - mu) * rs * g.x + b.x);
        o.y = fmaxf(0.f, (acc.y - mu) * rs * g.y + b.y);
        o.z = fmaxf(0.f, (acc.z - mu) * rs * g.z + b.z);
        o.w = fmaxf(0.f, (acc.w - mu) * rs * g.w + b.w);
        st4(&glom_out[(size_t)node * D + lane * 4], o);
    } else if (gw < 2 * N) {
        // ------------------------------ gin path --------------------------
        int node = gw - N;
        float c = 1.0f + eps[0];
        float4 acc = ld4(&x_imm[(size_t)node * D + lane * 4]);
        acc.x *= c; acc.y *= c; acc.z *= c; acc.w *= c;
        int p  = rows_gin[node];
        int p1 = rows_gin[node + 1];
        for (; p + 8 <= p1; p += 8) {
            int s0 = src_gin[p + 0], s1 = src_gin[p + 1];
            int s2 = src_gin[p + 2], s3 = src_gin[p + 3];
            int s4 = src_gin[p + 4], s5 = src_gin[p + 5];
            int s6 = src_gin[p + 6], s7 = src_gin[p + 7];
            float4 v0 = ldb4(&xb_glom[(size_t)s0 * D + lane * 4]);
            float4 v1 = ldb4(&xb_glom[(size_t)s1 * D + lane * 4]);
            float4 v2 = ldb4(&xb_glom[(size_t)s2 * D + lane * 4]);
            float4 v3 = ldb4(&xb_glom[(size_t)s3 * D + lane * 4]);
            float4 v4 = ldb4(&xb_glom[(size_t)s4 * D + lane * 4]);
            float4 v5 = ldb4(&xb_glom[(size_t)s5 * D + lane * 4]);
            float4 v6 = ldb4(&xb_glom[(size_t)s6 * D + lane * 4]);
            float4 v7 = ldb4(&xb_glom[(size_t)s7 * D + lane * 4]);
            acc.x += ((v0.x + v1.x) + (v2.x + v3.x)) + ((v4.x + v5.x) + (v6.x + v7.x));
            acc.y += ((v0.y + v1.y) + (v2.y + v3.y)) + ((v4.y + v5.y) + (v6.y + v7.y));
            acc.z += ((v0.z + v1.z) + (v2.z + v3.z)) + ((v4.z + v5.z) + (v6.z + v7.z));
            acc.w += ((v0.w + v1.w) + (v2.w + v3.w)) + ((v4.w + v5.w) + (v6.w + v7.w));
        }
        for (; p < p1; ++p) {
            int s = src_gin[p];
            float4 v = ldb4(&xb_glom[(size_t)s * D + lane * 4]);
            acc.x += v.x; acc.y += v.y; acc.z += v.z; acc.w += v.w;
        }
        ushort4 o;
        o.x = f2bf(acc.x); o.y = f2bf(acc.y); o.z = f2bf(acc.z); o.w = f2bf(acc.w);
        *reinterpret_cast<ushort4*>(agg + (size_t)node * D + lane * 4) = o;
    }
}

// ------------------------------------------------------------------ launch
extern "C" void kernel_launch(void* const* d_in, const int* in_sizes, int n_in,
                              void* d_out, int out_size, void* d_ws, size_t ws_size,
                              hipStream_t stream)
{
    const float* x_glom = (const float*)d_in[0];
    const float* x_imm  = (const float*)d_in[1];
    const float* ew_gg  = (const float*)d_in[2];
    const float* ea_ig  = (const float*)d_in[3];
    const float* W_gcn  = (const float*)d_in[4];
    const float* b_gcn  = (const float*)d_in[5];
    const float* Wl     = (const float*)d_in[6];
    const float* bl     = (const float*)d_in[7];
    const float* Wr     = (const float*)d_in[8];
    const float* br     = (const float*)d_in[9];
    const float* att    = (const float*)d_in[10];
    const float* We     = (const float*)d_in[11];
    const float* b_gat  = (const float*)d_in[12];
    const float* eps    = (const float*)d_in[13];
    const float* W_gin  = (const float*)d_in[14];
    const float* b_gin  = (const float*)d_in[15];
    const float* gamma  = (const float*)d_in[16];
    const float* beta   = (const float*)d_in[17];
    const int*   ei_gg  = (const int*)d_in[18];
    const int*   ei_ig  = (const int*)d_in[19];
    const int*   ei_gi  = (const int*)d_in[20];

    const int N = in_sizes[0] / D;     // 20000
    const int E = in_sizes[2];         // 320000
    const size_t ND = (size_t)N * D;
    const int TPT = (N + 255) / 256;   // scan tiles per type

    // ---- workspace layout ----
    char* base = (char*)d_ws;
    size_t off = 0;
    auto alloc = [&](size_t bytes) {
        void* p = base + off;
        off = (off + bytes + 255) & ~(size_t)255;
        return p;
    };
    unsigned short* xb_glom = (unsigned short*)alloc(ND * 2);
    unsigned short* xb_imm  = (unsigned short*)alloc(ND * 2);
    unsigned short* xws_b   = (unsigned short*)alloc(ND * 2);   // dinv-scaled xw
    unsigned short* hl_b    = (unsigned short*)alloc(ND * 2);
    unsigned short* hr_b    = (unsigned short*)alloc(ND * 2);
    unsigned short* agg_b   = (unsigned short*)alloc(ND * 2);
    unsigned short* Wt      = (unsigned short*)alloc(4 * D * D * 2);
    float* deg     = (float*)alloc(N * 4);
    float* dinv    = (float*)alloc(N * 4);
    float* val_gcn = (float*)alloc(E * 4);
    float* val_gat = (float*)alloc(E * 4);
    int*   counts  = (int*)alloc(3 * (size_t)N * 4);
    int*   rows    = (int*)alloc(3 * (size_t)(N + 1) * 4);
    int*   cur     = (int*)alloc(3 * (size_t)N * 4);
    int*   parts   = (int*)alloc(3 * (size_t)TPT * 4);
    int*   src_gcn = (int*)alloc(E * 4);
    int*   src_gat = (int*)alloc(E * 4);
    int*   src_gin = (int*)alloc(E * 4);

    float* glom_out = (float*)d_out;
    float* imm_out  = (float*)d_out + ND;

    int nb_cast  = (int)((ND / 4 + 255) / 256);
    int nb_wt    = (D * D + 255) / 256;
    int nb_3n    = (3 * N + 255) / 256;
    int nb_nodes = (N + 255) / 256;
    int nb_3e    = (3 * E + 255) / 256;
    int nb_2nw   = (2 * N + 3) / 4;          // 2N waves, 4 waves/block

    // --- prep: casts + W transposes (independent) ---
    k_cast2<<<dim3(nb_cast, 2), 256, 0, stream>>>(x_glom, xb_glom, x_imm, xb_imm,
                                                  (int)(ND / 4));
    k_prep_wt4<<<dim3(nb_wt, 4), 256, 0, stream>>>(W_gcn, Wr, Wl, W_gin, Wt);

    // --- CSR build + degrees ---
    hipMemsetAsync(counts, 0, 3 * (size_t)N * 4, stream);
    k_hist3<<<nb_3e, 256, 0, stream>>>(ei_gg, ei_ig, ei_gi, counts, E, N);
    k_scan_tile<<<dim3(TPT, 3), 256, 0, stream>>>(counts, rows, parts, N, TPT);
    k_scan_part<<<3, 128, 0, stream>>>(parts, TPT);
    k_scan_final<<<nb_3n, 256, 0, stream>>>(rows, cur, parts, deg, N, TPT, E);
    k_scatter3<<<nb_3e, 256, 0, stream>>>(ei_gg, ei_ig, ei_gi, ew_gg, ea_ig, cur,
                                          src_gcn, val_gcn, src_gat, val_gat,
                                          src_gin, deg, E, N);
    k_dinv<<<nb_nodes, 256, 0, stream>>>(deg, dinv, N);

    // --- projections: xw|hr (dual, xw scaled by dinv) and hl ---
    k_gemm_proj<<<dim3((N + 63) / 64, 8), 256, 0, stream>>>(
        xb_glom, Wt, dinv, nullptr, br, xws_b, hr_b, N);
    k_gemm_proj<<<dim3((N + 63) / 64, 4), 256, 0, stream>>>(
        xb_imm, Wt + 2 * D * D, nullptr, bl, nullptr, hl_b, nullptr, N);

    // --- fused gathers: glom (GCN+GAT+LN) and GIN, one launch ---
    k_gather_fused<<<nb_2nw, 256, 0, stream>>>(
        xws_b, hl_b, hr_b, dinv,
        rows, src_gcn, val_gcn,
        rows + (N + 1), src_gat, val_gat,
        We, att, b_gcn, b_gat, gamma, beta, glom_out,
        xb_glom, x_imm, eps,
        rows + 2 * (N + 1), src_gin, agg_b, N);

    // --- GIN GEMM + fused LN + ReLU ---
    k_gin_gemm_ln<<<(N + 15) / 16, 256, 0, stream>>>(
        agg_b, Wt + 3 * D * D, b_gin, gamma, beta, imm_out, N);
}

// Round 6
// 333.420 us; speedup vs baseline: 10.8547x; 1.0122x over previous
//
#include <hip/hip_runtime.h>

// HeteroMessagePassingLayer Round 6:
//  - 8-wide register-batched gather loops (GCN/GAT/GIN)
//  - rsqrt(deg) folded into consumers (k_dinv gone)
//  - prep kernel fuses W-transpose + counts zeroing (memset gone)
//  - single projection GEMM launch (grid.y=12)
//  - GIN GEMM+LN: wave covers full row, intra-wave LN reduce (no LDS)

constexpr int D = 256;

typedef __attribute__((ext_vector_type(4))) float f32x4v;
typedef __attribute__((ext_vector_type(8))) short short8;

// ---------------------------------------------------------------- utilities
__device__ __forceinline__ float4 ld4(const float* p) {
    return *reinterpret_cast<const float4*>(p);
}
__device__ __forceinline__ void st4(float* p, float4 v) {
    *reinterpret_cast<float4*>(p) = v;
}
__device__ __forceinline__ unsigned short f2bf(float f) {
    unsigned u = __float_as_uint(f);
    u = u + 0x7FFFu + ((u >> 16) & 1u);
    return (unsigned short)(u >> 16);
}
__device__ __forceinline__ float bf2f(unsigned short u) {
    return __uint_as_float(((unsigned)u) << 16);
}
__device__ __forceinline__ float4 ldb4(const unsigned short* p) {
    ushort4 u = *reinterpret_cast<const ushort4*>(p);
    return make_float4(bf2f(u.x), bf2f(u.y), bf2f(u.z), bf2f(u.w));
}
__device__ __forceinline__ float wave_sum(float p) {
#pragma unroll
    for (int off = 32; off > 0; off >>= 1) p += __shfl_xor(p, off, 64);
    return p;
}
__device__ __forceinline__ float gat_partial(float4 h, float4 hrv, float ea,
                                             float4 We4, float4 att4) {
    float z, pp = 0.f;
    z = h.x + hrv.x + ea * We4.x; z *= (z > 0.f) ? 1.0f : 0.2f; pp += z * att4.x;
    z = h.y + hrv.y + ea * We4.y; z *= (z > 0.f) ? 1.0f : 0.2f; pp += z * att4.y;
    z = h.z + hrv.z + ea * We4.z; z *= (z > 0.f) ? 1.0f : 0.2f; pp += z * att4.z;
    z = h.w + hrv.w + ea * We4.w; z *= (z > 0.f) ? 1.0f : 0.2f; pp += z * att4.w;
    return pp;
}

// ------------------------------------------------------------- cast f32->bf16
__global__ void k_cast2(const float* __restrict__ x0, unsigned short* __restrict__ y0,
                        const float* __restrict__ x1, unsigned short* __restrict__ y1,
                        int n4)
{
    int i = blockIdx.x * 256 + threadIdx.x;
    if (i >= n4) return;
    const float* x = blockIdx.y ? x1 : x0;
    unsigned short* y = blockIdx.y ? y1 : y0;
    float4 v = ld4(x + (size_t)i * 4);
    ushort4 o;
    o.x = f2bf(v.x); o.y = f2bf(v.y); o.z = f2bf(v.z); o.w = f2bf(v.w);
    *reinterpret_cast<ushort4*>(y + (size_t)i * 4) = o;
}

// ---------- W transposes (bf16, order Wgcn,Wr,Wl,Wgin) + counts zero; grid (256,5)
__global__ void k_prep_wtz(const float* __restrict__ W0, const float* __restrict__ W1,
                           const float* __restrict__ W2, const float* __restrict__ W3,
                           unsigned short* __restrict__ Wt, int* __restrict__ counts,
                           int n3)
{
    int w = blockIdx.y;
    int i = blockIdx.x * 256 + threadIdx.x;
    if (w < 4) {
        const float* W = (w == 0) ? W0 : (w == 1) ? W1 : (w == 2) ? W2 : W3;
        int c = i >> 8, k = i & 255;
        Wt[(size_t)w * D * D + i] = f2bf(W[k * D + c]);
    } else {
        if (i < n3) counts[i] = 0;
    }
}

// --------------------------------------------- merged projection GEMM
// grid.y < 8 : A=xb_glom, Bt=Wt[0..1] (512 cols): c<256 -> xws (rowscale
//              rsqrt(deg)), c>=256 -> hr (+br)
// grid.y >= 8: A=xb_imm, Bt=Wt[2] (256 cols) -> hl (+bl)
__global__ __launch_bounds__(256)
void k_proj(const unsigned short* __restrict__ xbg,
            const unsigned short* __restrict__ xbi,
            const unsigned short* __restrict__ Wt,
            const float* __restrict__ deg,
            const float* __restrict__ br, const float* __restrict__ bl,
            unsigned short* __restrict__ xws, unsigned short* __restrict__ hr,
            unsigned short* __restrict__ hl, int M)
{
    const int lane = threadIdx.x & 63;
    const int wave = threadIdx.x >> 6;
    const int lr = lane & 15;
    const int lk = lane >> 4;
    const int yy = blockIdx.y;
    const int row0 = blockIdx.x * 64 + wave * 16;

    const unsigned short* A;
    const unsigned short* Bt0;
    int col0;
    if (yy < 8) { A = xbg; Bt0 = Wt;             col0 = yy * 64; }
    else        { A = xbi; Bt0 = Wt + 2 * D * D; col0 = (yy - 8) * 64; }

    int arow = row0 + lr;
    int arow_c = (arow < M) ? arow : (M - 1);
    const unsigned short* ap = A + (size_t)arow_c * D + lk * 8;
    const unsigned short* bp = Bt0 + (size_t)(col0 + lr) * D + lk * 8;

    f32x4v acc[4] = {};
#pragma unroll
    for (int k0 = 0; k0 < 256; k0 += 32) {
        short8 af = *reinterpret_cast<const short8*>(ap + k0);
#pragma unroll
        for (int nf = 0; nf < 4; ++nf) {
            short8 bf = *reinterpret_cast<const short8*>(bp + (size_t)nf * 16 * D + k0);
            acc[nf] = __builtin_amdgcn_mfma_f32_16x16x32_bf16(af, bf, acc[nf], 0, 0, 0);
        }
    }

#pragma unroll
    for (int nf = 0; nf < 4; ++nf) {
        int c = col0 + nf * 16 + lr;
        unsigned short* dst;
        int cc;
        float bv;
        bool scaled;
        if (yy < 8) {
            if (c < 256) { dst = xws; cc = c;       bv = 0.f;    scaled = true;  }
            else         { dst = hr;  cc = c - 256; bv = br[cc]; scaled = false; }
        } else           { dst = hl;  cc = c;       bv = bl[cc]; scaled = false; }
#pragma unroll
        for (int i = 0; i < 4; ++i) {
            int r = row0 + 4 * lk + i;
            if (r < M) {
                float sc = scaled ? rsqrtf(deg[r]) : 1.0f;
                dst[(size_t)r * D + cc] = f2bf(acc[nf][i] * sc + bv);
            }
        }
    }
}

// ------------------------------------- GIN GEMM + fused LayerNorm + ReLU
// wave = 16 rows x 256 cols (16 frags); LN reduce = 4-step intra-wave shuffle.
__global__ __launch_bounds__(256)
void k_gin_gemm_ln(const unsigned short* __restrict__ A,
                   const unsigned short* __restrict__ Bt,
                   const float* __restrict__ bias,
                   const float* __restrict__ gamma, const float* __restrict__ beta,
                   float* __restrict__ out, int M)
{
    const int lane = threadIdx.x & 63;
    const int wave = threadIdx.x >> 6;
    const int lr = lane & 15;
    const int lk = lane >> 4;
    const int row0 = blockIdx.x * 64 + wave * 16;

    int arow = row0 + lr;
    int arow_c = (arow < M) ? arow : (M - 1);
    const unsigned short* ap = A + (size_t)arow_c * D + lk * 8;

    f32x4v acc[16] = {};
#pragma unroll
    for (int k0 = 0; k0 < 256; k0 += 32) {
        short8 af = *reinterpret_cast<const short8*>(ap + k0);
#pragma unroll
        for (int nf = 0; nf < 16; ++nf) {
            short8 bf = *reinterpret_cast<const short8*>(
                Bt + (size_t)(nf * 16 + lr) * D + lk * 8 + k0);
            acc[nf] = __builtin_amdgcn_mfma_f32_16x16x32_bf16(af, bf, acc[nf], 0, 0, 0);
        }
    }

    float bv[16];
#pragma unroll
    for (int nf = 0; nf < 16; ++nf) bv[nf] = bias[nf * 16 + lr];

    float ps[4], pq[4];
#pragma unroll
    for (int i = 0; i < 4; ++i) {
        float s = 0.f, q = 0.f;
#pragma unroll
        for (int nf = 0; nf < 16; ++nf) {
            float v = acc[nf][i] + bv[nf];
            acc[nf][i] = v;
            s += v; q += v * v;
        }
        ps[i] = s; pq[i] = q;
    }
#pragma unroll
    for (int off = 1; off < 16; off <<= 1) {
#pragma unroll
        for (int i = 0; i < 4; ++i) {
            ps[i] += __shfl_xor(ps[i], off, 64);
            pq[i] += __shfl_xor(pq[i], off, 64);
        }
    }

    float gv[16], be[16];
#pragma unroll
    for (int nf = 0; nf < 16; ++nf) {
        gv[nf] = gamma[nf * 16 + lr];
        be[nf] = beta[nf * 16 + lr];
    }
#pragma unroll
    for (int i = 0; i < 4; ++i) {
        float mu  = ps[i] * (1.0f / 256.0f);
        float var = pq[i] * (1.0f / 256.0f) - mu * mu;
        float rs  = rsqrtf(var + 1e-5f);
        int r = row0 + 4 * lk + i;
        if (r < M) {
#pragma unroll
            for (int nf = 0; nf < 16; ++nf) {
                out[(size_t)r * D + nf * 16 + lr] =
                    fmaxf(0.f, (acc[nf][i] - mu) * rs * gv[nf] + be[nf]);
            }
        }
    }
}

// --------------------------------------------------------------- CSR build
__global__ void k_hist3(const int* __restrict__ ei_gg, const int* __restrict__ ei_ig,
                        const int* __restrict__ ei_gi, int* __restrict__ counts,
                        int E, int N)
{
    int i = blockIdx.x * 256 + threadIdx.x;
    if (i >= 3 * E) return;
    int t = i / E, e = i - t * E;
    const int* ei = (t == 0) ? ei_gg : (t == 1) ? ei_ig : ei_gi;
    atomicAdd(&counts[t * N + ei[E + e]], 1);
}

__global__ __launch_bounds__(256)
void k_scan_tile(const int* __restrict__ counts, int* __restrict__ rows,
                 int* __restrict__ partials, int N, int TPT)
{
    int t = blockIdx.y, tile = blockIdx.x;
    int i = tile * 256 + threadIdx.x;
    __shared__ int sh[256];
    int v = (i < N) ? counts[(size_t)t * N + i] : 0;
    sh[threadIdx.x] = v;
    __syncthreads();
#pragma unroll
    for (int off = 1; off < 256; off <<= 1) {
        int add = (threadIdx.x >= off) ? sh[threadIdx.x - off] : 0;
        __syncthreads();
        sh[threadIdx.x] += add;
        __syncthreads();
    }
    if (i < N) rows[(size_t)t * (N + 1) + i] = sh[threadIdx.x] - v;
    if (threadIdx.x == 255) partials[t * TPT + tile] = sh[255];
}

__global__ __launch_bounds__(128)
void k_scan_part(int* __restrict__ partials, int TPT)
{
    int t = blockIdx.x;
    __shared__ int sh[128];
    int v = (threadIdx.x < TPT) ? partials[t * TPT + threadIdx.x] : 0;
    sh[threadIdx.x] = v;
    __syncthreads();
#pragma unroll
    for (int off = 1; off < 128; off <<= 1) {
        int add = (threadIdx.x >= off) ? sh[threadIdx.x - off] : 0;
        __syncthreads();
        sh[threadIdx.x] += add;
        __syncthreads();
    }
    if (threadIdx.x < TPT) partials[t * TPT + threadIdx.x] = sh[threadIdx.x] - v;
}

__global__ void k_scan_final(int* __restrict__ rows, int* __restrict__ cur,
                             const int* __restrict__ partials, float* __restrict__ deg,
                             int N, int TPT, int E)
{
    int i = blockIdx.x * 256 + threadIdx.x;
    if (i >= 3 * N) return;
    int t = i / N, j = i - t * N;
    int r = rows[(size_t)t * (N + 1) + j] + partials[t * TPT + (j >> 8)];
    rows[(size_t)t * (N + 1) + j] = r;
    cur[(size_t)t * N + j] = r;
    if (j == 0) rows[(size_t)t * (N + 1) + N] = E;
    if (t == 0) deg[j] = 1.0f;       // self-loop weight
}

__global__ void k_scatter3(const int* __restrict__ ei_gg, const int* __restrict__ ei_ig,
                           const int* __restrict__ ei_gi, const float* __restrict__ ew_gg,
                           const float* __restrict__ ea_ig, int* __restrict__ cur,
                           int* __restrict__ src_gcn, float* __restrict__ val_gcn,
                           int* __restrict__ src_gat, float* __restrict__ val_gat,
                           int* __restrict__ src_gin, float* __restrict__ deg,
                           int E, int N)
{
    int i = blockIdx.x * 256 + threadIdx.x;
    if (i >= 3 * E) return;
    int t = i / E, e = i - t * E;
    if (t == 0) {
        int s = ei_gg[e], d = ei_gg[E + e];
        int pos = atomicAdd(&cur[d], 1);
        src_gcn[pos] = s;
        float w = ew_gg[e];
        val_gcn[pos] = w;
        atomicAdd(&deg[d], w);
    } else if (t == 1) {
        int s = ei_ig[e], d = ei_ig[E + e];
        int pos = atomicAdd(&cur[N + d], 1);
        src_gat[pos] = s;
        val_gat[pos] = ea_ig[e];
    } else {
        int s = ei_gi[e], d = ei_gi[E + e];
        int pos = atomicAdd(&cur[2 * N + d], 1);
        src_gin[pos] = s;
    }
}

// ================== fused gather: glom (GCN+GATv2+LN) and GIN, one launch
__global__ __launch_bounds__(256)
void k_gather_fused(const unsigned short* __restrict__ xws,
                    const unsigned short* __restrict__ hl,
                    const unsigned short* __restrict__ hr,
                    const float* __restrict__ deg,
                    const int* __restrict__ rows_gcn, const int* __restrict__ src_gcn,
                    const float* __restrict__ val_gcn,
                    const int* __restrict__ rows_gat, const int* __restrict__ src_gat,
                    const float* __restrict__ val_gat,
                    const float* __restrict__ We, const float* __restrict__ att,
                    const float* __restrict__ b_gcn, const float* __restrict__ b_gat,
                    const float* __restrict__ gamma, const float* __restrict__ beta,
                    float* __restrict__ glom_out,
                    const unsigned short* __restrict__ xb_glom,
                    const float* __restrict__ x_imm, const float* __restrict__ eps,
                    const int* __restrict__ rows_gin, const int* __restrict__ src_gin,
                    unsigned short* __restrict__ agg,
                    int N)
{
    int gw   = (blockIdx.x * 256 + threadIdx.x) >> 6;
    int lane = threadIdx.x & 63;

    if (gw < N) {
        // ------------------------------ glom path -------------------------
        int node = gw;
        float4 We4  = ld4(&We[lane * 4]);
        float4 att4 = ld4(&att[lane * 4]);
        float4 hrv  = ldb4(&hr[(size_t)node * D + lane * 4]);

        float di = rsqrtf(deg[node]);
        float4 acc = ldb4(&xws[(size_t)node * D + lane * 4]);   // = dinv*xw
        float4 g0  = ld4(&b_gcn[lane * 4]);
        float4 a0  = ld4(&b_gat[lane * 4]);
        acc.x = di * acc.x + g0.x + a0.x;
        acc.y = di * acc.y + g0.y + a0.y;
        acc.z = di * acc.z + g0.z + a0.z;
        acc.w = di * acc.w + g0.w + a0.w;

        // ---- GCN neighbor sum, 8 edges in flight ----
        int p  = rows_gcn[node];
        int p1 = rows_gcn[node + 1];
        for (; p + 8 <= p1; p += 8) {
            int   s[8];
            float cf[8];
            float4 v[8];
#pragma unroll
            for (int j = 0; j < 8; ++j) { s[j] = src_gcn[p + j]; cf[j] = val_gcn[p + j] * di; }
#pragma unroll
            for (int j = 0; j < 8; ++j) v[j] = ldb4(&xws[(size_t)s[j] * D + lane * 4]);
#pragma unroll
            for (int j = 0; j < 8; ++j) {
                acc.x += cf[j] * v[j].x; acc.y += cf[j] * v[j].y;
                acc.z += cf[j] * v[j].z; acc.w += cf[j] * v[j].w;
            }
        }
        for (; p + 4 <= p1; p += 4) {
            int   s[4];
            float cf[4];
            float4 v[4];
#pragma unroll
            for (int j = 0; j < 4; ++j) { s[j] = src_gcn[p + j]; cf[j] = val_gcn[p + j] * di; }
#pragma unroll
            for (int j = 0; j < 4; ++j) v[j] = ldb4(&xws[(size_t)s[j] * D + lane * 4]);
#pragma unroll
            for (int j = 0; j < 4; ++j) {
                acc.x += cf[j] * v[j].x; acc.y += cf[j] * v[j].y;
                acc.z += cf[j] * v[j].z; acc.w += cf[j] * v[j].w;
            }
        }
        for (; p < p1; ++p) {
            int sx = src_gcn[p];
            float cx = val_gcn[p] * di;
            float4 v = ldb4(&xws[(size_t)sx * D + lane * 4]);
            acc.x += cx * v.x; acc.y += cx * v.y;
            acc.z += cx * v.z; acc.w += cx * v.w;
        }

        // ---- GATv2 online softmax, 8 edges in flight ----
        int q  = rows_gat[node];
        int q1 = rows_gat[node + 1];
        int has = (q1 > q);
        float m = -3.4e38f, den = 0.f;
        float4 ag = make_float4(0.f, 0.f, 0.f, 0.f);
        for (; q + 8 <= q1; q += 8) {
            int   s[8];
            float ev[8];
            float4 h[8];
            float pp[8];
#pragma unroll
            for (int j = 0; j < 8; ++j) { s[j] = src_gat[q + j]; ev[j] = val_gat[q + j]; }
#pragma unroll
            for (int j = 0; j < 8; ++j) h[j] = ldb4(&hl[(size_t)s[j] * D + lane * 4]);
#pragma unroll
            for (int j = 0; j < 8; ++j) pp[j] = wave_sum(gat_partial(h[j], hrv, ev[j], We4, att4));
            float mb = fmaxf(fmaxf(fmaxf(pp[0], pp[1]), fmaxf(pp[2], pp[3])),
                             fmaxf(fmaxf(pp[4], pp[5]), fmaxf(pp[6], pp[7])));
            float mn = fmaxf(m, mb);
            float scale = __expf(m - mn);
            float x[8];
#pragma unroll
            for (int j = 0; j < 8; ++j) x[j] = __expf(pp[j] - mn);
            den = den * scale + ((x[0] + x[1]) + (x[2] + x[3])) + ((x[4] + x[5]) + (x[6] + x[7]));
            float axx = 0.f, ayy = 0.f, azz = 0.f, aww = 0.f;
#pragma unroll
            for (int j = 0; j < 8; ++j) {
                axx += x[j] * h[j].x; ayy += x[j] * h[j].y;
                azz += x[j] * h[j].z; aww += x[j] * h[j].w;
            }
            ag.x = ag.x * scale + axx; ag.y = ag.y * scale + ayy;
            ag.z = ag.z * scale + azz; ag.w = ag.w * scale + aww;
            m = mn;
        }
        for (; q + 4 <= q1; q += 4) {
            int   s[4];
            float ev[4];
            float4 h[4];
            float pp[4];
#pragma unroll
            for (int j = 0; j < 4; ++j) { s[j] = src_gat[q + j]; ev[j] = val_gat[q + j]; }
#pragma unroll
            for (int j = 0; j < 4; ++j) h[j] = ldb4(&hl[(size_t)s[j] * D + lane * 4]);
#pragma unroll
            for (int j = 0; j < 4; ++j) pp[j] = wave_sum(gat_partial(h[j], hrv, ev[j], We4, att4));
            float mb = fmaxf(fmaxf(pp[0], pp[1]), fmaxf(pp[2], pp[3]));
            float mn = fmaxf(m, mb);
            float scale = __expf(m - mn);
            float x[4];
#pragma unroll
            for (int j = 0; j < 4; ++j) x[j] = __expf(pp[j] - mn);
            den = den * scale + (x[0] + x[1]) + (x[2] + x[3]);
            float axx = 0.f, ayy = 0.f, azz = 0.f, aww = 0.f;
#pragma unroll
            for (int j = 0; j < 4; ++j) {
                axx += x[j] * h[j].x; ayy += x[j] * h[j].y;
                azz += x[j] * h[j].z; aww += x[j] * h[j].w;
            }
            ag.x = ag.x * scale + axx; ag.y = ag.y * scale + ayy;
            ag.z = ag.z * scale + azz; ag.w = ag.w * scale + aww;
            m = mn;
        }
        for (; q < q1; ++q) {
            int sx = src_gat[q];
            float ea = val_gat[q];
            float4 h = ldb4(&hl[(size_t)sx * D + lane * 4]);
            float pp = wave_sum(gat_partial(h, hrv, ea, We4, att4));
            float mn = fmaxf(m, pp);
            float scale = __expf(m - mn);
            float ex = __expf(pp - mn);
            den = den * scale + ex;
            ag.x = ag.x * scale + ex * h.x;
            ag.y = ag.y * scale + ex * h.y;
            ag.z = ag.z * scale + ex * h.z;
            ag.w = ag.w * scale + ex * h.w;
            m = mn;
        }
        if (has) {
            float inv = 1.0f / den;
            acc.x += ag.x * inv; acc.y += ag.y * inv;
            acc.z += ag.z * inv; acc.w += ag.w * inv;
        }

        // ---- LayerNorm + ReLU ----
        float s_ = acc.x + acc.y + acc.z + acc.w;
        float sq = acc.x * acc.x + acc.y * acc.y + acc.z * acc.z + acc.w * acc.w;
#pragma unroll
        for (int off = 32; off > 0; off >>= 1) {
            s_ += __shfl_xor(s_, off, 64);
            sq += __shfl_xor(sq, off, 64);
        }
        float mu  = s_ * (1.0f / 256.0f);
        float var = sq * (1.0f / 256.0f) - mu * mu;
        float rs  = rsqrtf(var + 1e-5f);
        float4 g = ld4(&gamma[lane * 4]);
        float4 b = ld4(&beta[lane * 4]);
        float4 o;
        o.x = fmaxf(0.f, (acc.x - mu) * rs * g.x + b.x);
        o.y = fmaxf(0.f, (acc.y - mu) * rs * g.y + b.y);
        o.z = fmaxf(0.f, (acc.z - mu) * rs * g.z + b.z);
        o.w = fmaxf(0.f, (acc.w - mu) * rs * g.w + b.w);
        st4(&glom_out[(size_t)node * D + lane * 4], o);
    } else if (gw < 2 * N) {
        // ------------------------------ gin path --------------------------
        int node = gw - N;
        float c = 1.0f + eps[0];
        float4 acc = ld4(&x_imm[(size_t)node * D + lane * 4]);
        acc.x *= c; acc.y *= c; acc.z *= c; acc.w *= c;
        int p  = rows_gin[node];
        int p1 = rows_gin[node + 1];
        for (; p + 8 <= p1; p += 8) {
            int s[8];
            float4 v[8];
#pragma unroll
            for (int j = 0; j < 8; ++j) s[j] = src_gin[p + j];
#pragma unroll
            for (int j = 0; j < 8; ++j) v[j] = ldb4(&xb_glom[(size_t)s[j] * D + lane * 4]);
            acc.x += ((v[0].x + v[1].x) + (v[2].x + v[3].x)) + ((v[4].x + v[5].x) + (v[6].x + v[7].x));
            acc.y += ((v[0].y + v[1].y) + (v[2].y + v[3].y)) + ((v[4].y + v[5].y) + (v[6].y + v[7].y));
            acc.z += ((v[0].z + v[1].z) + (v[2].z + v[3].z)) + ((v[4].z + v[5].z) + (v[6].z + v[7].z));
            acc.w += ((v[0].w + v[1].w) + (v[2].w + v[3].w)) + ((v[4].w + v[5].w) + (v[6].w + v[7].w));
        }
        for (; p + 4 <= p1; p += 4) {
            int s[4];
            float4 v[4];
#pragma unroll
            for (int j = 0; j < 4; ++j) s[j] = src_gin[p + j];
#pragma unroll
            for (int j = 0; j < 4; ++j) v[j] = ldb4(&xb_glom[(size_t)s[j] * D + lane * 4]);
            acc.x += (v[0].x + v[1].x) + (v[2].x + v[3].x);
            acc.y += (v[0].y + v[1].y) + (v[2].y + v[3].y);
            acc.z += (v[0].z + v[1].z) + (v[2].z + v[3].z);
            acc.w += (v[0].w + v[1].w) + (v[2].w + v[3].w);
        }
        for (; p < p1; ++p) {
            int sx = src_gin[p];
            float4 v = ldb4(&xb_glom[(size_t)sx * D + lane * 4]);
            acc.x += v.x; acc.y += v.y; acc.z += v.z; acc.w += v.w;
        }
        ushort4 o;
        o.x = f2bf(acc.x); o.y = f2bf(acc.y); o.z = f2bf(acc.z); o.w = f2bf(acc.w);
        *reinterpret_cast<ushort4*>(agg + (size_t)node * D + lane * 4) = o;
    }
}

// ------------------------------------------------------------------ launch
extern "C" void kernel_launch(void* const* d_in, const int* in_sizes, int n_in,
                              void* d_out, int out_size, void* d_ws, size_t ws_size,
                              hipStream_t stream)
{
    const float* x_glom = (const float*)d_in[0];
    const float* x_imm  = (const float*)d_in[1];
    const float* ew_gg  = (const float*)d_in[2];
    const float* ea_ig  = (const float*)d_in[3];
    const float* W_gcn  = (const float*)d_in[4];
    const float* b_gcn  = (const float*)d_in[5];
    const float* Wl     = (const float*)d_in[6];
    const float* bl     = (const float*)d_in[7];
    const float* Wr     = (const float*)d_in[8];
    const float* br     = (const float*)d_in[9];
    const float* att    = (const float*)d_in[10];
    const float* We     = (const float*)d_in[11];
    const float* b_gat  = (const float*)d_in[12];
    const float* eps    = (const float*)d_in[13];
    const float* W_gin  = (const float*)d_in[14];
    const float* b_gin  = (const float*)d_in[15];
    const float* gamma  = (const float*)d_in[16];
    const float* beta   = (const float*)d_in[17];
    const int*   ei_gg  = (const int*)d_in[18];
    const int*   ei_ig  = (const int*)d_in[19];
    const int*   ei_gi  = (const int*)d_in[20];

    const int N = in_sizes[0] / D;     // 20000
    const int E = in_sizes[2];         // 320000
    const size_t ND = (size_t)N * D;
    const int TPT = (N + 255) / 256;

    // ---- workspace layout ----
    char* base = (char*)d_ws;
    size_t off = 0;
    auto alloc = [&](size_t bytes) {
        void* p = base + off;
        off = (off + bytes + 255) & ~(size_t)255;
        return p;
    };
    unsigned short* xb_glom = (unsigned short*)alloc(ND * 2);
    unsigned short* xb_imm  = (unsigned short*)alloc(ND * 2);
    unsigned short* xws_b   = (unsigned short*)alloc(ND * 2);
    unsigned short* hl_b    = (unsigned short*)alloc(ND * 2);
    unsigned short* hr_b    = (unsigned short*)alloc(ND * 2);
    unsigned short* agg_b   = (unsigned short*)alloc(ND * 2);
    unsigned short* Wt      = (unsigned short*)alloc(4 * D * D * 2);
    float* deg     = (float*)alloc(N * 4);
    float* val_gcn = (float*)alloc(E * 4);
    float* val_gat = (float*)alloc(E * 4);
    int*   counts  = (int*)alloc(3 * (size_t)N * 4);
    int*   rows    = (int*)alloc(3 * (size_t)(N + 1) * 4);
    int*   cur     = (int*)alloc(3 * (size_t)N * 4);
    int*   parts   = (int*)alloc(3 * (size_t)TPT * 4);
    int*   src_gcn = (int*)alloc(E * 4);
    int*   src_gat = (int*)alloc(E * 4);
    int*   src_gin = (int*)alloc(E * 4);

    float* glom_out = (float*)d_out;
    float* imm_out  = (float*)d_out + ND;

    int nb_cast  = (int)((ND / 4 + 255) / 256);
    int nb_3n    = (3 * N + 255) / 256;
    int nb_3e    = (3 * E + 255) / 256;
    int nb_2nw   = (2 * N + 3) / 4;

    // 1. casts
    k_cast2<<<dim3(nb_cast, 2), 256, 0, stream>>>(x_glom, xb_glom, x_imm, xb_imm,
                                                  (int)(ND / 4));
    // 2. W transposes + counts zero
    k_prep_wtz<<<dim3(256, 5), 256, 0, stream>>>(W_gcn, Wr, Wl, W_gin, Wt,
                                                 counts, 3 * N);
    // 3-7. CSR build + degrees
    k_hist3<<<nb_3e, 256, 0, stream>>>(ei_gg, ei_ig, ei_gi, counts, E, N);
    k_scan_tile<<<dim3(TPT, 3), 256, 0, stream>>>(counts, rows, parts, N, TPT);
    k_scan_part<<<3, 128, 0, stream>>>(parts, TPT);
    k_scan_final<<<nb_3n, 256, 0, stream>>>(rows, cur, parts, deg, N, TPT, E);
    k_scatter3<<<nb_3e, 256, 0, stream>>>(ei_gg, ei_ig, ei_gi, ew_gg, ea_ig, cur,
                                          src_gcn, val_gcn, src_gat, val_gat,
                                          src_gin, deg, E, N);
    // 8. merged projections
    k_proj<<<dim3((N + 63) / 64, 12), 256, 0, stream>>>(
        xb_glom, xb_imm, Wt, deg, br, bl, xws_b, hr_b, hl_b, N);
    // 9. fused gathers
    k_gather_fused<<<nb_2nw, 256, 0, stream>>>(
        xws_b, hl_b, hr_b, deg,
        rows, src_gcn, val_gcn,
        rows + (N + 1), src_gat, val_gat,
        We, att, b_gcn, b_gat, gamma, beta, glom_out,
        xb_glom, x_imm, eps,
        rows + 2 * (N + 1), src_gin, agg_b, N);
    // 10. GIN GEMM + fused LN + ReLU
    k_gin_gemm_ln<<<(N + 63) / 64, 256, 0, stream>>>(
        agg_b, Wt + 3 * D * D, b_gin, gamma, beta, imm_out, N);
}

// Round 7
// 292.043 us; speedup vs baseline: 12.3926x; 1.1417x over previous
//
#include <hip/hip_runtime.h>

// HeteroMessagePassingLayer Round 7:
//  - gather: back to 4-wide unroll (R6's 8-wide cost occupancy), node
//    scalarized via readfirstlane -> CSR index/val loads go to SMEM pipe
//  - GEMMs: 64 rows x 64 cols per wave (acc[4][4]) -> 2:1 MFMA:load ratio
//  - hist/scatter: grid.y=3 (no div/mod)

constexpr int D = 256;

typedef __attribute__((ext_vector_type(4))) float f32x4v;
typedef __attribute__((ext_vector_type(8))) short short8;

// ---------------------------------------------------------------- utilities
__device__ __forceinline__ float4 ld4(const float* p) {
    return *reinterpret_cast<const float4*>(p);
}
__device__ __forceinline__ void st4(float* p, float4 v) {
    *reinterpret_cast<float4*>(p) = v;
}
__device__ __forceinline__ unsigned short f2bf(float f) {
    unsigned u = __float_as_uint(f);
    u = u + 0x7FFFu + ((u >> 16) & 1u);
    return (unsigned short)(u >> 16);
}
__device__ __forceinline__ float bf2f(unsigned short u) {
    return __uint_as_float(((unsigned)u) << 16);
}
__device__ __forceinline__ float4 ldb4(const unsigned short* p) {
    ushort4 u = *reinterpret_cast<const ushort4*>(p);
    return make_float4(bf2f(u.x), bf2f(u.y), bf2f(u.z), bf2f(u.w));
}
__device__ __forceinline__ float wave_sum(float p) {
#pragma unroll
    for (int off = 32; off > 0; off >>= 1) p += __shfl_xor(p, off, 64);
    return p;
}
__device__ __forceinline__ float gat_partial(float4 h, float4 hrv, float ea,
                                             float4 We4, float4 att4) {
    float z, pp = 0.f;
    z = h.x + hrv.x + ea * We4.x; z *= (z > 0.f) ? 1.0f : 0.2f; pp += z * att4.x;
    z = h.y + hrv.y + ea * We4.y; z *= (z > 0.f) ? 1.0f : 0.2f; pp += z * att4.y;
    z = h.z + hrv.z + ea * We4.z; z *= (z > 0.f) ? 1.0f : 0.2f; pp += z * att4.z;
    z = h.w + hrv.w + ea * We4.w; z *= (z > 0.f) ? 1.0f : 0.2f; pp += z * att4.w;
    return pp;
}

// ------------------------------------------------------------- cast f32->bf16
__global__ void k_cast2(const float* __restrict__ x0, unsigned short* __restrict__ y0,
                        const float* __restrict__ x1, unsigned short* __restrict__ y1,
                        int n4)
{
    int i = blockIdx.x * 256 + threadIdx.x;
    if (i >= n4) return;
    const float* x = blockIdx.y ? x1 : x0;
    unsigned short* y = blockIdx.y ? y1 : y0;
    float4 v = ld4(x + (size_t)i * 4);
    ushort4 o;
    o.x = f2bf(v.x); o.y = f2bf(v.y); o.z = f2bf(v.z); o.w = f2bf(v.w);
    *reinterpret_cast<ushort4*>(y + (size_t)i * 4) = o;
}

// ---------- W transposes (bf16, order Wgcn,Wr,Wl,Wgin) + counts zero
__global__ void k_prep_wtz(const float* __restrict__ W0, const float* __restrict__ W1,
                           const float* __restrict__ W2, const float* __restrict__ W3,
                           unsigned short* __restrict__ Wt, int* __restrict__ counts,
                           int n3)
{
    int w = blockIdx.y;
    int i = blockIdx.x * 256 + threadIdx.x;
    if (w < 4) {
        const float* W = (w == 0) ? W0 : (w == 1) ? W1 : (w == 2) ? W2 : W3;
        int c = i >> 8, k = i & 255;
        Wt[(size_t)w * D * D + i] = f2bf(W[k * D + c]);
    } else {
        if (i < n3) counts[i] = 0;
    }
}

// --------------------------------------------- merged projection GEMM
// wave = 64 rows x 64 cols (acc[4][4]).  block = 4 waves = 256 rows.
// grid.y < 8 : A=xb_glom, Bt=Wt[0..1]: c<256 -> xws (rowscale rsqrt(deg)),
//              c>=256 -> hr (+br).   grid.y >= 8: A=xb_imm -> hl (+bl)
__global__ __launch_bounds__(256)
void k_proj(const unsigned short* __restrict__ xbg,
            const unsigned short* __restrict__ xbi,
            const unsigned short* __restrict__ Wt,
            const float* __restrict__ deg,
            const float* __restrict__ br, const float* __restrict__ bl,
            unsigned short* __restrict__ xws, unsigned short* __restrict__ hr,
            unsigned short* __restrict__ hl, int M)
{
    const int lane = threadIdx.x & 63;
    const int wave = threadIdx.x >> 6;
    const int lr = lane & 15;
    const int lk = lane >> 4;
    const int yy = blockIdx.y;
    const int row0 = blockIdx.x * 256 + wave * 64;

    const unsigned short* A;
    const unsigned short* Bt0;
    int col0;
    if (yy < 8) { A = xbg; Bt0 = Wt;             col0 = yy * 64; }
    else        { A = xbi; Bt0 = Wt + 2 * D * D; col0 = (yy - 8) * 64; }

    const unsigned short* ap[4];
#pragma unroll
    for (int rf = 0; rf < 4; ++rf) {
        int arow = row0 + rf * 16 + lr;
        int arow_c = (arow < M) ? arow : (M - 1);
        ap[rf] = A + (size_t)arow_c * D + lk * 8;
    }
    const unsigned short* bp = Bt0 + (size_t)(col0 + lr) * D + lk * 8;

    f32x4v acc[4][4] = {};
#pragma unroll
    for (int k0 = 0; k0 < 256; k0 += 32) {
        short8 af[4], bf[4];
#pragma unroll
        for (int rf = 0; rf < 4; ++rf)
            af[rf] = *reinterpret_cast<const short8*>(ap[rf] + k0);
#pragma unroll
        for (int nf = 0; nf < 4; ++nf)
            bf[nf] = *reinterpret_cast<const short8*>(bp + (size_t)nf * 16 * D + k0);
#pragma unroll
        for (int rf = 0; rf < 4; ++rf)
#pragma unroll
            for (int nf = 0; nf < 4; ++nf)
                acc[rf][nf] = __builtin_amdgcn_mfma_f32_16x16x32_bf16(
                    af[rf], bf[nf], acc[rf][nf], 0, 0, 0);
    }

#pragma unroll
    for (int nf = 0; nf < 4; ++nf) {
        int c = col0 + nf * 16 + lr;
        unsigned short* dst;
        int cc;
        float bv;
        bool scaled;
        if (yy < 8) {
            if (c < 256) { dst = xws; cc = c;       bv = 0.f;    scaled = true;  }
            else         { dst = hr;  cc = c - 256; bv = br[cc]; scaled = false; }
        } else           { dst = hl;  cc = c;       bv = bl[cc]; scaled = false; }
#pragma unroll
        for (int rf = 0; rf < 4; ++rf) {
#pragma unroll
            for (int i = 0; i < 4; ++i) {
                int r = row0 + rf * 16 + 4 * lk + i;
                if (r < M) {
                    float sc = scaled ? rsqrtf(deg[r]) : 1.0f;
                    dst[(size_t)r * D + cc] = f2bf(acc[rf][nf][i] * sc + bv);
                }
            }
        }
    }
}

// ------------------------------------- GIN GEMM + fused LayerNorm + ReLU
// block = 64 rows x 256 cols; wave = 64 rows x 64-col slice (acc[4][4]);
// LN partials reduced across the 4 waves via LDS.
__global__ __launch_bounds__(256)
void k_gin_gemm_ln(const unsigned short* __restrict__ A,
                   const unsigned short* __restrict__ Bt,
                   const float* __restrict__ bias,
                   const float* __restrict__ gamma, const float* __restrict__ beta,
                   float* __restrict__ out, int M)
{
    __shared__ float lds_s[4][64];
    __shared__ float lds_q[4][64];
    const int lane = threadIdx.x & 63;
    const int wave = threadIdx.x >> 6;
    const int lr = lane & 15;
    const int lk = lane >> 4;
    const int row0 = blockIdx.x * 64;
    const int col0 = wave * 64;

    const unsigned short* ap[4];
#pragma unroll
    for (int rf = 0; rf < 4; ++rf) {
        int arow = row0 + rf * 16 + lr;
        int arow_c = (arow < M) ? arow : (M - 1);
        ap[rf] = A + (size_t)arow_c * D + lk * 8;
    }
    const unsigned short* bp = Bt + (size_t)(col0 + lr) * D + lk * 8;

    f32x4v acc[4][4] = {};
#pragma unroll
    for (int k0 = 0; k0 < 256; k0 += 32) {
        short8 af[4], bf[4];
#pragma unroll
        for (int rf = 0; rf < 4; ++rf)
            af[rf] = *reinterpret_cast<const short8*>(ap[rf] + k0);
#pragma unroll
        for (int nf = 0; nf < 4; ++nf)
            bf[nf] = *reinterpret_cast<const short8*>(bp + (size_t)nf * 16 * D + k0);
#pragma unroll
        for (int rf = 0; rf < 4; ++rf)
#pragma unroll
            for (int nf = 0; nf < 4; ++nf)
                acc[rf][nf] = __builtin_amdgcn_mfma_f32_16x16x32_bf16(
                    af[rf], bf[nf], acc[rf][nf], 0, 0, 0);
    }

    float bv[4], gv[4], be[4];
#pragma unroll
    for (int nf = 0; nf < 4; ++nf) {
        int c = col0 + nf * 16 + lr;
        bv[nf] = bias[c]; gv[nf] = gamma[c]; be[nf] = beta[c];
    }

    // per-(rf,i) partial sums over this wave's 64 cols
#pragma unroll
    for (int rf = 0; rf < 4; ++rf) {
        float ps[4], pq[4];
#pragma unroll
        for (int i = 0; i < 4; ++i) {
            float s = 0.f, q = 0.f;
#pragma unroll
            for (int nf = 0; nf < 4; ++nf) {
                float v = acc[rf][nf][i] + bv[nf];
                acc[rf][nf][i] = v;
                s += v; q += v * v;
            }
            ps[i] = s; pq[i] = q;
        }
#pragma unroll
        for (int off = 1; off < 16; off <<= 1) {
#pragma unroll
            for (int i = 0; i < 4; ++i) {
                ps[i] += __shfl_xor(ps[i], off, 64);
                pq[i] += __shfl_xor(pq[i], off, 64);
            }
        }
        if (lr == 0) {
#pragma unroll
            for (int i = 0; i < 4; ++i) {
                lds_s[wave][rf * 16 + lk * 4 + i] = ps[i];
                lds_q[wave][rf * 16 + lk * 4 + i] = pq[i];
            }
        }
    }
    __syncthreads();

#pragma unroll
    for (int rf = 0; rf < 4; ++rf) {
#pragma unroll
        for (int i = 0; i < 4; ++i) {
            int rl = rf * 16 + 4 * lk + i;
            float s = lds_s[0][rl] + lds_s[1][rl] + lds_s[2][rl] + lds_s[3][rl];
            float q = lds_q[0][rl] + lds_q[1][rl] + lds_q[2][rl] + lds_q[3][rl];
            float mu  = s * (1.0f / 256.0f);
            float var = q * (1.0f / 256.0f) - mu * mu;
            float rs  = rsqrtf(var + 1e-5f);
            int r = row0 + rl;
            if (r < M) {
#pragma unroll
                for (int nf = 0; nf < 4; ++nf) {
                    out[(size_t)r * D + col0 + nf * 16 + lr] =
                        fmaxf(0.f, (acc[rf][nf][i] - mu) * rs * gv[nf] + be[nf]);
                }
            }
        }
    }
}

// --------------------------------------------------------------- CSR build
__global__ void k_hist3(const int* __restrict__ ei_gg, const int* __restrict__ ei_ig,
                        const int* __restrict__ ei_gi, int* __restrict__ counts,
                        int E, int N)
{
    int e = blockIdx.x * 256 + threadIdx.x;
    if (e >= E) return;
    int t = blockIdx.y;
    const int* ei = (t == 0) ? ei_gg : (t == 1) ? ei_ig : ei_gi;
    atomicAdd(&counts[t * N + ei[E + e]], 1);
}

__global__ __launch_bounds__(256)
void k_scan_tile(const int* __restrict__ counts, int* __restrict__ rows,
                 int* __restrict__ partials, int N, int TPT)
{
    int t = blockIdx.y, tile = blockIdx.x;
    int i = tile * 256 + threadIdx.x;
    __shared__ int sh[256];
    int v = (i < N) ? counts[(size_t)t * N + i] : 0;
    sh[threadIdx.x] = v;
    __syncthreads();
#pragma unroll
    for (int off = 1; off < 256; off <<= 1) {
        int add = (threadIdx.x >= off) ? sh[threadIdx.x - off] : 0;
        __syncthreads();
        sh[threadIdx.x] += add;
        __syncthreads();
    }
    if (i < N) rows[(size_t)t * (N + 1) + i] = sh[threadIdx.x] - v;
    if (threadIdx.x == 255) partials[t * TPT + tile] = sh[255];
}

__global__ __launch_bounds__(128)
void k_scan_part(int* __restrict__ partials, int TPT)
{
    int t = blockIdx.x;
    __shared__ int sh[128];
    int v = (threadIdx.x < TPT) ? partials[t * TPT + threadIdx.x] : 0;
    sh[threadIdx.x] = v;
    __syncthreads();
#pragma unroll
    for (int off = 1; off < 128; off <<= 1) {
        int add = (threadIdx.x >= off) ? sh[threadIdx.x - off] : 0;
        __syncthreads();
        sh[threadIdx.x] += add;
        __syncthreads();
    }
    if (threadIdx.x < TPT) partials[t * TPT + threadIdx.x] = sh[threadIdx.x] - v;
}

__global__ void k_scan_final(int* __restrict__ rows, int* __restrict__ cur,
                             const int* __restrict__ partials, float* __restrict__ deg,
                             int N, int TPT, int E)
{
    int i = blockIdx.x * 256 + threadIdx.x;
    if (i >= 3 * N) return;
    int t = i / N, j = i - t * N;
    int r = rows[(size_t)t * (N + 1) + j] + partials[t * TPT + (j >> 8)];
    rows[(size_t)t * (N + 1) + j] = r;
    cur[(size_t)t * N + j] = r;
    if (j == 0) rows[(size_t)t * (N + 1) + N] = E;
    if (t == 0) deg[j] = 1.0f;       // self-loop weight
}

__global__ void k_scatter3(const int* __restrict__ ei_gg, const int* __restrict__ ei_ig,
                           const int* __restrict__ ei_gi, const float* __restrict__ ew_gg,
                           const float* __restrict__ ea_ig, int* __restrict__ cur,
                           int* __restrict__ src_gcn, float* __restrict__ val_gcn,
                           int* __restrict__ src_gat, float* __restrict__ val_gat,
                           int* __restrict__ src_gin, float* __restrict__ deg,
                           int E, int N)
{
    int e = blockIdx.x * 256 + threadIdx.x;
    if (e >= E) return;
    int t = blockIdx.y;
    if (t == 0) {
        int s = ei_gg[e], d = ei_gg[E + e];
        int pos = atomicAdd(&cur[d], 1);
        src_gcn[pos] = s;
        float w = ew_gg[e];
        val_gcn[pos] = w;
        atomicAdd(&deg[d], w);
    } else if (t == 1) {
        int s = ei_ig[e], d = ei_ig[E + e];
        int pos = atomicAdd(&cur[N + d], 1);
        src_gat[pos] = s;
        val_gat[pos] = ea_ig[e];
    } else {
        int s = ei_gi[e], d = ei_gi[E + e];
        int pos = atomicAdd(&cur[2 * N + d], 1);
        src_gin[pos] = s;
    }
}

// ================== fused gather: glom (GCN+GATv2+LN) and GIN, one launch
__global__ __launch_bounds__(256)
void k_gather_fused(const unsigned short* __restrict__ xws,
                    const unsigned short* __restrict__ hl,
                    const unsigned short* __restrict__ hr,
                    const float* __restrict__ deg,
                    const int* __restrict__ rows_gcn, const int* __restrict__ src_gcn,
                    const float* __restrict__ val_gcn,
                    const int* __restrict__ rows_gat, const int* __restrict__ src_gat,
                    const float* __restrict__ val_gat,
                    const float* __restrict__ We, const float* __restrict__ att,
                    const float* __restrict__ b_gcn, const float* __restrict__ b_gat,
                    const float* __restrict__ gamma, const float* __restrict__ beta,
                    float* __restrict__ glom_out,
                    const unsigned short* __restrict__ xb_glom,
                    const float* __restrict__ x_imm, const float* __restrict__ eps,
                    const int* __restrict__ rows_gin, const int* __restrict__ src_gin,
                    unsigned short* __restrict__ agg,
                    int N)
{
    // node id is wave-uniform; readfirstlane makes it PROVABLY so ->
    // CSR rows/src/val loads compile to scalar (SMEM) loads.
    int gw   = __builtin_amdgcn_readfirstlane((blockIdx.x * 256 + threadIdx.x) >> 6);
    int lane = threadIdx.x & 63;

    if (gw < N) {
        // ------------------------------ glom path -------------------------
        int node = gw;
        float4 We4  = ld4(&We[lane * 4]);
        float4 att4 = ld4(&att[lane * 4]);
        float4 hrv  = ldb4(&hr[(size_t)node * D + lane * 4]);

        float di = rsqrtf(deg[node]);
        float4 acc = ldb4(&xws[(size_t)node * D + lane * 4]);   // = dinv*xw
        float4 g0  = ld4(&b_gcn[lane * 4]);
        float4 a0  = ld4(&b_gat[lane * 4]);
        acc.x = di * acc.x + g0.x + a0.x;
        acc.y = di * acc.y + g0.y + a0.y;
        acc.z = di * acc.z + g0.z + a0.z;
        acc.w = di * acc.w + g0.w + a0.w;

        // ---- GCN neighbor sum, 4 edges in flight ----
        int p  = rows_gcn[node];
        int p1 = rows_gcn[node + 1];
        for (; p + 4 <= p1; p += 4) {
            int   s[4];
            float cf[4];
            float4 v[4];
#pragma unroll
            for (int j = 0; j < 4; ++j) { s[j] = src_gcn[p + j]; cf[j] = val_gcn[p + j] * di; }
#pragma unroll
            for (int j = 0; j < 4; ++j) v[j] = ldb4(&xws[(size_t)s[j] * D + lane * 4]);
#pragma unroll
            for (int j = 0; j < 4; ++j) {
                acc.x += cf[j] * v[j].x; acc.y += cf[j] * v[j].y;
                acc.z += cf[j] * v[j].z; acc.w += cf[j] * v[j].w;
            }
        }
        for (; p < p1; ++p) {
            int sx = src_gcn[p];
            float cx = val_gcn[p] * di;
            float4 v = ldb4(&xws[(size_t)sx * D + lane * 4]);
            acc.x += cx * v.x; acc.y += cx * v.y;
            acc.z += cx * v.z; acc.w += cx * v.w;
        }

        // ---- GATv2 online softmax, 4 edges in flight ----
        int q  = rows_gat[node];
        int q1 = rows_gat[node + 1];
        int has = (q1 > q);
        float m = -3.4e38f, den = 0.f;
        float4 ag = make_float4(0.f, 0.f, 0.f, 0.f);
        for (; q + 4 <= q1; q += 4) {
            int   s[4];
            float ev[4];
            float4 h[4];
            float pp[4];
#pragma unroll
            for (int j = 0; j < 4; ++j) { s[j] = src_gat[q + j]; ev[j] = val_gat[q + j]; }
#pragma unroll
            for (int j = 0; j < 4; ++j) h[j] = ldb4(&hl[(size_t)s[j] * D + lane * 4]);
#pragma unroll
            for (int j = 0; j < 4; ++j) pp[j] = wave_sum(gat_partial(h[j], hrv, ev[j], We4, att4));
            float mb = fmaxf(fmaxf(pp[0], pp[1]), fmaxf(pp[2], pp[3]));
            float mn = fmaxf(m, mb);
            float scale = __expf(m - mn);
            float x[4];
#pragma unroll
            for (int j = 0; j < 4; ++j) x[j] = __expf(pp[j] - mn);
            den = den * scale + (x[0] + x[1]) + (x[2] + x[3]);
            float axx = 0.f, ayy = 0.f, azz = 0.f, aww = 0.f;
#pragma unroll
            for (int j = 0; j < 4; ++j) {
                axx += x[j] * h[j].x; ayy += x[j] * h[j].y;
                azz += x[j] * h[j].z; aww += x[j] * h[j].w;
            }
            ag.x = ag.x * scale + axx; ag.y = ag.y * scale + ayy;
            ag.z = ag.z * scale + azz; ag.w = ag.w * scale + aww;
            m = mn;
        }
        for (; q < q1; ++q) {
            int sx = src_gat[q];
            float ea = val_gat[q];
            float4 h = ldb4(&hl[(size_t)sx * D + lane * 4]);
            float pp = wave_sum(gat_partial(h, hrv, ea, We4, att4));
            float mn = fmaxf(m, pp);
            float scale = __expf(m - mn);
            float ex = __expf(pp - mn);
            den = den * scale + ex;
            ag.x = ag.x * scale + ex * h.x;
            ag.y = ag.y * scale + ex * h.y;
            ag.z = ag.z * scale + ex * h.z;
            ag.w = ag.w * scale + ex * h.w;
            m = mn;
        }
        if (has) {
            float inv = 1.0f / den;
            acc.x += ag.x * inv; acc.y += ag.y * inv;
            acc.z += ag.z * inv; acc.w += ag.w * inv;
        }

        // ---- LayerNorm + ReLU ----
        float s_ = acc.x + acc.y + acc.z + acc.w;
        float sq = acc.x * acc.x + acc.y * acc.y + acc.z * acc.z + acc.w * acc.w;
#pragma unroll
        for (int off = 32; off > 0; off >>= 1) {
            s_ += __shfl_xor(s_, off, 64);
            sq += __shfl_xor(sq, off, 64);
        }
        float mu  = s_ * (1.0f / 256.0f);
        float var = sq * (1.0f / 256.0f) - mu * mu;
        float rs  = rsqrtf(var + 1e-5f);
        float4 g = ld4(&gamma[lane * 4]);
        float4 b = ld4(&beta[lane * 4]);
        float4 o;
        o.x = fmaxf(0.f, (acc.x - mu) * rs * g.x + b.x);
        o.y = fmaxf(0.f, (acc.y - mu) * rs * g.y + b.y);
        o.z = fmaxf(0.f, (acc.z - mu) * rs * g.z + b.z);
        o.w = fmaxf(0.f, (acc.w - mu) * rs * g.w + b.w);
        st4(&glom_out[(size_t)node * D + lane * 4], o);
    } else if (gw < 2 * N) {
        // ------------------------------ gin path --------------------------
        int node = gw - N;
        float c = 1.0f + eps[0];
        float4 acc = ld4(&x_imm[(size_t)node * D + lane * 4]);
        acc.x *= c; acc.y *= c; acc.z *= c; acc.w *= c;
        int p  = rows_gin[node];
        int p1 = rows_gin[node + 1];
        for (; p + 4 <= p1; p += 4) {
            int s[4];
            float4 v[4];
#pragma unroll
            for (int j = 0; j < 4; ++j) s[j] = src_gin[p + j];
#pragma unroll
            for (int j = 0; j < 4; ++j) v[j] = ldb4(&xb_glom[(size_t)s[j] * D + lane * 4]);
            acc.x += (v[0].x + v[1].x) + (v[2].x + v[3].x);
            acc.y += (v[0].y + v[1].y) + (v[2].y + v[3].y);
            acc.z += (v[0].z + v[1].z) + (v[2].z + v[3].z);
            acc.w += (v[0].w + v[1].w) + (v[2].w + v[3].w);
        }
        for (; p < p1; ++p) {
            int sx = src_gin[p];
            float4 v = ldb4(&xb_glom[(size_t)sx * D + lane * 4]);
            acc.x += v.x; acc.y += v.y; acc.z += v.z; acc.w += v.w;
        }
        ushort4 o;
        o.x = f2bf(acc.x); o.y = f2bf(acc.y); o.z = f2bf(acc.z); o.w = f2bf(acc.w);
        *reinterpret_cast<ushort4*>(agg + (size_t)node * D + lane * 4) = o;
    }
}

// ------------------------------------------------------------------ launch
extern "C" void kernel_launch(void* const* d_in, const int* in_sizes, int n_in,
                              void* d_out, int out_size, void* d_ws, size_t ws_size,
                              hipStream_t stream)
{
    const float* x_glom = (const float*)d_in[0];
    const float* x_imm  = (const float*)d_in[1];
    const float* ew_gg  = (const float*)d_in[2];
    const float* ea_ig  = (const float*)d_in[3];
    const float* W_gcn  = (const float*)d_in[4];
    const float* b_gcn  = (const float*)d_in[5];
    const float* Wl     = (const float*)d_in[6];
    const float* bl     = (const float*)d_in[7];
    const float* Wr     = (const float*)d_in[8];
    const float* br     = (const float*)d_in[9];
    const float* att    = (const float*)d_in[10];
    const float* We     = (const float*)d_in[11];
    const float* b_gat  = (const float*)d_in[12];
    const float* eps    = (const float*)d_in[13];
    const float* W_gin  = (const float*)d_in[14];
    const float* b_gin  = (const float*)d_in[15];
    const float* gamma  = (const float*)d_in[16];
    const float* beta   = (const float*)d_in[17];
    const int*   ei_gg  = (const int*)d_in[18];
    const int*   ei_ig  = (const int*)d_in[19];
    const int*   ei_gi  = (const int*)d_in[20];

    const int N = in_sizes[0] / D;     // 20000
    const int E = in_sizes[2];         // 320000
    const size_t ND = (size_t)N * D;
    const int TPT = (N + 255) / 256;

    // ---- workspace layout ----
    char* base = (char*)d_ws;
    size_t off = 0;
    auto alloc = [&](size_t bytes) {
        void* p = base + off;
        off = (off + bytes + 255) & ~(size_t)255;
        return p;
    };
    unsigned short* xb_glom = (unsigned short*)alloc(ND * 2);
    unsigned short* xb_imm  = (unsigned short*)alloc(ND * 2);
    unsigned short* xws_b   = (unsigned short*)alloc(ND * 2);
    unsigned short* hl_b    = (unsigned short*)alloc(ND * 2);
    unsigned short* hr_b    = (unsigned short*)alloc(ND * 2);
    unsigned short* agg_b   = (unsigned short*)alloc(ND * 2);
    unsigned short* Wt      = (unsigned short*)alloc(4 * D * D * 2);
    float* deg     = (float*)alloc(N * 4);
    float* val_gcn = (float*)alloc(E * 4);
    float* val_gat = (float*)alloc(E * 4);
    int*   counts  = (int*)alloc(3 * (size_t)N * 4);
    int*   rows    = (int*)alloc(3 * (size_t)(N + 1) * 4);
    int*   cur     = (int*)alloc(3 * (size_t)N * 4);
    int*   parts   = (int*)alloc(3 * (size_t)TPT * 4);
    int*   src_gcn = (int*)alloc(E * 4);
    int*   src_gat = (int*)alloc(E * 4);
    int*   src_gin = (int*)alloc(E * 4);

    float* glom_out = (float*)d_out;
    float* imm_out  = (float*)d_out + ND;

    int nb_cast  = (int)((ND / 4 + 255) / 256);
    int nb_3n    = (3 * N + 255) / 256;
    int nb_e     = (E + 255) / 256;
    int nb_2nw   = (2 * N + 3) / 4;

    // 1. casts
    k_cast2<<<dim3(nb_cast, 2), 256, 0, stream>>>(x_glom, xb_glom, x_imm, xb_imm,
                                                  (int)(ND / 4));
    // 2. W transposes + counts zero
    k_prep_wtz<<<dim3(256, 5), 256, 0, stream>>>(W_gcn, Wr, Wl, W_gin, Wt,
                                                 counts, 3 * N);
    // 3-7. CSR build + degrees
    k_hist3<<<dim3(nb_e, 3), 256, 0, stream>>>(ei_gg, ei_ig, ei_gi, counts, E, N);
    k_scan_tile<<<dim3(TPT, 3), 256, 0, stream>>>(counts, rows, parts, N, TPT);
    k_scan_part<<<3, 128, 0, stream>>>(parts, TPT);
    k_scan_final<<<nb_3n, 256, 0, stream>>>(rows, cur, parts, deg, N, TPT, E);
    k_scatter3<<<dim3(nb_e, 3), 256, 0, stream>>>(ei_gg, ei_ig, ei_gi, ew_gg, ea_ig,
                                                  cur, src_gcn, val_gcn, src_gat,
                                                  val_gat, src_gin, deg, E, N);
    // 8. merged projections (wave = 64x64)
    k_proj<<<dim3((N + 255) / 256, 12), 256, 0, stream>>>(
        xb_glom, xb_imm, Wt, deg, br, bl, xws_b, hr_b, hl_b, N);
    // 9. fused gathers
    k_gather_fused<<<nb_2nw, 256, 0, stream>>>(
        xws_b, hl_b, hr_b, deg,
        rows, src_gcn, val_gcn,
        rows + (N + 1), src_gat, val_gat,
        We, att, b_gcn, b_gat, gamma, beta, glom_out,
        xb_glom, x_imm, eps,
        rows + 2 * (N + 1), src_gin, agg_b, N);
    // 10. GIN GEMM + fused LN + ReLU (block = 64 rows x 256 cols)
    k_gin_gemm_ln<<<(N + 63) / 64, 256, 0, stream>>>(
        agg_b, Wt + 3 * D * D, b_gin, gamma, beta, imm_out, N);
}

// Round 8
// 250.260 us; speedup vs baseline: 14.4616x; 1.1670x over previous
//
#include <hip/hip_runtime.h>

// HeteroMessagePassingLayer Round 8:
//  - CSR build: rank assigned in histogram (coalesced), scatter is atomic-free
//  - (src,val) packed as int2 -> one 8B random store per edge (was 2x4B)
//  - deg accumulation in hist; deg init in prep kernel
//  - gather reads packed CSR via scalar 8B loads

constexpr int D = 256;

typedef __attribute__((ext_vector_type(4))) float f32x4v;
typedef __attribute__((ext_vector_type(8))) short short8;

// ---------------------------------------------------------------- utilities
__device__ __forceinline__ float4 ld4(const float* p) {
    return *reinterpret_cast<const float4*>(p);
}
__device__ __forceinline__ void st4(float* p, float4 v) {
    *reinterpret_cast<float4*>(p) = v;
}
__device__ __forceinline__ unsigned short f2bf(float f) {
    unsigned u = __float_as_uint(f);
    u = u + 0x7FFFu + ((u >> 16) & 1u);
    return (unsigned short)(u >> 16);
}
__device__ __forceinline__ float bf2f(unsigned short u) {
    return __uint_as_float(((unsigned)u) << 16);
}
__device__ __forceinline__ float4 ldb4(const unsigned short* p) {
    ushort4 u = *reinterpret_cast<const ushort4*>(p);
    return make_float4(bf2f(u.x), bf2f(u.y), bf2f(u.z), bf2f(u.w));
}
__device__ __forceinline__ float wave_sum(float p) {
#pragma unroll
    for (int off = 32; off > 0; off >>= 1) p += __shfl_xor(p, off, 64);
    return p;
}
__device__ __forceinline__ float gat_partial(float4 h, float4 hrv, float ea,
                                             float4 We4, float4 att4) {
    float z, pp = 0.f;
    z = h.x + hrv.x + ea * We4.x; z *= (z > 0.f) ? 1.0f : 0.2f; pp += z * att4.x;
    z = h.y + hrv.y + ea * We4.y; z *= (z > 0.f) ? 1.0f : 0.2f; pp += z * att4.y;
    z = h.z + hrv.z + ea * We4.z; z *= (z > 0.f) ? 1.0f : 0.2f; pp += z * att4.z;
    z = h.w + hrv.w + ea * We4.w; z *= (z > 0.f) ? 1.0f : 0.2f; pp += z * att4.w;
    return pp;
}

// ------------------------------------------------------------- cast f32->bf16
__global__ void k_cast2(const float* __restrict__ x0, unsigned short* __restrict__ y0,
                        const float* __restrict__ x1, unsigned short* __restrict__ y1,
                        int n4)
{
    int i = blockIdx.x * 256 + threadIdx.x;
    if (i >= n4) return;
    const float* x = blockIdx.y ? x1 : x0;
    unsigned short* y = blockIdx.y ? y1 : y0;
    float4 v = ld4(x + (size_t)i * 4);
    ushort4 o;
    o.x = f2bf(v.x); o.y = f2bf(v.y); o.z = f2bf(v.z); o.w = f2bf(v.w);
    *reinterpret_cast<ushort4*>(y + (size_t)i * 4) = o;
}

// ---------- W transposes (bf16) + counts zero + deg init;  grid (256,5)
__global__ void k_prep_wtz(const float* __restrict__ W0, const float* __restrict__ W1,
                           const float* __restrict__ W2, const float* __restrict__ W3,
                           unsigned short* __restrict__ Wt, int* __restrict__ counts,
                           float* __restrict__ deg, int n3, int N)
{
    int w = blockIdx.y;
    int i = blockIdx.x * 256 + threadIdx.x;
    if (w < 4) {
        const float* W = (w == 0) ? W0 : (w == 1) ? W1 : (w == 2) ? W2 : W3;
        int c = i >> 8, k = i & 255;
        Wt[(size_t)w * D * D + i] = f2bf(W[k * D + c]);
    } else {
        if (i < n3) counts[i] = 0;
        if (i < N) deg[i] = 1.0f;      // self-loop weight
    }
}

// --------------------------------------------- merged projection GEMM
__global__ __launch_bounds__(256)
void k_proj(const unsigned short* __restrict__ xbg,
            const unsigned short* __restrict__ xbi,
            const unsigned short* __restrict__ Wt,
            const float* __restrict__ deg,
            const float* __restrict__ br, const float* __restrict__ bl,
            unsigned short* __restrict__ xws, unsigned short* __restrict__ hr,
            unsigned short* __restrict__ hl, int M)
{
    const int lane = threadIdx.x & 63;
    const int wave = threadIdx.x >> 6;
    const int lr = lane & 15;
    const int lk = lane >> 4;
    const int yy = blockIdx.y;
    const int row0 = blockIdx.x * 256 + wave * 64;

    const unsigned short* A;
    const unsigned short* Bt0;
    int col0;
    if (yy < 8) { A = xbg; Bt0 = Wt;             col0 = yy * 64; }
    else        { A = xbi; Bt0 = Wt + 2 * D * D; col0 = (yy - 8) * 64; }

    const unsigned short* ap[4];
#pragma unroll
    for (int rf = 0; rf < 4; ++rf) {
        int arow = row0 + rf * 16 + lr;
        int arow_c = (arow < M) ? arow : (M - 1);
        ap[rf] = A + (size_t)arow_c * D + lk * 8;
    }
    const unsigned short* bp = Bt0 + (size_t)(col0 + lr) * D + lk * 8;

    f32x4v acc[4][4] = {};
#pragma unroll
    for (int k0 = 0; k0 < 256; k0 += 32) {
        short8 af[4], bf[4];
#pragma unroll
        for (int rf = 0; rf < 4; ++rf)
            af[rf] = *reinterpret_cast<const short8*>(ap[rf] + k0);
#pragma unroll
        for (int nf = 0; nf < 4; ++nf)
            bf[nf] = *reinterpret_cast<const short8*>(bp + (size_t)nf * 16 * D + k0);
#pragma unroll
        for (int rf = 0; rf < 4; ++rf)
#pragma unroll
            for (int nf = 0; nf < 4; ++nf)
                acc[rf][nf] = __builtin_amdgcn_mfma_f32_16x16x32_bf16(
                    af[rf], bf[nf], acc[rf][nf], 0, 0, 0);
    }

#pragma unroll
    for (int nf = 0; nf < 4; ++nf) {
        int c = col0 + nf * 16 + lr;
        unsigned short* dst;
        int cc;
        float bv;
        bool scaled;
        if (yy < 8) {
            if (c < 256) { dst = xws; cc = c;       bv = 0.f;    scaled = true;  }
            else         { dst = hr;  cc = c - 256; bv = br[cc]; scaled = false; }
        } else           { dst = hl;  cc = c;       bv = bl[cc]; scaled = false; }
#pragma unroll
        for (int rf = 0; rf < 4; ++rf) {
#pragma unroll
            for (int i = 0; i < 4; ++i) {
                int r = row0 + rf * 16 + 4 * lk + i;
                if (r < M) {
                    float sc = scaled ? rsqrtf(deg[r]) : 1.0f;
                    dst[(size_t)r * D + cc] = f2bf(acc[rf][nf][i] * sc + bv);
                }
            }
        }
    }
}

// ------------------------------------- GIN GEMM + fused LayerNorm + ReLU
__global__ __launch_bounds__(256)
void k_gin_gemm_ln(const unsigned short* __restrict__ A,
                   const unsigned short* __restrict__ Bt,
                   const float* __restrict__ bias,
                   const float* __restrict__ gamma, const float* __restrict__ beta,
                   float* __restrict__ out, int M)
{
    __shared__ float lds_s[4][64];
    __shared__ float lds_q[4][64];
    const int lane = threadIdx.x & 63;
    const int wave = threadIdx.x >> 6;
    const int lr = lane & 15;
    const int lk = lane >> 4;
    const int row0 = blockIdx.x * 64;
    const int col0 = wave * 64;

    const unsigned short* ap[4];
#pragma unroll
    for (int rf = 0; rf < 4; ++rf) {
        int arow = row0 + rf * 16 + lr;
        int arow_c = (arow < M) ? arow : (M - 1);
        ap[rf] = A + (size_t)arow_c * D + lk * 8;
    }
    const unsigned short* bp = Bt + (size_t)(col0 + lr) * D + lk * 8;

    f32x4v acc[4][4] = {};
#pragma unroll
    for (int k0 = 0; k0 < 256; k0 += 32) {
        short8 af[4], bf[4];
#pragma unroll
        for (int rf = 0; rf < 4; ++rf)
            af[rf] = *reinterpret_cast<const short8*>(ap[rf] + k0);
#pragma unroll
        for (int nf = 0; nf < 4; ++nf)
            bf[nf] = *reinterpret_cast<const short8*>(bp + (size_t)nf * 16 * D + k0);
#pragma unroll
        for (int rf = 0; rf < 4; ++rf)
#pragma unroll
            for (int nf = 0; nf < 4; ++nf)
                acc[rf][nf] = __builtin_amdgcn_mfma_f32_16x16x32_bf16(
                    af[rf], bf[nf], acc[rf][nf], 0, 0, 0);
    }

    float bv[4], gv[4], be[4];
#pragma unroll
    for (int nf = 0; nf < 4; ++nf) {
        int c = col0 + nf * 16 + lr;
        bv[nf] = bias[c]; gv[nf] = gamma[c]; be[nf] = beta[c];
    }

#pragma unroll
    for (int rf = 0; rf < 4; ++rf) {
        float ps[4], pq[4];
#pragma unroll
        for (int i = 0; i < 4; ++i) {
            float s = 0.f, q = 0.f;
#pragma unroll
            for (int nf = 0; nf < 4; ++nf) {
                float v = acc[rf][nf][i] + bv[nf];
                acc[rf][nf][i] = v;
                s += v; q += v * v;
            }
            ps[i] = s; pq[i] = q;
        }
#pragma unroll
        for (int off = 1; off < 16; off <<= 1) {
#pragma unroll
            for (int i = 0; i < 4; ++i) {
                ps[i] += __shfl_xor(ps[i], off, 64);
                pq[i] += __shfl_xor(pq[i], off, 64);
            }
        }
        if (lr == 0) {
#pragma unroll
            for (int i = 0; i < 4; ++i) {
                lds_s[wave][rf * 16 + lk * 4 + i] = ps[i];
                lds_q[wave][rf * 16 + lk * 4 + i] = pq[i];
            }
        }
    }
    __syncthreads();

#pragma unroll
    for (int rf = 0; rf < 4; ++rf) {
#pragma unroll
        for (int i = 0; i < 4; ++i) {
            int rl = rf * 16 + 4 * lk + i;
            float s = lds_s[0][rl] + lds_s[1][rl] + lds_s[2][rl] + lds_s[3][rl];
            float q = lds_q[0][rl] + lds_q[1][rl] + lds_q[2][rl] + lds_q[3][rl];
            float mu  = s * (1.0f / 256.0f);
            float var = q * (1.0f / 256.0f) - mu * mu;
            float rs  = rsqrtf(var + 1e-5f);
            int r = row0 + rl;
            if (r < M) {
#pragma unroll
                for (int nf = 0; nf < 4; ++nf) {
                    out[(size_t)r * D + col0 + nf * 16 + lr] =
                        fmaxf(0.f, (acc[rf][nf][i] - mu) * rs * gv[nf] + be[nf]);
                }
            }
        }
    }
}

// --------------------------------------------------------------- CSR build
// hist: counts + per-edge rank (coalesced write) + deg accumulation
__global__ void k_hist3(const int* __restrict__ ei_gg, const int* __restrict__ ei_ig,
                        const int* __restrict__ ei_gi, const float* __restrict__ ew_gg,
                        int* __restrict__ counts, int* __restrict__ rank,
                        float* __restrict__ deg, int E, int N)
{
    int e = blockIdx.x * 256 + threadIdx.x;
    if (e >= E) return;
    int t = blockIdx.y;
    const int* ei = (t == 0) ? ei_gg : (t == 1) ? ei_ig : ei_gi;
    int d = ei[E + e];
    rank[(size_t)t * E + e] = atomicAdd(&counts[t * N + d], 1);
    if (t == 0) atomicAdd(&deg[d], ew_gg[e]);
}

__global__ __launch_bounds__(256)
void k_scan_tile(const int* __restrict__ counts, int* __restrict__ rows,
                 int* __restrict__ partials, int N, int TPT)
{
    int t = blockIdx.y, tile = blockIdx.x;
    int i = tile * 256 + threadIdx.x;
    __shared__ int sh[256];
    int v = (i < N) ? counts[(size_t)t * N + i] : 0;
    sh[threadIdx.x] = v;
    __syncthreads();
#pragma unroll
    for (int off = 1; off < 256; off <<= 1) {
        int add = (threadIdx.x >= off) ? sh[threadIdx.x - off] : 0;
        __syncthreads();
        sh[threadIdx.x] += add;
        __syncthreads();
    }
    if (i < N) rows[(size_t)t * (N + 1) + i] = sh[threadIdx.x] - v;
    if (threadIdx.x == 255) partials[t * TPT + tile] = sh[255];
}

__global__ __launch_bounds__(128)
void k_scan_part(int* __restrict__ partials, int TPT)
{
    int t = blockIdx.x;
    __shared__ int sh[128];
    int v = (threadIdx.x < TPT) ? partials[t * TPT + threadIdx.x] : 0;
    sh[threadIdx.x] = v;
    __syncthreads();
#pragma unroll
    for (int off = 1; off < 128; off <<= 1) {
        int add = (threadIdx.x >= off) ? sh[threadIdx.x - off] : 0;
        __syncthreads();
        sh[threadIdx.x] += add;
        __syncthreads();
    }
    if (threadIdx.x < TPT) partials[t * TPT + threadIdx.x] = sh[threadIdx.x] - v;
}

__global__ void k_scan_final(int* __restrict__ rows, const int* __restrict__ partials,
                             int N, int TPT, int E)
{
    int i = blockIdx.x * 256 + threadIdx.x;
    if (i >= 3 * N) return;
    int t = i / N, j = i - t * N;
    rows[(size_t)t * (N + 1) + j] += partials[t * TPT + (j >> 8)];
    if (j == 0) rows[(size_t)t * (N + 1) + N] = E;
}

// atomic-free scatter: pos = rows[d] + rank[e]; packed 8B payloads
__global__ void k_scatter3(const int* __restrict__ ei_gg, const int* __restrict__ ei_ig,
                           const int* __restrict__ ei_gi, const float* __restrict__ ew_gg,
                           const float* __restrict__ ea_ig,
                           const int* __restrict__ rows, const int* __restrict__ rank,
                           int2* __restrict__ pk_gcn, int2* __restrict__ pk_gat,
                           int* __restrict__ src_gin, int E, int N)
{
    int e = blockIdx.x * 256 + threadIdx.x;
    if (e >= E) return;
    int t = blockIdx.y;
    if (t == 0) {
        int s = ei_gg[e], d = ei_gg[E + e];
        int pos = rows[d] + rank[e];
        pk_gcn[pos] = make_int2(s, __float_as_int(ew_gg[e]));
    } else if (t == 1) {
        int s = ei_ig[e], d = ei_ig[E + e];
        int pos = rows[(N + 1) + d] + rank[(size_t)E + e];
        pk_gat[pos] = make_int2(s, __float_as_int(ea_ig[e]));
    } else {
        int s = ei_gi[e], d = ei_gi[E + e];
        int pos = rows[2 * (N + 1) + d] + rank[2 * (size_t)E + e];
        src_gin[pos] = s;
    }
}

// ================== fused gather: glom (GCN+GATv2+LN) and GIN, one launch
__global__ __launch_bounds__(256)
void k_gather_fused(const unsigned short* __restrict__ xws,
                    const unsigned short* __restrict__ hl,
                    const unsigned short* __restrict__ hr,
                    const float* __restrict__ deg,
                    const int* __restrict__ rows_gcn, const int2* __restrict__ pk_gcn,
                    const int* __restrict__ rows_gat, const int2* __restrict__ pk_gat,
                    const float* __restrict__ We, const float* __restrict__ att,
                    const float* __restrict__ b_gcn, const float* __restrict__ b_gat,
                    const float* __restrict__ gamma, const float* __restrict__ beta,
                    float* __restrict__ glom_out,
                    const unsigned short* __restrict__ xb_glom,
                    const float* __restrict__ x_imm, const float* __restrict__ eps,
                    const int* __restrict__ rows_gin, const int* __restrict__ src_gin,
                    unsigned short* __restrict__ agg,
                    int N)
{
    int gw   = __builtin_amdgcn_readfirstlane((blockIdx.x * 256 + threadIdx.x) >> 6);
    int lane = threadIdx.x & 63;

    if (gw < N) {
        // ------------------------------ glom path -------------------------
        int node = gw;
        float4 We4  = ld4(&We[lane * 4]);
        float4 att4 = ld4(&att[lane * 4]);
        float4 hrv  = ldb4(&hr[(size_t)node * D + lane * 4]);

        float di = rsqrtf(deg[node]);
        float4 acc = ldb4(&xws[(size_t)node * D + lane * 4]);   // = dinv*xw
        float4 g0  = ld4(&b_gcn[lane * 4]);
        float4 a0  = ld4(&b_gat[lane * 4]);
        acc.x = di * acc.x + g0.x + a0.x;
        acc.y = di * acc.y + g0.y + a0.y;
        acc.z = di * acc.z + g0.z + a0.z;
        acc.w = di * acc.w + g0.w + a0.w;

        // ---- GCN neighbor sum, 4 edges in flight ----
        int p  = rows_gcn[node];
        int p1 = rows_gcn[node + 1];
        for (; p + 4 <= p1; p += 4) {
            int2  pk[4];
            float cf[4];
            float4 v[4];
#pragma unroll
            for (int j = 0; j < 4; ++j) pk[j] = pk_gcn[p + j];
#pragma unroll
            for (int j = 0; j < 4; ++j) cf[j] = __int_as_float(pk[j].y) * di;
#pragma unroll
            for (int j = 0; j < 4; ++j) v[j] = ldb4(&xws[(size_t)pk[j].x * D + lane * 4]);
#pragma unroll
            for (int j = 0; j < 4; ++j) {
                acc.x += cf[j] * v[j].x; acc.y += cf[j] * v[j].y;
                acc.z += cf[j] * v[j].z; acc.w += cf[j] * v[j].w;
            }
        }
        for (; p < p1; ++p) {
            int2 pk = pk_gcn[p];
            float cx = __int_as_float(pk.y) * di;
            float4 v = ldb4(&xws[(size_t)pk.x * D + lane * 4]);
            acc.x += cx * v.x; acc.y += cx * v.y;
            acc.z += cx * v.z; acc.w += cx * v.w;
        }

        // ---- GATv2 online softmax, 4 edges in flight ----
        int q  = rows_gat[node];
        int q1 = rows_gat[node + 1];
        int has = (q1 > q);
        float m = -3.4e38f, den = 0.f;
        float4 ag = make_float4(0.f, 0.f, 0.f, 0.f);
        for (; q + 4 <= q1; q += 4) {
            int2  pk[4];
            float4 h[4];
            float pp[4];
#pragma unroll
            for (int j = 0; j < 4; ++j) pk[j] = pk_gat[q + j];
#pragma unroll
            for (int j = 0; j < 4; ++j) h[j] = ldb4(&hl[(size_t)pk[j].x * D + lane * 4]);
#pragma unroll
            for (int j = 0; j < 4; ++j)
                pp[j] = wave_sum(gat_partial(h[j], hrv, __int_as_float(pk[j].y), We4, att4));
            float mb = fmaxf(fmaxf(pp[0], pp[1]), fmaxf(pp[2], pp[3]));
            float mn = fmaxf(m, mb);
            float scale = __expf(m - mn);
            float x[4];
#pragma unroll
            for (int j = 0; j < 4; ++j) x[j] = __expf(pp[j] - mn);
            den = den * scale + (x[0] + x[1]) + (x[2] + x[3]);
            float axx = 0.f, ayy = 0.f, azz = 0.f, aww = 0.f;
#pragma unroll
            for (int j = 0; j < 4; ++j) {
                axx += x[j] * h[j].x; ayy += x[j] * h[j].y;
                azz += x[j] * h[j].z; aww += x[j] * h[j].w;
            }
            ag.x = ag.x * scale + axx; ag.y = ag.y * scale + ayy;
            ag.z = ag.z * scale + azz; ag.w = ag.w * scale + aww;
            m = mn;
        }
        for (; q < q1; ++q) {
            int2 pk = pk_gat[q];
            float4 h = ldb4(&hl[(size_t)pk.x * D + lane * 4]);
            float pp = wave_sum(gat_partial(h, hrv, __int_as_float(pk.y), We4, att4));
            float mn = fmaxf(m, pp);
            float scale = __expf(m - mn);
            float ex = __expf(pp - mn);
            den = den * scale + ex;
            ag.x = ag.x * scale + ex * h.x;
            ag.y = ag.y * scale + ex * h.y;
            ag.z = ag.z * scale + ex * h.z;
            ag.w = ag.w * scale + ex * h.w;
            m = mn;
        }
        if (has) {
            float inv = 1.0f / den;
            acc.x += ag.x * inv; acc.y += ag.y * inv;
            acc.z += ag.z * inv; acc.w += ag.w * inv;
        }

        // ---- LayerNorm + ReLU ----
        float s_ = acc.x + acc.y + acc.z + acc.w;
        float sq = acc.x * acc.x + acc.y * acc.y + acc.z * acc.z + acc.w * acc.w;
#pragma unroll
        for (int off = 32; off > 0; off >>= 1) {
            s_ += __shfl_xor(s_, off, 64);
            sq += __shfl_xor(sq, off, 64);
        }
        float mu  = s_ * (1.0f / 256.0f);
        float var = sq * (1.0f / 256.0f) - mu * mu;
        float rs  = rsqrtf(var + 1e-5f);
        float4 g = ld4(&gamma[lane * 4]);
        float4 b = ld4(&beta[lane * 4]);
        float4 o;
        o.x = fmaxf(0.f, (acc.x - mu) * rs * g.x + b.x);
        o.y = fmaxf(0.f, (acc.y - mu) * rs * g.y + b.y);
        o.z = fmaxf(0.f, (acc.z - mu) * rs * g.z + b.z);
        o.w = fmaxf(0.f, (acc.w - mu) * rs * g.w + b.w);
        st4(&glom_out[(size_t)node * D + lane * 4], o);
    } else if (gw < 2 * N) {
        // ------------------------------ gin path --------------------------
        int node = gw - N;
        float c = 1.0f + eps[0];
        float4 acc = ld4(&x_imm[(size_t)node * D + lane * 4]);
        acc.x *= c; acc.y *= c; acc.z *= c; acc.w *= c;
        int p  = rows_gin[node];
        int p1 = rows_gin[node + 1];
        for (; p + 4 <= p1; p += 4) {
            int s[4];
            float4 v[4];
#pragma unroll
            for (int j = 0; j < 4; ++j) s[j] = src_gin[p + j];
#pragma unroll
            for (int j = 0; j < 4; ++j) v[j] = ldb4(&xb_glom[(size_t)s[j] * D + lane * 4]);
            acc.x += (v[0].x + v[1].x) + (v[2].x + v[3].x);
            acc.y += (v[0].y + v[1].y) + (v[2].y + v[3].y);
            acc.z += (v[0].z + v[1].z) + (v[2].z + v[3].z);
            acc.w += (v[0].w + v[1].w) + (v[2].w + v[3].w);
        }
        for (; p < p1; ++p) {
            int sx = src_gin[p];
            float4 v = ldb4(&xb_glom[(size_t)sx * D + lane * 4]);
            acc.x += v.x; acc.y += v.y; acc.z += v.z; acc.w += v.w;
        }
        ushort4 o;
        o.x = f2bf(acc.x); o.y = f2bf(acc.y); o.z = f2bf(acc.z); o.w = f2bf(acc.w);
        *reinterpret_cast<ushort4*>(agg + (size_t)node * D + lane * 4) = o;
    }
}

// ------------------------------------------------------------------ launch
extern "C" void kernel_launch(void* const* d_in, const int* in_sizes, int n_in,
                              void* d_out, int out_size, void* d_ws, size_t ws_size,
                              hipStream_t stream)
{
    const float* x_glom = (const float*)d_in[0];
    const float* x_imm  = (const float*)d_in[1];
    const float* ew_gg  = (const float*)d_in[2];
    const float* ea_ig  = (const float*)d_in[3];
    const float* W_gcn  = (const float*)d_in[4];
    const float* b_gcn  = (const float*)d_in[5];
    const float* Wl     = (const float*)d_in[6];
    const float* bl     = (const float*)d_in[7];
    const float* Wr     = (const float*)d_in[8];
    const float* br     = (const float*)d_in[9];
    const float* att    = (const float*)d_in[10];
    const float* We     = (const float*)d_in[11];
    const float* b_gat  = (const float*)d_in[12];
    const float* eps    = (const float*)d_in[13];
    const float* W_gin  = (const float*)d_in[14];
    const float* b_gin  = (const float*)d_in[15];
    const float* gamma  = (const float*)d_in[16];
    const float* beta   = (const float*)d_in[17];
    const int*   ei_gg  = (const int*)d_in[18];
    const int*   ei_ig  = (const int*)d_in[19];
    const int*   ei_gi  = (const int*)d_in[20];

    const int N = in_sizes[0] / D;     // 20000
    const int E = in_sizes[2];         // 320000
    const size_t ND = (size_t)N * D;
    const int TPT = (N + 255) / 256;

    // ---- workspace layout ----
    char* base = (char*)d_ws;
    size_t off = 0;
    auto alloc = [&](size_t bytes) {
        void* p = base + off;
        off = (off + bytes + 255) & ~(size_t)255;
        return p;
    };
    unsigned short* xb_glom = (unsigned short*)alloc(ND * 2);
    unsigned short* xb_imm  = (unsigned short*)alloc(ND * 2);
    unsigned short* xws_b   = (unsigned short*)alloc(ND * 2);
    unsigned short* hl_b    = (unsigned short*)alloc(ND * 2);
    unsigned short* hr_b    = (unsigned short*)alloc(ND * 2);
    unsigned short* agg_b   = (unsigned short*)alloc(ND * 2);
    unsigned short* Wt      = (unsigned short*)alloc(4 * D * D * 2);
    float* deg     = (float*)alloc(N * 4);
    int*   counts  = (int*)alloc(3 * (size_t)N * 4);
    int*   rows    = (int*)alloc(3 * (size_t)(N + 1) * 4);
    int*   parts   = (int*)alloc(3 * (size_t)TPT * 4);
    int*   rank    = (int*)alloc(3 * (size_t)E * 4);
    int2*  pk_gcn  = (int2*)alloc((size_t)E * 8);
    int2*  pk_gat  = (int2*)alloc((size_t)E * 8);
    int*   src_gin = (int*)alloc((size_t)E * 4);

    float* glom_out = (float*)d_out;
    float* imm_out  = (float*)d_out + ND;

    int nb_cast  = (int)((ND / 4 + 255) / 256);
    int nb_3n    = (3 * N + 255) / 256;
    int nb_e     = (E + 255) / 256;
    int nb_2nw   = (2 * N + 3) / 4;

    // 1. casts
    k_cast2<<<dim3(nb_cast, 2), 256, 0, stream>>>(x_glom, xb_glom, x_imm, xb_imm,
                                                  (int)(ND / 4));
    // 2. W transposes + counts zero + deg init
    k_prep_wtz<<<dim3(256, 5), 256, 0, stream>>>(W_gcn, Wr, Wl, W_gin, Wt,
                                                 counts, deg, 3 * N, N);
    // 3-6. CSR build (rank in hist; atomic-free scatter)
    k_hist3<<<dim3(nb_e, 3), 256, 0, stream>>>(ei_gg, ei_ig, ei_gi, ew_gg,
                                               counts, rank, deg, E, N);
    k_scan_tile<<<dim3(TPT, 3), 256, 0, stream>>>(counts, rows, parts, N, TPT);
    k_scan_part<<<3, 128, 0, stream>>>(parts, TPT);
    k_scan_final<<<nb_3n, 256, 0, stream>>>(rows, parts, N, TPT, E);
    k_scatter3<<<dim3(nb_e, 3), 256, 0, stream>>>(ei_gg, ei_ig, ei_gi, ew_gg, ea_ig,
                                                  rows, rank, pk_gcn, pk_gat,
                                                  src_gin, E, N);
    // 7. merged projections
    k_proj<<<dim3((N + 255) / 256, 12), 256, 0, stream>>>(
        xb_glom, xb_imm, Wt, deg, br, bl, xws_b, hr_b, hl_b, N);
    // 8. fused gathers
    k_gather_fused<<<nb_2nw, 256, 0, stream>>>(
        xws_b, hl_b, hr_b, deg,
        rows, pk_gcn,
        rows + (N + 1), pk_gat,
        We, att, b_gcn, b_gat, gamma, beta, glom_out,
        xb_glom, x_imm, eps,
        rows + 2 * (N + 1), src_gin, agg_b, N);
    // 9. GIN GEMM + fused LN + ReLU
    k_gin_gemm_ln<<<(N + 63) / 64, 256, 0, stream>>>(
        agg_b, Wt + 3 * D * D, b_gin, gamma, beta, imm_out, N);
}

// Round 9
// 240.449 us; speedup vs baseline: 15.0517x; 1.0408x over previous
//
#include <hip/hip_runtime.h>

// HeteroMessagePassingLayer Round 9:
//  - k_front: casts || W-transpose || hist3 in one launch (independent work)
//  - k_mid:  proj GEMM || atomic-free scatter in one launch
//  - gather: software-pipelined CSR packet prefetch
//  - deg = 1 + degsum (degsum zeroed by memset, accumulated in hist)

constexpr int D = 256;

typedef __attribute__((ext_vector_type(4))) float f32x4v;
typedef __attribute__((ext_vector_type(8))) short short8;

// ---------------------------------------------------------------- utilities
__device__ __forceinline__ float4 ld4(const float* p) {
    return *reinterpret_cast<const float4*>(p);
}
__device__ __forceinline__ void st4(float* p, float4 v) {
    *reinterpret_cast<float4*>(p) = v;
}
__device__ __forceinline__ unsigned short f2bf(float f) {
    unsigned u = __float_as_uint(f);
    u = u + 0x7FFFu + ((u >> 16) & 1u);
    return (unsigned short)(u >> 16);
}
__device__ __forceinline__ float bf2f(unsigned short u) {
    return __uint_as_float(((unsigned)u) << 16);
}
__device__ __forceinline__ float4 ldb4(const unsigned short* p) {
    ushort4 u = *reinterpret_cast<const ushort4*>(p);
    return make_float4(bf2f(u.x), bf2f(u.y), bf2f(u.z), bf2f(u.w));
}
__device__ __forceinline__ float wave_sum(float p) {
#pragma unroll
    for (int off = 32; off > 0; off >>= 1) p += __shfl_xor(p, off, 64);
    return p;
}
__device__ __forceinline__ float gat_partial(float4 h, float4 hrv, float ea,
                                             float4 We4, float4 att4) {
    float z, pp = 0.f;
    z = h.x + hrv.x + ea * We4.x; z *= (z > 0.f) ? 1.0f : 0.2f; pp += z * att4.x;
    z = h.y + hrv.y + ea * We4.y; z *= (z > 0.f) ? 1.0f : 0.2f; pp += z * att4.y;
    z = h.z + hrv.z + ea * We4.z; z *= (z > 0.f) ? 1.0f : 0.2f; pp += z * att4.z;
    z = h.w + hrv.w + ea * We4.w; z *= (z > 0.f) ? 1.0f : 0.2f; pp += z * att4.w;
    return pp;
}

// ============ k_front: cast x_glom | cast x_imm | W transposes | hist3
__global__ __launch_bounds__(256)
void k_front(const float* __restrict__ x_glom, const float* __restrict__ x_imm,
             unsigned short* __restrict__ xb_glom, unsigned short* __restrict__ xb_imm,
             const float* __restrict__ W0, const float* __restrict__ W1,
             const float* __restrict__ W2, const float* __restrict__ W3,
             unsigned short* __restrict__ Wt,
             const int* __restrict__ ei_gg, const int* __restrict__ ei_ig,
             const int* __restrict__ ei_gi, const float* __restrict__ ew_gg,
             int* __restrict__ counts, int* __restrict__ rank,
             float* __restrict__ degsum,
             int n4, int nbCast, int nbHist, int E, int N)
{
    int bx = blockIdx.x;
    if (bx < 2 * nbCast) {
        // ---- casts ----
        bool second = (bx >= nbCast);
        int i = (second ? bx - nbCast : bx) * 256 + threadIdx.x;
        if (i < n4) {
            const float* x = second ? x_imm : x_glom;
            unsigned short* y = second ? xb_imm : xb_glom;
            float4 v = ld4(x + (size_t)i * 4);
            ushort4 o;
            o.x = f2bf(v.x); o.y = f2bf(v.y); o.z = f2bf(v.z); o.w = f2bf(v.w);
            *reinterpret_cast<ushort4*>(y + (size_t)i * 4) = o;
        }
        return;
    }
    bx -= 2 * nbCast;
    if (bx < 1024) {
        // ---- W transposes (bf16, order Wgcn, Wr, Wl, Wgin) ----
        int w = bx >> 8;
        int i = ((bx & 255) << 8) + threadIdx.x;
        const float* W = (w == 0) ? W0 : (w == 1) ? W1 : (w == 2) ? W2 : W3;
        int c = i >> 8, k = i & 255;
        Wt[(size_t)w * D * D + i] = f2bf(W[k * D + c]);
        return;
    }
    bx -= 1024;
    {
        // ---- hist: counts + rank + degsum ----
        int t = bx / nbHist;
        int e = (bx - t * nbHist) * 256 + threadIdx.x;
        if (e >= E) return;
        const int* ei = (t == 0) ? ei_gg : (t == 1) ? ei_ig : ei_gi;
        int d = ei[E + e];
        rank[(size_t)t * E + e] = atomicAdd(&counts[t * N + d], 1);
        if (t == 0) atomicAdd(&degsum[d], ew_gg[e]);
    }
}

// --------------------------------------------------------------- scans
__global__ __launch_bounds__(256)
void k_scan_tile(const int* __restrict__ counts, int* __restrict__ rows,
                 int* __restrict__ partials, int N, int TPT)
{
    int t = blockIdx.y, tile = blockIdx.x;
    int i = tile * 256 + threadIdx.x;
    __shared__ int sh[256];
    int v = (i < N) ? counts[(size_t)t * N + i] : 0;
    sh[threadIdx.x] = v;
    __syncthreads();
#pragma unroll
    for (int off = 1; off < 256; off <<= 1) {
        int add = (threadIdx.x >= off) ? sh[threadIdx.x - off] : 0;
        __syncthreads();
        sh[threadIdx.x] += add;
        __syncthreads();
    }
    if (i < N) rows[(size_t)t * (N + 1) + i] = sh[threadIdx.x] - v;
    if (threadIdx.x == 255) partials[t * TPT + tile] = sh[255];
}

__global__ __launch_bounds__(128)
void k_scan_part(int* __restrict__ partials, int TPT)
{
    int t = blockIdx.x;
    __shared__ int sh[128];
    int v = (threadIdx.x < TPT) ? partials[t * TPT + threadIdx.x] : 0;
    sh[threadIdx.x] = v;
    __syncthreads();
#pragma unroll
    for (int off = 1; off < 128; off <<= 1) {
        int add = (threadIdx.x >= off) ? sh[threadIdx.x - off] : 0;
        __syncthreads();
        sh[threadIdx.x] += add;
        __syncthreads();
    }
    if (threadIdx.x < TPT) partials[t * TPT + threadIdx.x] = sh[threadIdx.x] - v;
}

__global__ void k_scan_final(int* __restrict__ rows, const int* __restrict__ partials,
                             int N, int TPT, int E)
{
    int i = blockIdx.x * 256 + threadIdx.x;
    if (i >= 3 * N) return;
    int t = i / N, j = i - t * N;
    rows[(size_t)t * (N + 1) + j] += partials[t * TPT + (j >> 8)];
    if (j == 0) rows[(size_t)t * (N + 1) + N] = E;
}

// ============ k_mid: proj GEMM blocks first, then scatter blocks
__global__ __launch_bounds__(256)
void k_mid(// proj
           const unsigned short* __restrict__ xbg,
           const unsigned short* __restrict__ xbi,
           const unsigned short* __restrict__ Wt,
           const float* __restrict__ degsum,
           const float* __restrict__ br, const float* __restrict__ bl,
           unsigned short* __restrict__ xws, unsigned short* __restrict__ hr,
           unsigned short* __restrict__ hl,
           // scatter
           const int* __restrict__ ei_gg, const int* __restrict__ ei_ig,
           const int* __restrict__ ei_gi, const float* __restrict__ ew_gg,
           const float* __restrict__ ea_ig,
           const int* __restrict__ rows, const int* __restrict__ rank,
           int2* __restrict__ pk_gcn, int2* __restrict__ pk_gat,
           int* __restrict__ src_gin,
           int nbProjRow, int nbProj, int nbE, int E, int N, int M)
{
    int bx = blockIdx.x;
    if (bx < nbProj) {
        // ----------------------------- proj GEMM --------------------------
        int brow = bx / 12;
        int yy   = bx - brow * 12;
        const int lane = threadIdx.x & 63;
        const int wave = threadIdx.x >> 6;
        const int lr = lane & 15;
        const int lk = lane >> 4;
        const int row0 = brow * 256 + wave * 64;

        const unsigned short* A;
        const unsigned short* Bt0;
        int col0;
        if (yy < 8) { A = xbg; Bt0 = Wt;             col0 = yy * 64; }
        else        { A = xbi; Bt0 = Wt + 2 * D * D; col0 = (yy - 8) * 64; }

        const unsigned short* ap[4];
#pragma unroll
        for (int rf = 0; rf < 4; ++rf) {
            int arow = row0 + rf * 16 + lr;
            int arow_c = (arow < M) ? arow : (M - 1);
            ap[rf] = A + (size_t)arow_c * D + lk * 8;
        }
        const unsigned short* bp = Bt0 + (size_t)(col0 + lr) * D + lk * 8;

        f32x4v acc[4][4] = {};
#pragma unroll
        for (int k0 = 0; k0 < 256; k0 += 32) {
            short8 af[4], bf[4];
#pragma unroll
            for (int rf = 0; rf < 4; ++rf)
                af[rf] = *reinterpret_cast<const short8*>(ap[rf] + k0);
#pragma unroll
            for (int nf = 0; nf < 4; ++nf)
                bf[nf] = *reinterpret_cast<const short8*>(bp + (size_t)nf * 16 * D + k0);
#pragma unroll
            for (int rf = 0; rf < 4; ++rf)
#pragma unroll
                for (int nf = 0; nf < 4; ++nf)
                    acc[rf][nf] = __builtin_amdgcn_mfma_f32_16x16x32_bf16(
                        af[rf], bf[nf], acc[rf][nf], 0, 0, 0);
        }

#pragma unroll
        for (int nf = 0; nf < 4; ++nf) {
            int c = col0 + nf * 16 + lr;
            unsigned short* dst;
            int cc;
            float bv;
            bool scaled;
            if (yy < 8) {
                if (c < 256) { dst = xws; cc = c;       bv = 0.f;    scaled = true;  }
                else         { dst = hr;  cc = c - 256; bv = br[cc]; scaled = false; }
            } else           { dst = hl;  cc = c;       bv = bl[cc]; scaled = false; }
#pragma unroll
            for (int rf = 0; rf < 4; ++rf) {
#pragma unroll
                for (int i = 0; i < 4; ++i) {
                    int r = row0 + rf * 16 + 4 * lk + i;
                    if (r < M) {
                        float sc = scaled ? rsqrtf(1.0f + degsum[r]) : 1.0f;
                        dst[(size_t)r * D + cc] = f2bf(acc[rf][nf][i] * sc + bv);
                    }
                }
            }
        }
        return;
    }
    // ------------------------------- scatter ------------------------------
    int sx = bx - nbProj;
    int t = sx / nbE;
    int e = (sx - t * nbE) * 256 + threadIdx.x;
    if (e >= E) return;
    if (t == 0) {
        int s = ei_gg[e], d = ei_gg[E + e];
        int pos = rows[d] + rank[e];
        pk_gcn[pos] = make_int2(s, __float_as_int(ew_gg[e]));
    } else if (t == 1) {
        int s = ei_ig[e], d = ei_ig[E + e];
        int pos = rows[(N + 1) + d] + rank[(size_t)E + e];
        pk_gat[pos] = make_int2(s, __float_as_int(ea_ig[e]));
    } else {
        int s = ei_gi[e], d = ei_gi[E + e];
        int pos = rows[2 * (N + 1) + d] + rank[2 * (size_t)E + e];
        src_gin[pos] = s;
    }
}

// ------------------------------------- GIN GEMM + fused LayerNorm + ReLU
__global__ __launch_bounds__(256)
void k_gin_gemm_ln(const unsigned short* __restrict__ A,
                   const unsigned short* __restrict__ Bt,
                   const float* __restrict__ bias,
                   const float* __restrict__ gamma, const float* __restrict__ beta,
                   float* __restrict__ out, int M)
{
    __shared__ float lds_s[4][64];
    __shared__ float lds_q[4][64];
    const int lane = threadIdx.x & 63;
    const int wave = threadIdx.x >> 6;
    const int lr = lane & 15;
    const int lk = lane >> 4;
    const int row0 = blockIdx.x * 64;
    const int col0 = wave * 64;

    const unsigned short* ap[4];
#pragma unroll
    for (int rf = 0; rf < 4; ++rf) {
        int arow = row0 + rf * 16 + lr;
        int arow_c = (arow < M) ? arow : (M - 1);
        ap[rf] = A + (size_t)arow_c * D + lk * 8;
    }
    const unsigned short* bp = Bt + (size_t)(col0 + lr) * D + lk * 8;

    f32x4v acc[4][4] = {};
#pragma unroll
    for (int k0 = 0; k0 < 256; k0 += 32) {
        short8 af[4], bf[4];
#pragma unroll
        for (int rf = 0; rf < 4; ++rf)
            af[rf] = *reinterpret_cast<const short8*>(ap[rf] + k0);
#pragma unroll
        for (int nf = 0; nf < 4; ++nf)
            bf[nf] = *reinterpret_cast<const short8*>(bp + (size_t)nf * 16 * D + k0);
#pragma unroll
        for (int rf = 0; rf < 4; ++rf)
#pragma unroll
            for (int nf = 0; nf < 4; ++nf)
                acc[rf][nf] = __builtin_amdgcn_mfma_f32_16x16x32_bf16(
                    af[rf], bf[nf], acc[rf][nf], 0, 0, 0);
    }

    float bv[4], gv[4], be[4];
#pragma unroll
    for (int nf = 0; nf < 4; ++nf) {
        int c = col0 + nf * 16 + lr;
        bv[nf] = bias[c]; gv[nf] = gamma[c]; be[nf] = beta[c];
    }

#pragma unroll
    for (int rf = 0; rf < 4; ++rf) {
        float ps[4], pq[4];
#pragma unroll
        for (int i = 0; i < 4; ++i) {
            float s = 0.f, q = 0.f;
#pragma unroll
            for (int nf = 0; nf < 4; ++nf) {
                float v = acc[rf][nf][i] + bv[nf];
                acc[rf][nf][i] = v;
                s += v; q += v * v;
            }
            ps[i] = s; pq[i] = q;
        }
#pragma unroll
        for (int off = 1; off < 16; off <<= 1) {
#pragma unroll
            for (int i = 0; i < 4; ++i) {
                ps[i] += __shfl_xor(ps[i], off, 64);
                pq[i] += __shfl_xor(pq[i], off, 64);
            }
        }
        if (lr == 0) {
#pragma unroll
            for (int i = 0; i < 4; ++i) {
                lds_s[wave][rf * 16 + lk * 4 + i] = ps[i];
                lds_q[wave][rf * 16 + lk * 4 + i] = pq[i];
            }
        }
    }
    __syncthreads();

#pragma unroll
    for (int rf = 0; rf < 4; ++rf) {
#pragma unroll
        for (int i = 0; i < 4; ++i) {
            int rl = rf * 16 + 4 * lk + i;
            float s = lds_s[0][rl] + lds_s[1][rl] + lds_s[2][rl] + lds_s[3][rl];
            float q = lds_q[0][rl] + lds_q[1][rl] + lds_q[2][rl] + lds_q[3][rl];
            float mu  = s * (1.0f / 256.0f);
            float var = q * (1.0f / 256.0f) - mu * mu;
            float rs  = rsqrtf(var + 1e-5f);
            int r = row0 + rl;
            if (r < M) {
#pragma unroll
                for (int nf = 0; nf < 4; ++nf) {
                    out[(size_t)r * D + col0 + nf * 16 + lr] =
                        fmaxf(0.f, (acc[rf][nf][i] - mu) * rs * gv[nf] + be[nf]);
                }
            }
        }
    }
}

// ================== fused gather: glom (GCN+GATv2+LN) and GIN, one launch
__global__ __launch_bounds__(256)
void k_gather_fused(const unsigned short* __restrict__ xws,
                    const unsigned short* __restrict__ hl,
                    const unsigned short* __restrict__ hr,
                    const float* __restrict__ degsum,
                    const int* __restrict__ rows_gcn, const int2* __restrict__ pk_gcn,
                    const int* __restrict__ rows_gat, const int2* __restrict__ pk_gat,
                    const float* __restrict__ We, const float* __restrict__ att,
                    const float* __restrict__ b_gcn, const float* __restrict__ b_gat,
                    const float* __restrict__ gamma, const float* __restrict__ beta,
                    float* __restrict__ glom_out,
                    const unsigned short* __restrict__ xb_glom,
                    const float* __restrict__ x_imm, const float* __restrict__ eps,
                    const int* __restrict__ rows_gin, const int* __restrict__ src_gin,
                    unsigned short* __restrict__ agg,
                    int N)
{
    int gw   = __builtin_amdgcn_readfirstlane((blockIdx.x * 256 + threadIdx.x) >> 6);
    int lane = threadIdx.x & 63;

    if (gw < N) {
        // ------------------------------ glom path -------------------------
        int node = gw;
        float4 We4  = ld4(&We[lane * 4]);
        float4 att4 = ld4(&att[lane * 4]);
        float4 hrv  = ldb4(&hr[(size_t)node * D + lane * 4]);

        float di = rsqrtf(1.0f + degsum[node]);
        float4 acc = ldb4(&xws[(size_t)node * D + lane * 4]);   // = dinv*xw
        float4 g0  = ld4(&b_gcn[lane * 4]);
        float4 a0  = ld4(&b_gat[lane * 4]);
        acc.x = di * acc.x + g0.x + a0.x;
        acc.y = di * acc.y + g0.y + a0.y;
        acc.z = di * acc.z + g0.z + a0.z;
        acc.w = di * acc.w + g0.w + a0.w;

        // ---- GCN neighbor sum, 4-wide + pk prefetch ----
        int p  = rows_gcn[node];
        int p1 = rows_gcn[node + 1];
        int2 pkn[4];
        if (p + 4 <= p1) {
#pragma unroll
            for (int j = 0; j < 4; ++j) pkn[j] = pk_gcn[p + j];
        }
        while (p + 4 <= p1) {
            int2 pkc[4];
#pragma unroll
            for (int j = 0; j < 4; ++j) pkc[j] = pkn[j];
            p += 4;
            if (p + 4 <= p1) {
#pragma unroll
                for (int j = 0; j < 4; ++j) pkn[j] = pk_gcn[p + j];
            }
            float cf[4];
            float4 v[4];
#pragma unroll
            for (int j = 0; j < 4; ++j) cf[j] = __int_as_float(pkc[j].y) * di;
#pragma unroll
            for (int j = 0; j < 4; ++j) v[j] = ldb4(&xws[(size_t)pkc[j].x * D + lane * 4]);
#pragma unroll
            for (int j = 0; j < 4; ++j) {
                acc.x += cf[j] * v[j].x; acc.y += cf[j] * v[j].y;
                acc.z += cf[j] * v[j].z; acc.w += cf[j] * v[j].w;
            }
        }
        for (; p < p1; ++p) {
            int2 pk = pk_gcn[p];
            float cx = __int_as_float(pk.y) * di;
            float4 v = ldb4(&xws[(size_t)pk.x * D + lane * 4]);
            acc.x += cx * v.x; acc.y += cx * v.y;
            acc.z += cx * v.z; acc.w += cx * v.w;
        }

        // ---- GATv2 online softmax, 4-wide + pk prefetch ----
        int q  = rows_gat[node];
        int q1 = rows_gat[node + 1];
        int has = (q1 > q);
        float m = -3.4e38f, den = 0.f;
        float4 ag = make_float4(0.f, 0.f, 0.f, 0.f);
        int2 qkn[4];
        if (q + 4 <= q1) {
#pragma unroll
            for (int j = 0; j < 4; ++j) qkn[j] = pk_gat[q + j];
        }
        while (q + 4 <= q1) {
            int2 qkc[4];
#pragma unroll
            for (int j = 0; j < 4; ++j) qkc[j] = qkn[j];
            q += 4;
            if (q + 4 <= q1) {
#pragma unroll
                for (int j = 0; j < 4; ++j) qkn[j] = pk_gat[q + j];
            }
            float4 h[4];
            float pp[4];
#pragma unroll
            for (int j = 0; j < 4; ++j) h[j] = ldb4(&hl[(size_t)qkc[j].x * D + lane * 4]);
#pragma unroll
            for (int j = 0; j < 4; ++j)
                pp[j] = wave_sum(gat_partial(h[j], hrv, __int_as_float(qkc[j].y), We4, att4));
            float mb = fmaxf(fmaxf(pp[0], pp[1]), fmaxf(pp[2], pp[3]));
            float mn = fmaxf(m, mb);
            float scale = __expf(m - mn);
            float x[4];
#pragma unroll
            for (int j = 0; j < 4; ++j) x[j] = __expf(pp[j] - mn);
            den = den * scale + (x[0] + x[1]) + (x[2] + x[3]);
            float axx = 0.f, ayy = 0.f, azz = 0.f, aww = 0.f;
#pragma unroll
            for (int j = 0; j < 4; ++j) {
                axx += x[j] * h[j].x; ayy += x[j] * h[j].y;
                azz += x[j] * h[j].z; aww += x[j] * h[j].w;
            }
            ag.x = ag.x * scale + axx; ag.y = ag.y * scale + ayy;
            ag.z = ag.z * scale + azz; ag.w = ag.w * scale + aww;
            m = mn;
        }
        for (; q < q1; ++q) {
            int2 pk = pk_gat[q];
            float4 h = ldb4(&hl[(size_t)pk.x * D + lane * 4]);
            float pp = wave_sum(gat_partial(h, hrv, __int_as_float(pk.y), We4, att4));
            float mn = fmaxf(m, pp);
            float scale = __expf(m - mn);
            float ex = __expf(pp - mn);
            den = den * scale + ex;
            ag.x = ag.x * scale + ex * h.x;
            ag.y = ag.y * scale + ex * h.y;
            ag.z = ag.z * scale + ex * h.z;
            ag.w = ag.w * scale + ex * h.w;
            m = mn;
        }
        if (has) {
            float inv = 1.0f / den;
            acc.x += ag.x * inv; acc.y += ag.y * inv;
            acc.z += ag.z * inv; acc.w += ag.w * inv;
        }

        // ---- LayerNorm + ReLU ----
        float s_ = acc.x + acc.y + acc.z + acc.w;
        float sq = acc.x * acc.x + acc.y * acc.y + acc.z * acc.z + acc.w * acc.w;
#pragma unroll
        for (int off = 32; off > 0; off >>= 1) {
            s_ += __shfl_xor(s_, off, 64);
            sq += __shfl_xor(sq, off, 64);
        }
        float mu  = s_ * (1.0f / 256.0f);
        float var = sq * (1.0f / 256.0f) - mu * mu;
        float rs  = rsqrtf(var + 1e-5f);
        float4 g = ld4(&gamma[lane * 4]);
        float4 b = ld4(&beta[lane * 4]);
        float4 o;
        o.x = fmaxf(0.f, (acc.x - mu) * rs * g.x + b.x);
        o.y = fmaxf(0.f, (acc.y - mu) * rs * g.y + b.y);
        o.z = fmaxf(0.f, (acc.z - mu) * rs * g.z + b.z);
        o.w = fmaxf(0.f, (acc.w - mu) * rs * g.w + b.w);
        st4(&glom_out[(size_t)node * D + lane * 4], o);
    } else if (gw < 2 * N) {
        // ------------------------------ gin path --------------------------
        int node = gw - N;
        float c = 1.0f + eps[0];
        float4 acc = ld4(&x_imm[(size_t)node * D + lane * 4]);
        acc.x *= c; acc.y *= c; acc.z *= c; acc.w *= c;
        int p  = rows_gin[node];
        int p1 = rows_gin[node + 1];
        int sn[4];
        if (p + 4 <= p1) {
#pragma unroll
            for (int j = 0; j < 4; ++j) sn[j] = src_gin[p + j];
        }
        while (p + 4 <= p1) {
            int sc[4];
#pragma unroll
            for (int j = 0; j < 4; ++j) sc[j] = sn[j];
            p += 4;
            if (p + 4 <= p1) {
#pragma unroll
                for (int j = 0; j < 4; ++j) sn[j] = src_gin[p + j];
            }
            float4 v[4];
#pragma unroll
            for (int j = 0; j < 4; ++j) v[j] = ldb4(&xb_glom[(size_t)sc[j] * D + lane * 4]);
            acc.x += (v[0].x + v[1].x) + (v[2].x + v[3].x);
            acc.y += (v[0].y + v[1].y) + (v[2].y + v[3].y);
            acc.z += (v[0].z + v[1].z) + (v[2].z + v[3].z);
            acc.w += (v[0].w + v[1].w) + (v[2].w + v[3].w);
        }
        for (; p < p1; ++p) {
            int sx = src_gin[p];
            float4 v = ldb4(&xb_glom[(size_t)sx * D + lane * 4]);
            acc.x += v.x; acc.y += v.y; acc.z += v.z; acc.w += v.w;
        }
        ushort4 o;
        o.x = f2bf(acc.x); o.y = f2bf(acc.y); o.z = f2bf(acc.z); o.w = f2bf(acc.w);
        *reinterpret_cast<ushort4*>(agg + (size_t)node * D + lane * 4) = o;
    }
}

// ------------------------------------------------------------------ launch
extern "C" void kernel_launch(void* const* d_in, const int* in_sizes, int n_in,
                              void* d_out, int out_size, void* d_ws, size_t ws_size,
                              hipStream_t stream)
{
    const float* x_glom = (const float*)d_in[0];
    const float* x_imm  = (const float*)d_in[1];
    const float* ew_gg  = (const float*)d_in[2];
    const float* ea_ig  = (const float*)d_in[3];
    const float* W_gcn  = (const float*)d_in[4];
    const float* b_gcn  = (const float*)d_in[5];
    const float* Wl     = (const float*)d_in[6];
    const float* bl     = (const float*)d_in[7];
    const float* Wr     = (const float*)d_in[8];
    const float* br     = (const float*)d_in[9];
    const float* att    = (const float*)d_in[10];
    const float* We     = (const float*)d_in[11];
    const float* b_gat  = (const float*)d_in[12];
    const float* eps    = (const float*)d_in[13];
    const float* W_gin  = (const float*)d_in[14];
    const float* b_gin  = (const float*)d_in[15];
    const float* gamma  = (const float*)d_in[16];
    const float* beta   = (const float*)d_in[17];
    const int*   ei_gg  = (const int*)d_in[18];
    const int*   ei_ig  = (const int*)d_in[19];
    const int*   ei_gi  = (const int*)d_in[20];

    const int N = in_sizes[0] / D;     // 20000
    const int E = in_sizes[2];         // 320000
    const size_t ND = (size_t)N * D;
    const int TPT = (N + 255) / 256;

    // ---- workspace layout ----
    char* base = (char*)d_ws;
    size_t off = 0;
    auto alloc = [&](size_t bytes) {
        void* p = base + off;
        off = (off + bytes + 255) & ~(size_t)255;
        return p;
    };
    unsigned short* xb_glom = (unsigned short*)alloc(ND * 2);
    unsigned short* xb_imm  = (unsigned short*)alloc(ND * 2);
    unsigned short* xws_b   = (unsigned short*)alloc(ND * 2);
    unsigned short* hl_b    = (unsigned short*)alloc(ND * 2);
    unsigned short* hr_b    = (unsigned short*)alloc(ND * 2);
    unsigned short* agg_b   = (unsigned short*)alloc(ND * 2);
    unsigned short* Wt      = (unsigned short*)alloc(4 * D * D * 2);
    int*   counts  = (int*)alloc(3 * (size_t)N * 4 + (size_t)N * 4); // + degsum
    float* degsum  = (float*)(counts + 3 * (size_t)N);
    int*   rows    = (int*)alloc(3 * (size_t)(N + 1) * 4);
    int*   parts   = (int*)alloc(3 * (size_t)TPT * 4);
    int*   rank    = (int*)alloc(3 * (size_t)E * 4);
    int2*  pk_gcn  = (int2*)alloc((size_t)E * 8);
    int2*  pk_gat  = (int2*)alloc((size_t)E * 8);
    int*   src_gin = (int*)alloc((size_t)E * 4);

    float* glom_out = (float*)d_out;
    float* imm_out  = (float*)d_out + ND;

    const int n4      = (int)(ND / 4);
    const int nbCast  = (n4 + 255) / 256;          // 5000
    const int nbHist  = (E + 255) / 256;           // 1250
    const int nb_3n   = (3 * N + 255) / 256;
    const int nb_2nw  = (2 * N + 3) / 4;
    const int nbProjRow = (N + 255) / 256;         // 79
    const int nbProj    = nbProjRow * 12;          // 948

    // 0. zero counts + degsum (contiguous)
    hipMemsetAsync(counts, 0, 4 * (size_t)N * 4, stream);
    // 1. front: casts || W transposes || hist3
    k_front<<<2 * nbCast + 1024 + 3 * nbHist, 256, 0, stream>>>(
        x_glom, x_imm, xb_glom, xb_imm,
        W_gcn, Wr, Wl, W_gin, Wt,
        ei_gg, ei_ig, ei_gi, ew_gg,
        counts, rank, degsum, n4, nbCast, nbHist, E, N);
    // 2-4. scans
    k_scan_tile<<<dim3(TPT, 3), 256, 0, stream>>>(counts, rows, parts, N, TPT);
    k_scan_part<<<3, 128, 0, stream>>>(parts, TPT);
    k_scan_final<<<nb_3n, 256, 0, stream>>>(rows, parts, N, TPT, E);
    // 5. mid: proj GEMM || scatter
    k_mid<<<nbProj + 3 * nbHist, 256, 0, stream>>>(
        xb_glom, xb_imm, Wt, degsum, br, bl, xws_b, hr_b, hl_b,
        ei_gg, ei_ig, ei_gi, ew_gg, ea_ig,
        rows, rank, pk_gcn, pk_gat, src_gin,
        nbProjRow, nbProj, nbHist, E, N, N);
    // 6. fused gathers
    k_gather_fused<<<nb_2nw, 256, 0, stream>>>(
        xws_b, hl_b, hr_b, degsum,
        rows, pk_gcn,
        rows + (N + 1), pk_gat,
        We, att, b_gcn, b_gat, gamma, beta, glom_out,
        xb_glom, x_imm, eps,
        rows + 2 * (N + 1), src_gin, agg_b, N);
    // 7. GIN GEMM + fused LN + ReLU
    k_gin_gemm_ln<<<(N + 63) / 64, 256, 0, stream>>>(
        agg_b, Wt + 3 * D * D, b_gin, gamma, beta, imm_out, N);
}